// Round 1
// baseline (1666.883 us; speedup 1.0000x reference)
//
#include <hip/hip_runtime.h>
#include <math.h>

#define B_ 4
#define S_ 8192
#define D_ 512
#define H_ 8
#define HD_ 64
#define U_ 45            // int(5*ln(8193)) = 45
#define NCHUNK 32
#define CH 256           // keys per attention block

__device__ __forceinline__ float bfbits2f(unsigned short v) {
    unsigned u = ((unsigned)v) << 16;
    return __uint_as_float(u);
}
__device__ __forceinline__ unsigned short f2bf(float f) {
    unsigned u = __float_as_uint(f);
    unsigned r = u + 0x7fffu + ((u >> 16) & 1u);   // RNE
    return (unsigned short)(r >> 16);
}

// ---------------------------------------------------------------------------
// Fused QKV projection GEMM: X[32768x512] @ {Wq,Wk,Wv}[512x512] (+bias).
// Q columns -> per-(b,h,s) sum of squares (sparsity), values discarded.
// K,V columns -> bf16 buffers.
// Grid (512, 24): blockIdx.y: 0..7 Q-heads, 8..15 K n-tiles, 16..23 V n-tiles.
// ---------------------------------------------------------------------------
__global__ __launch_bounds__(256) void qkv_gemm(
    const float* __restrict__ X,
    const float* __restrict__ Wq, const float* __restrict__ bq,
    const float* __restrict__ Wk, const float* __restrict__ bk,
    const float* __restrict__ Wv, const float* __restrict__ bv,
    unsigned short* __restrict__ Kbuf, unsigned short* __restrict__ Vbuf,
    float* __restrict__ sparsity)
{
    __shared__ float As[16][64];   // [k][m] transposed
    __shared__ float Bs[16][64];   // [k][n]
    __shared__ float red[64];

    const int tid  = threadIdx.x;
    const int m0   = blockIdx.x * 64;
    const int nb   = blockIdx.y;
    const int mat  = nb >> 3;                 // 0=q 1=k 2=v
    const int col0 = (nb & 7) * 64;
    const float* W    = (mat == 0) ? Wq : (mat == 1) ? Wk : Wv;
    const float* bias = (mat == 0) ? bq : (mat == 1) ? bk : bv;

    const int lrow = tid >> 2;                // A-load row 0..63
    const int lkq  = (tid & 3) * 4;           // A-load k offset
    const int brow = tid >> 4;                // B-load k 0..15
    const int bcol = (tid & 15) * 4;          // B-load col

    const int ty = tid >> 4;                  // m-group 0..15
    const int tx = tid & 15;                  // n-group 0..15

    float acc[4][4] = {};
    for (int k0 = 0; k0 < 512; k0 += 16) {
        float4 av  = *(const float4*)(X + (size_t)(m0 + lrow) * 512 + k0 + lkq);
        float4 bv4 = *(const float4*)(W + (size_t)(k0 + brow) * 512 + col0 + bcol);
        __syncthreads();
        As[lkq + 0][lrow] = av.x;
        As[lkq + 1][lrow] = av.y;
        As[lkq + 2][lrow] = av.z;
        As[lkq + 3][lrow] = av.w;
        *(float4*)&Bs[brow][bcol] = bv4;
        __syncthreads();
#pragma unroll
        for (int kk = 0; kk < 16; ++kk) {
            float4 a4 = *(const float4*)&As[kk][ty * 4];
            float4 b4 = *(const float4*)&Bs[kk][tx * 4];
            float ar[4] = {a4.x, a4.y, a4.z, a4.w};
            float br[4] = {b4.x, b4.y, b4.z, b4.w};
#pragma unroll
            for (int i = 0; i < 4; ++i)
#pragma unroll
                for (int j = 0; j < 4; ++j)
                    acc[i][j] = fmaf(ar[i], br[j], acc[i][j]);
        }
    }

    float4 bias4 = *(const float4*)(bias + col0 + tx * 4);
    float bb[4] = {bias4.x, bias4.y, bias4.z, bias4.w};

    const int b    = m0 / S_;                 // 64 | 8192 so uniform per block
    const int s0   = m0 % S_;

    if (mat == 0) {
        if (tid < 64) red[tid] = 0.f;
        __syncthreads();
#pragma unroll
        for (int i = 0; i < 4; ++i) {
            float p = 0.f;
#pragma unroll
            for (int j = 0; j < 4; ++j) {
                float v = acc[i][j] + bb[j];
                p = fmaf(v, v, p);
            }
            atomicAdd(&red[ty * 4 + i], p);
        }
        __syncthreads();
        if (tid < 64) {
            int h = col0 >> 6;
            sparsity[((size_t)b * H_ + h) * S_ + s0 + tid] = red[tid];
        }
    } else {
        unsigned short* Obuf = (mat == 1) ? Kbuf : Vbuf;
#pragma unroll
        for (int i = 0; i < 4; ++i) {
            ushort4 o;
            o.x = f2bf(acc[i][0] + bb[0]);
            o.y = f2bf(acc[i][1] + bb[1]);
            o.z = f2bf(acc[i][2] + bb[2]);
            o.w = f2bf(acc[i][3] + bb[3]);
            *(ushort4*)(Obuf + (size_t)(m0 + ty * 4 + i) * 512 + col0 + tx * 4) = o;
        }
    }
}

// ---------------------------------------------------------------------------
// Per-(b,h) sum of V over sequence -> vsum[bh][64]  (fp32)
// ---------------------------------------------------------------------------
__global__ __launch_bounds__(256) void vsum_kernel(
    const unsigned short* __restrict__ Vbuf, float* __restrict__ vsum)
{
    const int bh = blockIdx.x, b = bh >> 3, h = bh & 7;
    const int d = threadIdx.x & 63, sg = threadIdx.x >> 6;
    const unsigned short* vp = Vbuf + (size_t)b * S_ * 512 + h * 64 + d;
    float s = 0.f;
    for (int srow = sg; srow < S_; srow += 4)
        s += bfbits2f(vp[(size_t)srow * 512]);
    __shared__ float red[4][64];
    red[sg][d] = s;
    __syncthreads();
    if (threadIdx.x < 64) {
        int t = threadIdx.x;
        vsum[bh * 64 + t] = red[0][t] + red[1][t] + red[2][t] + red[3][t];
    }
}

// ---------------------------------------------------------------------------
// Top-45 per (b,h) by iterative argmax (stable: smaller index wins ties)
// ---------------------------------------------------------------------------
__global__ __launch_bounds__(256) void topk_kernel(
    const float* __restrict__ sparsity, int* __restrict__ topidx)
{
    __shared__ float vals[S_];
    __shared__ float rmax[256];
    __shared__ int   ridx[256];
    const int bh = blockIdx.x, tid = threadIdx.x;
    const float* sp = sparsity + (size_t)bh * S_;
    for (int i = tid; i < S_; i += 256) vals[i] = sp[i];
    __syncthreads();
    for (int it = 0; it < U_; ++it) {
        float bm = -INFINITY; int bi = S_;
        for (int i = tid; i < S_; i += 256) {
            float v = vals[i];
            if (v > bm) { bm = v; bi = i; }
        }
        rmax[tid] = bm; ridx[tid] = bi;
        __syncthreads();
        for (int off = 128; off > 0; off >>= 1) {
            if (tid < off) {
                float ov = rmax[tid + off]; int oi = ridx[tid + off];
                if (ov > rmax[tid] || (ov == rmax[tid] && oi < ridx[tid])) {
                    rmax[tid] = ov; ridx[tid] = oi;
                }
            }
            __syncthreads();
        }
        if (tid == 0) {
            topidx[bh * U_ + it] = ridx[0];
            vals[ridx[0]] = -INFINITY;
        }
        __syncthreads();
    }
}

// ---------------------------------------------------------------------------
// Recompute selected Q rows exactly in fp32: selq[bh][q][64]
// ---------------------------------------------------------------------------
__global__ __launch_bounds__(64) void selq_kernel(
    const float* __restrict__ X, const float* __restrict__ Wq,
    const float* __restrict__ bq, const int* __restrict__ topidx,
    float* __restrict__ selq)
{
    const int q = blockIdx.x, bh = blockIdx.y;
    const int b = bh >> 3, h = bh & 7, d = threadIdx.x;
    const int s = topidx[bh * U_ + q];
    const float* xr = X + ((size_t)b * S_ + s) * 512;
    const float* wp = Wq + h * 64 + d;
    float acc = bq[h * 64 + d];
    for (int r = 0; r < 512; ++r)
        acc = fmaf(xr[r], wp[(size_t)r * 512], acc);
    selq[((size_t)bh * U_ + q) * 64 + d] = acc;
}

// ---------------------------------------------------------------------------
// Attention partials: per (bh, chunk of 256 keys):
//   scores -> chunk softmax stats (m,l) -> unnormalized P -> P@V partial acc
// ---------------------------------------------------------------------------
__global__ __launch_bounds__(256) void attn_partial(
    const unsigned short* __restrict__ Kbuf,
    const unsigned short* __restrict__ Vbuf,
    const float* __restrict__ selq,
    float* __restrict__ pm, float* __restrict__ pl, float* __restrict__ pacc)
{
    __shared__ float qs[U_ * 64];   // 11.25 KB
    __shared__ float sc[U_][CH];    // 45 KB
    const int tid = threadIdx.x;
    const int chunk = blockIdx.x;
    const int bh = blockIdx.y, b = bh >> 3, h = bh & 7;
    const int s0 = chunk * CH;

    for (int i = tid; i < U_ * 64; i += 256)
        qs[i] = selq[(size_t)bh * U_ * 64 + i];
    __syncthreads();

    // Phase A: one key per thread, scores for all 45 queries
    {
        const unsigned short* kp = Kbuf + (size_t)(b * S_ + s0 + tid) * 512 + h * 64;
        float kreg[64];
        const uint4* kp4 = (const uint4*)kp;
#pragma unroll
        for (int i = 0; i < 8; ++i) {
            uint4 u = kp4[i];
            unsigned w[4] = {u.x, u.y, u.z, u.w};
#pragma unroll
            for (int j = 0; j < 4; ++j) {
                kreg[i * 8 + j * 2 + 0] = bfbits2f((unsigned short)(w[j] & 0xffffu));
                kreg[i * 8 + j * 2 + 1] = bfbits2f((unsigned short)(w[j] >> 16));
            }
        }
        for (int q = 0; q < U_; ++q) {
            float a = 0.f;
#pragma unroll
            for (int d4 = 0; d4 < 16; ++d4) {
                float4 qv = *(const float4*)&qs[q * 64 + d4 * 4];
                a = fmaf(qv.x, kreg[d4 * 4 + 0], a);
                a = fmaf(qv.y, kreg[d4 * 4 + 1], a);
                a = fmaf(qv.z, kreg[d4 * 4 + 2], a);
                a = fmaf(qv.w, kreg[d4 * 4 + 3], a);
            }
            sc[q][tid] = a * 0.125f;
        }
    }
    __syncthreads();

    // Phase B: wave per query: max, exp, sum (unnormalized weights left in sc)
    {
        const int wid = tid >> 6, lane = tid & 63;
        for (int q = wid; q < U_; q += 4) {
            float m = -INFINITY;
#pragma unroll
            for (int r = 0; r < 4; ++r) m = fmaxf(m, sc[q][lane + r * 64]);
            for (int off = 32; off; off >>= 1) m = fmaxf(m, __shfl_xor(m, off));
            float l = 0.f;
#pragma unroll
            for (int r = 0; r < 4; ++r) {
                float p = __expf(sc[q][lane + r * 64] - m);
                sc[q][lane + r * 64] = p;
                l += p;
            }
            for (int off = 32; off; off >>= 1) l += __shfl_xor(l, off);
            if (lane == 0) {
                pm[((size_t)bh * NCHUNK + chunk) * U_ + q] = m;
                pl[((size_t)bh * NCHUNK + chunk) * U_ + q] = l;
            }
        }
    }
    __syncthreads();

    // Phase C: P[45xCH] @ V[CHx64], lane <-> d, 4 query groups
    {
        const int d = tid & 63, qg = tid >> 6;
        const unsigned short* vp = Vbuf + (size_t)(b * S_ + s0) * 512 + h * 64 + d;
        float facc[12] = {};
        for (int s4 = 0; s4 < CH; s4 += 4) {
            float v0 = bfbits2f(vp[(size_t)(s4 + 0) * 512]);
            float v1 = bfbits2f(vp[(size_t)(s4 + 1) * 512]);
            float v2 = bfbits2f(vp[(size_t)(s4 + 2) * 512]);
            float v3 = bfbits2f(vp[(size_t)(s4 + 3) * 512]);
            int qi = 0;
            for (int q = qg; q < U_; q += 4, ++qi) {
                float4 w = *(const float4*)&sc[q][s4];
                facc[qi] = fmaf(w.x, v0, facc[qi]);
                facc[qi] = fmaf(w.y, v1, facc[qi]);
                facc[qi] = fmaf(w.z, v2, facc[qi]);
                facc[qi] = fmaf(w.w, v3, facc[qi]);
            }
        }
        int qi = 0;
        for (int q = qg; q < U_; q += 4, ++qi)
            pacc[(((size_t)bh * NCHUNK + chunk) * U_ + q) * 64 + d] = facc[qi];
    }
}

// ---------------------------------------------------------------------------
// Combine chunk partials -> correction vector (sel_ctx - mean_v)
// ---------------------------------------------------------------------------
__global__ __launch_bounds__(64) void attn_combine(
    const float* __restrict__ pm, const float* __restrict__ pl,
    const float* __restrict__ pacc, const float* __restrict__ vsum,
    float* __restrict__ corr)
{
    const int q = blockIdx.x, bh = blockIdx.y, d = threadIdx.x;
    float M = -INFINITY;
    for (int c = 0; c < NCHUNK; ++c)
        M = fmaxf(M, pm[((size_t)bh * NCHUNK + c) * U_ + q]);
    float L = 0.f, a = 0.f;
    for (int c = 0; c < NCHUNK; ++c) {
        float mc = pm[((size_t)bh * NCHUNK + c) * U_ + q];
        float lc = pl[((size_t)bh * NCHUNK + c) * U_ + q];
        float f = __expf(mc - M);
        L = fmaf(lc, f, L);
        a = fmaf(f, pacc[(((size_t)bh * NCHUNK + c) * U_ + q) * 64 + d], a);
    }
    corr[((size_t)bh * U_ + q) * 64 + d] = a / L - vsum[bh * 64 + d] * (1.0f / S_);
}

// ---------------------------------------------------------------------------
// out_base[b][512] = bo + mean_flat[b] @ Wo
// ---------------------------------------------------------------------------
__global__ __launch_bounds__(512) void outbase_kernel(
    const float* __restrict__ vsum, const float* __restrict__ Wo,
    const float* __restrict__ bo, float* __restrict__ outbase)
{
    const int b = blockIdx.x, d = threadIdx.x;
    float acc = bo[d];
    for (int r = 0; r < 512; ++r) {
        float mv = vsum[b * 512 + r] * (1.0f / S_);
        acc = fmaf(mv, Wo[(size_t)r * 512 + d], acc);
    }
    outbase[b * 512 + d] = acc;
}

// ---------------------------------------------------------------------------
// Broadcast fill: out[b,s,:] = out_base[b,:]
// ---------------------------------------------------------------------------
__global__ __launch_bounds__(256) void fill_kernel(
    const float* __restrict__ outbase, float* __restrict__ out)
{
    size_t gid = (size_t)blockIdx.x * 256 + threadIdx.x;
    size_t e0 = gid * 4;
    int b = (int)(e0 >> 22);          // 8192*512 = 2^22
    int col = (int)(e0 & 511);
    float4 v = *(const float4*)&outbase[b * 512 + col];
    *(float4*)&out[e0] = v;
}

// ---------------------------------------------------------------------------
// Rank-64 corrections: out[b, s_q, :] += corr[bh][q] @ Wo_h
// ---------------------------------------------------------------------------
__global__ __launch_bounds__(512) void correction_kernel(
    const float* __restrict__ corr, const float* __restrict__ Wo,
    const int* __restrict__ topidx, float* __restrict__ out)
{
    const int q = blockIdx.x, bh = blockIdx.y;
    const int b = bh >> 3, h = bh & 7, d = threadIdx.x;
    const int s = topidx[bh * U_ + q];
    const float* cp = corr + ((size_t)bh * U_ + q) * 64;
    float delta = 0.f;
#pragma unroll
    for (int r = 0; r < 64; ++r)
        delta = fmaf(cp[r], Wo[(size_t)(h * 64 + r) * 512 + d], delta);
    atomicAdd(&out[((size_t)b * S_ + s) * 512 + d], delta);
}

// ---------------------------------------------------------------------------
extern "C" void kernel_launch(void* const* d_in, const int* in_sizes, int n_in,
                              void* d_out, int out_size, void* d_ws, size_t ws_size,
                              hipStream_t stream)
{
    const float* X  = (const float*)d_in[0];
    const float* Wq = (const float*)d_in[1];
    const float* bq = (const float*)d_in[2];
    const float* Wk = (const float*)d_in[3];
    const float* bk = (const float*)d_in[4];
    const float* Wv = (const float*)d_in[5];
    const float* bv = (const float*)d_in[6];
    const float* Wo = (const float*)d_in[7];
    const float* bo = (const float*)d_in[8];
    float* out = (float*)d_out;

    char* ws = (char*)d_ws;
    size_t off = 0;
    auto alloc = [&](size_t bytes) {
        void* p = ws + off;
        off = (off + bytes + 255) & ~(size_t)255;
        return p;
    };
    unsigned short* Kbuf = (unsigned short*)alloc((size_t)B_ * S_ * D_ * 2);
    unsigned short* Vbuf = (unsigned short*)alloc((size_t)B_ * S_ * D_ * 2);
    float* sparsity = (float*)alloc((size_t)B_ * H_ * S_ * 4);
    int*   topidx   = (int*)alloc((size_t)B_ * H_ * U_ * 4);
    float* selq     = (float*)alloc((size_t)B_ * H_ * U_ * 64 * 4);
    float* pm       = (float*)alloc((size_t)B_ * H_ * NCHUNK * U_ * 4);
    float* pl       = (float*)alloc((size_t)B_ * H_ * NCHUNK * U_ * 4);
    float* pacc     = (float*)alloc((size_t)B_ * H_ * NCHUNK * U_ * 64 * 4);
    float* corr     = (float*)alloc((size_t)B_ * H_ * U_ * 64 * 4);
    float* vsum     = (float*)alloc((size_t)B_ * H_ * 64 * 4);
    float* outbase  = (float*)alloc((size_t)B_ * 512 * 4);

    qkv_gemm<<<dim3(512, 24), 256, 0, stream>>>(X, Wq, bq, Wk, bk, Wv, bv,
                                                Kbuf, Vbuf, sparsity);
    vsum_kernel<<<B_ * H_, 256, 0, stream>>>(Vbuf, vsum);
    topk_kernel<<<B_ * H_, 256, 0, stream>>>(sparsity, topidx);
    selq_kernel<<<dim3(U_, B_ * H_), 64, 0, stream>>>(X, Wq, bq, topidx, selq);
    attn_partial<<<dim3(NCHUNK, B_ * H_), 256, 0, stream>>>(Kbuf, Vbuf, selq,
                                                            pm, pl, pacc);
    attn_combine<<<dim3(U_, B_ * H_), 64, 0, stream>>>(pm, pl, pacc, vsum, corr);
    outbase_kernel<<<B_, 512, 0, stream>>>(vsum, Wo, bo, outbase);
    fill_kernel<<<(B_ * S_ * D_ / 4 + 255) / 256, 256, 0, stream>>>(outbase, out);
    correction_kernel<<<dim3(U_, B_ * H_), 512, 0, stream>>>(corr, Wo, topidx, out);
}

// Round 2
// 631.667 us; speedup vs baseline: 2.6389x; 2.6389x over previous
//
#include <hip/hip_runtime.h>
#include <math.h>

#define B_ 4
#define S_ 8192
#define D_ 512
#define H_ 8
#define U_ 45            // int(5*ln(8193)) = 45
#define NCHUNK 32
#define CH 256           // keys per attention block

typedef unsigned short ushortT;
typedef __attribute__((ext_vector_type(8))) short short8;
typedef __attribute__((ext_vector_type(4))) float f32x4;

__device__ __forceinline__ float bfbits2f(unsigned short v) {
    unsigned u = ((unsigned)v) << 16;
    return __uint_as_float(u);
}
__device__ __forceinline__ unsigned short f2bf(float f) {
    unsigned u = __float_as_uint(f);
    unsigned r = u + 0x7fffu + ((u >> 16) & 1u);   // RNE
    return (unsigned short)(r >> 16);
}

__device__ __forceinline__ void gload_lds16(const ushortT* g, ushortT* l) {
    __builtin_amdgcn_global_load_lds(
        (const __attribute__((address_space(1))) void*)g,
        (__attribute__((address_space(3))) void*)l,
        16, 0, 0);
}

// ---------------------------------------------------------------------------
// Pre-pass 1: split X (fp32) into bf16 hi + bf16 lo residual.
// ---------------------------------------------------------------------------
__global__ __launch_bounds__(256) void split_x(
    const float* __restrict__ X, ushortT* __restrict__ Xh, ushortT* __restrict__ Xl)
{
    size_t i = ((size_t)blockIdx.x * 256 + threadIdx.x) * 8;
    float4 a = *(const float4*)(X + i);
    float4 b = *(const float4*)(X + i + 4);
    float v[8] = {a.x, a.y, a.z, a.w, b.x, b.y, b.z, b.w};
    ushort4 h0, h1, l0, l1;
    ushortT h[8], l[8];
#pragma unroll
    for (int j = 0; j < 8; ++j) {
        h[j] = f2bf(v[j]);
        l[j] = f2bf(v[j] - bfbits2f(h[j]));
    }
    h0 = make_ushort4(h[0], h[1], h[2], h[3]);
    h1 = make_ushort4(h[4], h[5], h[6], h[7]);
    l0 = make_ushort4(l[0], l[1], l[2], l[3]);
    l1 = make_ushort4(l[4], l[5], l[6], l[7]);
    *(ushort4*)(Xh + i) = h0; *(ushort4*)(Xh + i + 4) = h1;
    *(ushort4*)(Xl + i) = l0; *(ushort4*)(Xl + i + 4) = l1;
}

// ---------------------------------------------------------------------------
// Pre-pass 2: transpose + bf16-convert weights.  WT[n][k] = W[k][n].
// z=0: Wq -> WqhT + WqlT (hi/lo).  z=1: Wk -> WkT.  z=2: Wv -> WvT.
// ---------------------------------------------------------------------------
__global__ __launch_bounds__(256) void wprep(
    const float* __restrict__ Wq, const float* __restrict__ Wk,
    const float* __restrict__ Wv,
    ushortT* __restrict__ WqhT, ushortT* __restrict__ WqlT,
    ushortT* __restrict__ WkT,  ushortT* __restrict__ WvT)
{
    __shared__ float t[32][33];
    const int z = blockIdx.z;
    const float* W = (z == 0) ? Wq : (z == 1) ? Wk : Wv;
    const int tx = threadIdx.x & 31, ty4 = (threadIdx.x >> 5) * 4;
    const int r0 = blockIdx.y * 32, c0 = blockIdx.x * 32;
#pragma unroll
    for (int i = 0; i < 4; ++i)
        t[ty4 + i][tx] = W[(size_t)(r0 + ty4 + i) * 512 + c0 + tx];
    __syncthreads();
#pragma unroll
    for (int i = 0; i < 4; ++i) {
        float v = t[tx][ty4 + i];                       // = W[r0+tx][c0+ty4+i]
        size_t oidx = (size_t)(c0 + ty4 + i) * 512 + r0 + tx;
        if (z == 0) {
            ushortT h = f2bf(v);
            WqhT[oidx] = h;
            WqlT[oidx] = f2bf(v - bfbits2f(h));
        } else if (z == 1) {
            WkT[oidx] = f2bf(v);
        } else {
            WvT[oidx] = f2bf(v);
        }
    }
}

// ---------------------------------------------------------------------------
// MFMA QKV projection.  grid (256 m-tiles, 12): y 0-3 Q, 4-7 K, 8-11 V.
// 128x128 tile, BK=32, 4 waves in 2x2, each wave 64x64 (4x4 MFMA tiles).
// Q: split-bf16 3-term product -> sparsity (sum q^2 per head) plain stores.
// K/V: bf16 product -> bf16 buffers; V also accumulates column sums (vsum).
// ---------------------------------------------------------------------------
__global__ __launch_bounds__(256, 2) void qkv_mfma(
    const ushortT* __restrict__ Xh, const ushortT* __restrict__ Xl,
    const ushortT* __restrict__ WqhT, const ushortT* __restrict__ WqlT,
    const ushortT* __restrict__ WkT,  const ushortT* __restrict__ WvT,
    const float* __restrict__ bq, const float* __restrict__ bk,
    const float* __restrict__ bv,
    ushortT* __restrict__ Kbuf, ushortT* __restrict__ Vbuf,
    float* __restrict__ sparsity, float* __restrict__ vsum)
{
    __shared__ ushortT lds[4 * 128 * 32];   // Ah | Bh | Al | Bl, 8KB each
    ushortT* Ah = lds;
    ushortT* Bh = lds + 4096;
    ushortT* Al = lds + 8192;
    ushortT* Bl = lds + 12288;

    const int tid  = threadIdx.x;
    const int w    = tid >> 6, lane = tid & 63;
    const int quad = lane >> 4, c16 = lane & 15;
    const int wr   = w >> 1,  wc  = w & 1;
    const int mat  = blockIdx.y >> 2;        // 0=Q 1=K 2=V
    const int nt   = blockIdx.y & 3;
    const int m0   = blockIdx.x * 128;
    const int n0   = nt * 128;

    const int srow   = lane >> 2;            // staging row within 16-row chunk
    const int schunk = (lane & 3) * 8;       // ushort offset (16B chunks)

    f32x4 acc[4][4];
#pragma unroll
    for (int i = 0; i < 4; ++i)
#pragma unroll
        for (int j = 0; j < 4; ++j) acc[i][j] = (f32x4){0.f, 0.f, 0.f, 0.f};

    if (mat == 0) {
        for (int k0 = 0; k0 < 512; k0 += 32) {
            __syncthreads();
#pragma unroll
            for (int c = 0; c < 2; ++c) {
                const int row = w * 32 + c * 16 + srow;
                const int lbase = (w * 32 + c * 16) * 32;
                gload_lds16(Xh   + (size_t)(m0 + row) * 512 + k0 + schunk, Ah + lbase);
                gload_lds16(Xl   + (size_t)(m0 + row) * 512 + k0 + schunk, Al + lbase);
                gload_lds16(WqhT + (size_t)(n0 + row) * 512 + k0 + schunk, Bh + lbase);
                gload_lds16(WqlT + (size_t)(n0 + row) * 512 + k0 + schunk, Bl + lbase);
            }
            __syncthreads();
            short8 ah[4], al[4], bhf[4], blf[4];
#pragma unroll
            for (int i = 0; i < 4; ++i) {
                ah[i]  = *(const short8*)&Ah[(wr * 64 + i * 16 + c16) * 32 + quad * 8];
                al[i]  = *(const short8*)&Al[(wr * 64 + i * 16 + c16) * 32 + quad * 8];
                bhf[i] = *(const short8*)&Bh[(wc * 64 + i * 16 + c16) * 32 + quad * 8];
                blf[i] = *(const short8*)&Bl[(wc * 64 + i * 16 + c16) * 32 + quad * 8];
            }
#pragma unroll
            for (int i = 0; i < 4; ++i)
#pragma unroll
                for (int j = 0; j < 4; ++j) {
                    acc[i][j] = __builtin_amdgcn_mfma_f32_16x16x32_bf16(ah[i], bhf[j], acc[i][j], 0, 0, 0);
                    acc[i][j] = __builtin_amdgcn_mfma_f32_16x16x32_bf16(ah[i], blf[j], acc[i][j], 0, 0, 0);
                    acc[i][j] = __builtin_amdgcn_mfma_f32_16x16x32_bf16(al[i], bhf[j], acc[i][j], 0, 0, 0);
                }
        }
    } else {
        const ushortT* Bg = (mat == 1) ? WkT : WvT;
        for (int k0 = 0; k0 < 512; k0 += 32) {
            __syncthreads();
#pragma unroll
            for (int c = 0; c < 2; ++c) {
                const int row = w * 32 + c * 16 + srow;
                const int lbase = (w * 32 + c * 16) * 32;
                gload_lds16(Xh + (size_t)(m0 + row) * 512 + k0 + schunk, Ah + lbase);
                gload_lds16(Bg + (size_t)(n0 + row) * 512 + k0 + schunk, Bh + lbase);
            }
            __syncthreads();
            short8 af[4], bf[4];
#pragma unroll
            for (int i = 0; i < 4; ++i) {
                af[i] = *(const short8*)&Ah[(wr * 64 + i * 16 + c16) * 32 + quad * 8];
                bf[i] = *(const short8*)&Bh[(wc * 64 + i * 16 + c16) * 32 + quad * 8];
            }
#pragma unroll
            for (int i = 0; i < 4; ++i)
#pragma unroll
                for (int j = 0; j < 4; ++j)
                    acc[i][j] = __builtin_amdgcn_mfma_f32_16x16x32_bf16(af[i], bf[j], acc[i][j], 0, 0, 0);
        }
    }

    // ---- epilogue ----
    const int b = m0 >> 13;                   // m0 / 8192
    const int srow0 = (m0 & 8191) + wr * 64;  // sequence row base for this wave

    if (mat == 0) {
        float bb[4];
#pragma unroll
        for (int j = 0; j < 4; ++j) bb[j] = bq[n0 + wc * 64 + j * 16 + c16];
        const int head = (n0 + wc * 64) >> 6;
#pragma unroll
        for (int i = 0; i < 4; ++i)
#pragma unroll
            for (int r = 0; r < 4; ++r) {
                float p = 0.f;
#pragma unroll
                for (int j = 0; j < 4; ++j) {
                    float v = acc[i][j][r] + bb[j];
                    p = fmaf(v, v, p);
                }
                p += __shfl_xor(p, 1);
                p += __shfl_xor(p, 2);
                p += __shfl_xor(p, 4);
                p += __shfl_xor(p, 8);
                if (c16 == 0) {
                    int s = srow0 + i * 16 + quad * 4 + r;
                    sparsity[((size_t)b * H_ + head) * S_ + s] = p;
                }
            }
    } else {
        ushortT* Obuf = (mat == 1) ? Kbuf : Vbuf;
        const float* bias = (mat == 1) ? bk : bv;
        float bb[4];
        int gc[4];
#pragma unroll
        for (int j = 0; j < 4; ++j) {
            gc[j] = n0 + wc * 64 + j * 16 + c16;
            bb[j] = bias[gc[j]];
        }
        float vs[4] = {0.f, 0.f, 0.f, 0.f};
#pragma unroll
        for (int i = 0; i < 4; ++i)
#pragma unroll
            for (int r = 0; r < 4; ++r) {
                const int grow = m0 + wr * 64 + i * 16 + quad * 4 + r;
#pragma unroll
                for (int j = 0; j < 4; ++j) {
                    float v = acc[i][j][r] + bb[j];
                    Obuf[(size_t)grow * 512 + gc[j]] = f2bf(v);
                    vs[j] += v;
                }
            }
        if (mat == 2) {
#pragma unroll
            for (int j = 0; j < 4; ++j) {
                vs[j] += __shfl_xor(vs[j], 16);
                vs[j] += __shfl_xor(vs[j], 32);
            }
            if (lane < 16)
#pragma unroll
                for (int j = 0; j < 4; ++j)
                    atomicAdd(&vsum[b * 512 + gc[j]], vs[j]);
        }
    }
}

// ---------------------------------------------------------------------------
// Top-45 per (b,h) by iterative argmax (stable: smaller index wins ties)
// ---------------------------------------------------------------------------
__global__ __launch_bounds__(256) void topk_kernel(
    const float* __restrict__ sparsity, int* __restrict__ topidx)
{
    __shared__ float vals[S_];
    __shared__ float rmax[256];
    __shared__ int   ridx[256];
    const int bh = blockIdx.x, tid = threadIdx.x;
    const float* sp = sparsity + (size_t)bh * S_;
    for (int i = tid; i < S_; i += 256) vals[i] = sp[i];
    __syncthreads();
    for (int it = 0; it < U_; ++it) {
        float bm = -INFINITY; int bi = S_;
        for (int i = tid; i < S_; i += 256) {
            float v = vals[i];
            if (v > bm) { bm = v; bi = i; }
        }
        rmax[tid] = bm; ridx[tid] = bi;
        __syncthreads();
        for (int off = 128; off > 0; off >>= 1) {
            if (tid < off) {
                float ov = rmax[tid + off]; int oi = ridx[tid + off];
                if (ov > rmax[tid] || (ov == rmax[tid] && oi < ridx[tid])) {
                    rmax[tid] = ov; ridx[tid] = oi;
                }
            }
            __syncthreads();
        }
        if (tid == 0) {
            topidx[bh * U_ + it] = ridx[0];
            vals[ridx[0]] = -INFINITY;
        }
        __syncthreads();
    }
}

// ---------------------------------------------------------------------------
// Recompute selected Q rows exactly in fp32: selq[bh][q][64]
// ---------------------------------------------------------------------------
__global__ __launch_bounds__(64) void selq_kernel(
    const float* __restrict__ X, const float* __restrict__ Wq,
    const float* __restrict__ bq, const int* __restrict__ topidx,
    float* __restrict__ selq)
{
    const int q = blockIdx.x, bh = blockIdx.y;
    const int b = bh >> 3, h = bh & 7, d = threadIdx.x;
    const int s = topidx[bh * U_ + q];
    const float* xr = X + ((size_t)b * S_ + s) * 512;
    const float* wp = Wq + h * 64 + d;
    float acc = bq[h * 64 + d];
    for (int r = 0; r < 512; ++r)
        acc = fmaf(xr[r], wp[(size_t)r * 512], acc);
    selq[((size_t)bh * U_ + q) * 64 + d] = acc;
}

// ---------------------------------------------------------------------------
// Attention partials: per (bh, chunk of 256 keys):
//   scores -> chunk softmax stats (m,l) -> unnormalized P -> P@V partial acc
// ---------------------------------------------------------------------------
__global__ __launch_bounds__(256) void attn_partial(
    const unsigned short* __restrict__ Kbuf,
    const unsigned short* __restrict__ Vbuf,
    const float* __restrict__ selq,
    float* __restrict__ pm, float* __restrict__ pl, float* __restrict__ pacc)
{
    __shared__ float qs[U_ * 64];   // 11.25 KB
    __shared__ float sc[U_][CH];    // 45 KB
    const int tid = threadIdx.x;
    const int chunk = blockIdx.x;
    const int bh = blockIdx.y, b = bh >> 3, h = bh & 7;
    const int s0 = chunk * CH;

    for (int i = tid; i < U_ * 64; i += 256)
        qs[i] = selq[(size_t)bh * U_ * 64 + i];
    __syncthreads();

    // Phase A: one key per thread, scores for all 45 queries
    {
        const unsigned short* kp = Kbuf + (size_t)(b * S_ + s0 + tid) * 512 + h * 64;
        float kreg[64];
        const uint4* kp4 = (const uint4*)kp;
#pragma unroll
        for (int i = 0; i < 8; ++i) {
            uint4 u = kp4[i];
            unsigned w[4] = {u.x, u.y, u.z, u.w};
#pragma unroll
            for (int j = 0; j < 4; ++j) {
                kreg[i * 8 + j * 2 + 0] = bfbits2f((unsigned short)(w[j] & 0xffffu));
                kreg[i * 8 + j * 2 + 1] = bfbits2f((unsigned short)(w[j] >> 16));
            }
        }
        for (int q = 0; q < U_; ++q) {
            float a = 0.f;
#pragma unroll
            for (int d4 = 0; d4 < 16; ++d4) {
                float4 qv = *(const float4*)&qs[q * 64 + d4 * 4];
                a = fmaf(qv.x, kreg[d4 * 4 + 0], a);
                a = fmaf(qv.y, kreg[d4 * 4 + 1], a);
                a = fmaf(qv.z, kreg[d4 * 4 + 2], a);
                a = fmaf(qv.w, kreg[d4 * 4 + 3], a);
            }
            sc[q][tid] = a * 0.125f;
        }
    }
    __syncthreads();

    // Phase B: wave per query: max, exp, sum (unnormalized weights left in sc)
    {
        const int wid = tid >> 6, lane = tid & 63;
        for (int q = wid; q < U_; q += 4) {
            float m = -INFINITY;
#pragma unroll
            for (int r = 0; r < 4; ++r) m = fmaxf(m, sc[q][lane + r * 64]);
            for (int off = 32; off; off >>= 1) m = fmaxf(m, __shfl_xor(m, off));
            float l = 0.f;
#pragma unroll
            for (int r = 0; r < 4; ++r) {
                float p = __expf(sc[q][lane + r * 64] - m);
                sc[q][lane + r * 64] = p;
                l += p;
            }
            for (int off = 32; off; off >>= 1) l += __shfl_xor(l, off);
            if (lane == 0) {
                pm[((size_t)bh * NCHUNK + chunk) * U_ + q] = m;
                pl[((size_t)bh * NCHUNK + chunk) * U_ + q] = l;
            }
        }
    }
    __syncthreads();

    // Phase C: P[45xCH] @ V[CHx64], lane <-> d, 4 query groups
    {
        const int d = tid & 63, qg = tid >> 6;
        const unsigned short* vp = Vbuf + (size_t)(b * S_ + s0) * 512 + h * 64 + d;
        float facc[12] = {};
        for (int s4 = 0; s4 < CH; s4 += 4) {
            float v0 = bfbits2f(vp[(size_t)(s4 + 0) * 512]);
            float v1 = bfbits2f(vp[(size_t)(s4 + 1) * 512]);
            float v2 = bfbits2f(vp[(size_t)(s4 + 2) * 512]);
            float v3 = bfbits2f(vp[(size_t)(s4 + 3) * 512]);
            int qi = 0;
            for (int q = qg; q < U_; q += 4, ++qi) {
                float4 w = *(const float4*)&sc[q][s4];
                facc[qi] = fmaf(w.x, v0, facc[qi]);
                facc[qi] = fmaf(w.y, v1, facc[qi]);
                facc[qi] = fmaf(w.z, v2, facc[qi]);
                facc[qi] = fmaf(w.w, v3, facc[qi]);
            }
        }
        int qi = 0;
        for (int q = qg; q < U_; q += 4, ++qi)
            pacc[(((size_t)bh * NCHUNK + chunk) * U_ + q) * 64 + d] = facc[qi];
    }
}

// ---------------------------------------------------------------------------
// Combine chunk partials -> correction vector (sel_ctx - mean_v)
// ---------------------------------------------------------------------------
__global__ __launch_bounds__(64) void attn_combine(
    const float* __restrict__ pm, const float* __restrict__ pl,
    const float* __restrict__ pacc, const float* __restrict__ vsum,
    float* __restrict__ corr)
{
    const int q = blockIdx.x, bh = blockIdx.y, d = threadIdx.x;
    float M = -INFINITY;
    for (int c = 0; c < NCHUNK; ++c)
        M = fmaxf(M, pm[((size_t)bh * NCHUNK + c) * U_ + q]);
    float L = 0.f, a = 0.f;
    for (int c = 0; c < NCHUNK; ++c) {
        float mc = pm[((size_t)bh * NCHUNK + c) * U_ + q];
        float lc = pl[((size_t)bh * NCHUNK + c) * U_ + q];
        float f = __expf(mc - M);
        L = fmaf(lc, f, L);
        a = fmaf(f, pacc[(((size_t)bh * NCHUNK + c) * U_ + q) * 64 + d], a);
    }
    corr[((size_t)bh * U_ + q) * 64 + d] = a / L - vsum[bh * 64 + d] * (1.0f / S_);
}

// ---------------------------------------------------------------------------
// out_base[b][512] = bo + mean_flat[b] @ Wo
// ---------------------------------------------------------------------------
__global__ __launch_bounds__(512) void outbase_kernel(
    const float* __restrict__ vsum, const float* __restrict__ Wo,
    const float* __restrict__ bo, float* __restrict__ outbase)
{
    const int b = blockIdx.x, d = threadIdx.x;
    float acc = bo[d];
    for (int r = 0; r < 512; ++r) {
        float mv = vsum[b * 512 + r] * (1.0f / S_);
        acc = fmaf(mv, Wo[(size_t)r * 512 + d], acc);
    }
    outbase[b * 512 + d] = acc;
}

// ---------------------------------------------------------------------------
// Broadcast fill: out[b,s,:] = out_base[b,:]
// ---------------------------------------------------------------------------
__global__ __launch_bounds__(256) void fill_kernel(
    const float* __restrict__ outbase, float* __restrict__ out)
{
    size_t gid = (size_t)blockIdx.x * 256 + threadIdx.x;
    size_t e0 = gid * 4;
    int b = (int)(e0 >> 22);          // 8192*512 = 2^22
    int col = (int)(e0 & 511);
    float4 v = *(const float4*)&outbase[b * 512 + col];
    *(float4*)&out[e0] = v;
}

// ---------------------------------------------------------------------------
// Rank-64 corrections: out[b, s_q, :] += corr[bh][q] @ Wo_h
// ---------------------------------------------------------------------------
__global__ __launch_bounds__(512) void correction_kernel(
    const float* __restrict__ corr, const float* __restrict__ Wo,
    const int* __restrict__ topidx, float* __restrict__ out)
{
    const int q = blockIdx.x, bh = blockIdx.y;
    const int b = bh >> 3, h = bh & 7, d = threadIdx.x;
    const int s = topidx[bh * U_ + q];
    const float* cp = corr + ((size_t)bh * U_ + q) * 64;
    float delta = 0.f;
#pragma unroll
    for (int r = 0; r < 64; ++r)
        delta = fmaf(cp[r], Wo[(size_t)(h * 64 + r) * 512 + d], delta);
    atomicAdd(&out[((size_t)b * S_ + s) * 512 + d], delta);
}

// ---------------------------------------------------------------------------
extern "C" void kernel_launch(void* const* d_in, const int* in_sizes, int n_in,
                              void* d_out, int out_size, void* d_ws, size_t ws_size,
                              hipStream_t stream)
{
    const float* X  = (const float*)d_in[0];
    const float* Wq = (const float*)d_in[1];
    const float* bq = (const float*)d_in[2];
    const float* Wk = (const float*)d_in[3];
    const float* bk = (const float*)d_in[4];
    const float* Wv = (const float*)d_in[5];
    const float* bv = (const float*)d_in[6];
    const float* Wo = (const float*)d_in[7];
    const float* bo = (const float*)d_in[8];
    float* out = (float*)d_out;

    char* ws = (char*)d_ws;
    size_t off = 0;
    auto alloc = [&](size_t bytes) {
        void* p = ws + off;
        off = (off + bytes + 255) & ~(size_t)255;
        return p;
    };
    ushortT* Xh   = (ushortT*)alloc((size_t)B_ * S_ * D_ * 2);
    ushortT* Xl   = (ushortT*)alloc((size_t)B_ * S_ * D_ * 2);
    ushortT* Kbuf = (ushortT*)alloc((size_t)B_ * S_ * D_ * 2);
    ushortT* Vbuf = (ushortT*)alloc((size_t)B_ * S_ * D_ * 2);
    ushortT* WqhT = (ushortT*)alloc((size_t)D_ * D_ * 2);
    ushortT* WqlT = (ushortT*)alloc((size_t)D_ * D_ * 2);
    ushortT* WkT  = (ushortT*)alloc((size_t)D_ * D_ * 2);
    ushortT* WvT  = (ushortT*)alloc((size_t)D_ * D_ * 2);
    float* sparsity = (float*)alloc((size_t)B_ * H_ * S_ * 4);
    int*   topidx   = (int*)alloc((size_t)B_ * H_ * U_ * 4);
    float* selq     = (float*)alloc((size_t)B_ * H_ * U_ * 64 * 4);
    float* pm       = (float*)alloc((size_t)B_ * H_ * NCHUNK * U_ * 4);
    float* pl       = (float*)alloc((size_t)B_ * H_ * NCHUNK * U_ * 4);
    float* pacc     = (float*)alloc((size_t)B_ * H_ * NCHUNK * U_ * 64 * 4);
    float* corr     = (float*)alloc((size_t)B_ * H_ * U_ * 64 * 4);
    float* vsum     = (float*)alloc((size_t)B_ * 512 * 4);
    float* outbase  = (float*)alloc((size_t)B_ * 512 * 4);

    hipMemsetAsync(vsum, 0, (size_t)B_ * 512 * 4, stream);

    split_x<<<(B_ * S_ * D_) / (256 * 8), 256, 0, stream>>>(X, Xh, Xl);
    wprep<<<dim3(16, 16, 3), 256, 0, stream>>>(Wq, Wk, Wv, WqhT, WqlT, WkT, WvT);
    qkv_mfma<<<dim3(256, 12), 256, 0, stream>>>(Xh, Xl, WqhT, WqlT, WkT, WvT,
                                                bq, bk, bv, Kbuf, Vbuf,
                                                sparsity, vsum);
    topk_kernel<<<B_ * H_, 256, 0, stream>>>(sparsity, topidx);
    selq_kernel<<<dim3(U_, B_ * H_), 64, 0, stream>>>(X, Wq, bq, topidx, selq);
    attn_partial<<<dim3(NCHUNK, B_ * H_), 256, 0, stream>>>(Kbuf, Vbuf, selq,
                                                            pm, pl, pacc);
    attn_combine<<<dim3(U_, B_ * H_), 64, 0, stream>>>(pm, pl, pacc, vsum, corr);
    outbase_kernel<<<B_, 512, 0, stream>>>(vsum, Wo, bo, outbase);
    fill_kernel<<<(B_ * S_ * D_ / 4 + 255) / 256, 256, 0, stream>>>(outbase, out);
    correction_kernel<<<dim3(U_, B_ * H_), 512, 0, stream>>>(corr, Wo, topidx, out);
}

// Round 3
// 483.868 us; speedup vs baseline: 3.4449x; 1.3055x over previous
//
#include <hip/hip_runtime.h>
#include <math.h>

#define B_ 4
#define S_ 8192
#define D_ 512
#define H_ 8
#define U_ 45            // int(5*ln(8193)) = 45
#define NCHUNK 16        // 512 keys per attention block

typedef unsigned short ushortT;
typedef __attribute__((ext_vector_type(8))) short short8;
typedef __attribute__((ext_vector_type(4))) float f32x4;

__device__ __forceinline__ float bfbits2f(unsigned short v) {
    unsigned u = ((unsigned)v) << 16;
    return __uint_as_float(u);
}
__device__ __forceinline__ unsigned short f2bf(float f) {
    unsigned u = __float_as_uint(f);
    unsigned r = u + 0x7fffu + ((u >> 16) & 1u);   // RNE
    return (unsigned short)(r >> 16);
}

__device__ __forceinline__ void gload_lds16(const ushortT* g, ushortT* l) {
    __builtin_amdgcn_global_load_lds(
        (const __attribute__((address_space(1))) void*)g,
        (__attribute__((address_space(3))) void*)l,
        16, 0, 0);
}

// ---------------------------------------------------------------------------
// Pre-pass 1: split X (fp32) into bf16 hi + bf16 lo residual.
// ---------------------------------------------------------------------------
__global__ __launch_bounds__(256) void split_x(
    const float* __restrict__ X, ushortT* __restrict__ Xh, ushortT* __restrict__ Xl)
{
    size_t i = ((size_t)blockIdx.x * 256 + threadIdx.x) * 8;
    float4 a = *(const float4*)(X + i);
    float4 b = *(const float4*)(X + i + 4);
    float v[8] = {a.x, a.y, a.z, a.w, b.x, b.y, b.z, b.w};
    ushortT h[8], l[8];
#pragma unroll
    for (int j = 0; j < 8; ++j) {
        h[j] = f2bf(v[j]);
        l[j] = f2bf(v[j] - bfbits2f(h[j]));
    }
    *(ushort4*)(Xh + i)     = make_ushort4(h[0], h[1], h[2], h[3]);
    *(ushort4*)(Xh + i + 4) = make_ushort4(h[4], h[5], h[6], h[7]);
    *(ushort4*)(Xl + i)     = make_ushort4(l[0], l[1], l[2], l[3]);
    *(ushort4*)(Xl + i + 4) = make_ushort4(l[4], l[5], l[6], l[7]);
}

// ---------------------------------------------------------------------------
// Pre-pass 2: transpose + bf16-convert weights.  WT[n][k] = W[k][n].
// ---------------------------------------------------------------------------
__global__ __launch_bounds__(256) void wprep(
    const float* __restrict__ Wq, const float* __restrict__ Wk,
    const float* __restrict__ Wv,
    ushortT* __restrict__ WqhT, ushortT* __restrict__ WqlT,
    ushortT* __restrict__ WkT,  ushortT* __restrict__ WvT)
{
    __shared__ float t[32][33];
    const int z = blockIdx.z;
    const float* W = (z == 0) ? Wq : (z == 1) ? Wk : Wv;
    const int tx = threadIdx.x & 31, ty4 = (threadIdx.x >> 5) * 4;
    const int r0 = blockIdx.y * 32, c0 = blockIdx.x * 32;
#pragma unroll
    for (int i = 0; i < 4; ++i)
        t[ty4 + i][tx] = W[(size_t)(r0 + ty4 + i) * 512 + c0 + tx];
    __syncthreads();
#pragma unroll
    for (int i = 0; i < 4; ++i) {
        float v = t[tx][ty4 + i];                       // = W[r0+tx][c0+ty4+i]
        size_t oidx = (size_t)(c0 + ty4 + i) * 512 + r0 + tx;
        if (z == 0) {
            ushortT h = f2bf(v);
            WqhT[oidx] = h;
            WqlT[oidx] = f2bf(v - bfbits2f(h));
        } else if (z == 1) {
            WkT[oidx] = f2bf(v);
        } else {
            WvT[oidx] = f2bf(v);
        }
    }
}

// ---------------------------------------------------------------------------
// MFMA QKV projection.  grid (256, 12): y 0-3 Q n-tiles, 4-7 K n-tiles,
// 8-11 V column-tiles.  128x128 tile, BK=32, 4 waves 2x2, wave = 64x64.
// Q: split-bf16 3-term -> sparsity (sum q^2).  K -> head-major [bh][s][64].
// V: computed TRANSPOSED (A=WvT, B=Xh) -> VT [bh][64][8192]; vsum folded in.
// ---------------------------------------------------------------------------
__global__ __launch_bounds__(256, 2) void qkv_mfma(
    const ushortT* __restrict__ Xh, const ushortT* __restrict__ Xl,
    const ushortT* __restrict__ WqhT, const ushortT* __restrict__ WqlT,
    const ushortT* __restrict__ WkT,  const ushortT* __restrict__ WvT,
    const float* __restrict__ bq, const float* __restrict__ bk,
    const float* __restrict__ bv,
    ushortT* __restrict__ Kbuf, ushortT* __restrict__ VT,
    float* __restrict__ sparsity, float* __restrict__ vsum)
{
    __shared__ ushortT lds[4 * 128 * 32];   // Ah | Bh | Al | Bl, 8KB each
    ushortT* Ah = lds;
    ushortT* Bh = lds + 4096;
    ushortT* Al = lds + 8192;
    ushortT* Bl = lds + 12288;

    const int tid  = threadIdx.x;
    const int w    = tid >> 6, lane = tid & 63;
    const int quad = lane >> 4, c16 = lane & 15;
    const int wr   = w >> 1,  wc  = w & 1;
    const int mat  = blockIdx.y >> 2;        // 0=Q 1=K 2=V
    const int nt   = blockIdx.y & 3;
    const int m0   = blockIdx.x * 128;
    const int n0   = nt * 128;

    const int srow   = lane >> 2;            // staging row within 16-row chunk
    const int schunk = (lane & 3) * 8;       // ushort offset (16B chunks)

    f32x4 acc[4][4];
#pragma unroll
    for (int i = 0; i < 4; ++i)
#pragma unroll
        for (int j = 0; j < 4; ++j) acc[i][j] = (f32x4){0.f, 0.f, 0.f, 0.f};

    if (mat == 0) {
        for (int k0 = 0; k0 < 512; k0 += 32) {
            __syncthreads();
#pragma unroll
            for (int c = 0; c < 2; ++c) {
                const int row = w * 32 + c * 16 + srow;
                const int lbase = (w * 32 + c * 16) * 32;
                gload_lds16(Xh   + (size_t)(m0 + row) * 512 + k0 + schunk, Ah + lbase);
                gload_lds16(Xl   + (size_t)(m0 + row) * 512 + k0 + schunk, Al + lbase);
                gload_lds16(WqhT + (size_t)(n0 + row) * 512 + k0 + schunk, Bh + lbase);
                gload_lds16(WqlT + (size_t)(n0 + row) * 512 + k0 + schunk, Bl + lbase);
            }
            __syncthreads();
            short8 ah[4], al[4], bhf[4], blf[4];
#pragma unroll
            for (int i = 0; i < 4; ++i) {
                ah[i]  = *(const short8*)&Ah[(wr * 64 + i * 16 + c16) * 32 + quad * 8];
                al[i]  = *(const short8*)&Al[(wr * 64 + i * 16 + c16) * 32 + quad * 8];
                bhf[i] = *(const short8*)&Bh[(wc * 64 + i * 16 + c16) * 32 + quad * 8];
                blf[i] = *(const short8*)&Bl[(wc * 64 + i * 16 + c16) * 32 + quad * 8];
            }
#pragma unroll
            for (int i = 0; i < 4; ++i)
#pragma unroll
                for (int j = 0; j < 4; ++j) {
                    acc[i][j] = __builtin_amdgcn_mfma_f32_16x16x32_bf16(ah[i], bhf[j], acc[i][j], 0, 0, 0);
                    acc[i][j] = __builtin_amdgcn_mfma_f32_16x16x32_bf16(ah[i], blf[j], acc[i][j], 0, 0, 0);
                    acc[i][j] = __builtin_amdgcn_mfma_f32_16x16x32_bf16(al[i], bhf[j], acc[i][j], 0, 0, 0);
                }
        }
    } else {
        // mat1 (K): A = Xh rows m0+, B = WkT rows n0+   -> C[s][col]
        // mat2 (V): A = WvT rows n0+, B = Xh rows m0+   -> C^T[col][s]
        const ushortT* Ag = (mat == 1) ? Xh : WvT;
        const ushortT* Bg = (mat == 1) ? WkT : Xh;
        const int arow0 = (mat == 1) ? m0 : n0;
        const int brow0 = (mat == 1) ? n0 : m0;
        for (int k0 = 0; k0 < 512; k0 += 32) {
            __syncthreads();
#pragma unroll
            for (int c = 0; c < 2; ++c) {
                const int row = w * 32 + c * 16 + srow;
                const int lbase = (w * 32 + c * 16) * 32;
                gload_lds16(Ag + (size_t)(arow0 + row) * 512 + k0 + schunk, Ah + lbase);
                gload_lds16(Bg + (size_t)(brow0 + row) * 512 + k0 + schunk, Bh + lbase);
            }
            __syncthreads();
            short8 af[4], bf[4];
#pragma unroll
            for (int i = 0; i < 4; ++i) {
                af[i] = *(const short8*)&Ah[(wr * 64 + i * 16 + c16) * 32 + quad * 8];
                bf[i] = *(const short8*)&Bh[(wc * 64 + i * 16 + c16) * 32 + quad * 8];
            }
#pragma unroll
            for (int i = 0; i < 4; ++i)
#pragma unroll
                for (int j = 0; j < 4; ++j)
                    acc[i][j] = __builtin_amdgcn_mfma_f32_16x16x32_bf16(af[i], bf[j], acc[i][j], 0, 0, 0);
        }
    }

    // ---- epilogue ----
    if (mat == 0) {
        const int b = m0 >> 13;
        const int srow0 = (m0 & 8191) + wr * 64;
        float bb[4];
#pragma unroll
        for (int j = 0; j < 4; ++j) bb[j] = bq[n0 + wc * 64 + j * 16 + c16];
        const int head = (n0 + wc * 64) >> 6;
#pragma unroll
        for (int i = 0; i < 4; ++i)
#pragma unroll
            for (int r = 0; r < 4; ++r) {
                float p = 0.f;
#pragma unroll
                for (int j = 0; j < 4; ++j) {
                    float v = acc[i][j][r] + bb[j];
                    p = fmaf(v, v, p);
                }
                p += __shfl_xor(p, 1);
                p += __shfl_xor(p, 2);
                p += __shfl_xor(p, 4);
                p += __shfl_xor(p, 8);
                if (c16 == 0) {
                    int s = srow0 + i * 16 + quad * 4 + r;
                    sparsity[((size_t)b * H_ + head) * S_ + s] = p;
                }
            }
    } else if (mat == 1) {
        // K head-major: Kbuf[((b*8+head)*8192 + s)*64 + dd]
        const int b = m0 >> 13;
        const int head = (n0 + wc * 64) >> 6;     // uniform (j*16+c16 < 64)
        float bb[4];
#pragma unroll
        for (int j = 0; j < 4; ++j) bb[j] = bk[n0 + wc * 64 + j * 16 + c16];
        ushortT* kbase = Kbuf + ((size_t)(b * 8 + head) * 8192) * 64;
#pragma unroll
        for (int i = 0; i < 4; ++i)
#pragma unroll
            for (int r = 0; r < 4; ++r) {
                const int s = (m0 & 8191) + wr * 64 + i * 16 + quad * 4 + r;
#pragma unroll
                for (int j = 0; j < 4; ++j)
                    kbase[(size_t)s * 64 + j * 16 + c16] = f2bf(acc[i][j][r] + bb[j]);
            }
    } else {
        // V transposed: m-dim = column, n-dim = sequence row.
        // VT[((b*8+head)*64 + dd)*8192 + s]
        const int b = m0 >> 13;
        const int sbase = (m0 & 8191) + wc * 64;
#pragma unroll
        for (int i = 0; i < 4; ++i)
#pragma unroll
            for (int r = 0; r < 4; ++r) {
                const int dcol = n0 + wr * 64 + i * 16 + quad * 4 + r;
                const int head = dcol >> 6, dd = dcol & 63;
                const float biasv = bv[dcol];
                ushortT* vrow = VT + ((size_t)(b * 8 + head) * 64 + dd) * 8192;
                float vsa = 0.f;
#pragma unroll
                for (int j = 0; j < 4; ++j) {
                    float v = acc[i][j][r] + biasv;
                    vrow[sbase + j * 16 + c16] = f2bf(v);
                    vsa += v;
                }
                vsa += __shfl_xor(vsa, 1);
                vsa += __shfl_xor(vsa, 2);
                vsa += __shfl_xor(vsa, 4);
                vsa += __shfl_xor(vsa, 8);
                if (c16 == 0) atomicAdd(&vsum[b * 512 + dcol], vsa);
            }
    }
}

// ---------------------------------------------------------------------------
// Top-45 per (b,h) by iterative argmax (stable: smaller index wins ties)
// ---------------------------------------------------------------------------
__global__ __launch_bounds__(256) void topk_kernel(
    const float* __restrict__ sparsity, int* __restrict__ topidx)
{
    __shared__ float vals[S_];
    __shared__ float rmax[256];
    __shared__ int   ridx[256];
    const int bh = blockIdx.x, tid = threadIdx.x;
    const float* sp = sparsity + (size_t)bh * S_;
    for (int i = tid; i < S_; i += 256) vals[i] = sp[i];
    __syncthreads();
    for (int it = 0; it < U_; ++it) {
        float bm = -INFINITY; int bi = S_;
        for (int i = tid; i < S_; i += 256) {
            float v = vals[i];
            if (v > bm) { bm = v; bi = i; }
        }
        rmax[tid] = bm; ridx[tid] = bi;
        __syncthreads();
        for (int off = 128; off > 0; off >>= 1) {
            if (tid < off) {
                float ov = rmax[tid + off]; int oi = ridx[tid + off];
                if (ov > rmax[tid] || (ov == rmax[tid] && oi < ridx[tid])) {
                    rmax[tid] = ov; ridx[tid] = oi;
                }
            }
            __syncthreads();
        }
        if (tid == 0) {
            topidx[bh * U_ + it] = ridx[0];
            vals[ridx[0]] = -INFINITY;
        }
        __syncthreads();
    }
}

// ---------------------------------------------------------------------------
// Recompute selected Q rows exactly in fp32: selq[bh][q][64]
// ---------------------------------------------------------------------------
__global__ __launch_bounds__(64) void selq_kernel(
    const float* __restrict__ X, const float* __restrict__ Wq,
    const float* __restrict__ bq, const int* __restrict__ topidx,
    float* __restrict__ selq)
{
    const int q = blockIdx.x, bh = blockIdx.y;
    const int b = bh >> 3, h = bh & 7, d = threadIdx.x;
    const int s = topidx[bh * U_ + q];
    const float* xr = X + ((size_t)b * S_ + s) * 512;
    const float* wp = Wq + h * 64 + d;
    float acc = bq[h * 64 + d];
    for (int r = 0; r < 512; ++r)
        acc = fmaf(xr[r], wp[(size_t)r * 512], acc);
    selq[((size_t)bh * U_ + q) * 64 + d] = acc;
}

// ---------------------------------------------------------------------------
// Flash-style MFMA attention partials.  Grid (NCHUNK=16, 32 bh), 256 thr.
// Block = 512 keys, 4 inner chunks of 128.  K/VT read direct from global
// (line-coalesced fragment gathers).  Per chunk: QK mfma -> sc LDS ->
// per-row online softmax (m,l,alpha) -> P bf16 packed in-place in sc ->
// PV mfma with rescale.  Epilogue: pm/pl/pacc per (bh, chunk-block).
// ---------------------------------------------------------------------------
__global__ __launch_bounds__(256, 2) void attn_mfma(
    const ushortT* __restrict__ Kbuf, const ushortT* __restrict__ VT,
    const float* __restrict__ selq,
    float* __restrict__ pm, float* __restrict__ pl, float* __restrict__ pacc)
{
    __shared__ float sc[48 * 132];          // scores f32; P bf16 in-place
    __shared__ ushortT Qb[48 * 72];         // Q bf16, scale folded, padded
    __shared__ float mrun[48], lrun[48], alphaS[48];

    const int tid = threadIdx.x;
    const int w = tid >> 6, lane = tid & 63;
    const int quad = lane >> 4, c16 = lane & 15;
    const int bh = blockIdx.y;
    const int s_base = blockIdx.x * 512;

    // stage Q (scale 0.125 folded; exact: pow2 scale)
    for (int i = tid; i < 48 * 64; i += 256) {
        int q = i >> 6, d = i & 63;
        float v = (q < U_) ? selq[((size_t)bh * U_ + q) * 64 + d] * 0.125f : 0.f;
        Qb[q * 72 + d] = f2bf(v);
    }
    if (tid < 48) { mrun[tid] = -INFINITY; lrun[tid] = 0.f; }

    f32x4 O[3];
#pragma unroll
    for (int mt = 0; mt < 3; ++mt) O[mt] = (f32x4){0.f, 0.f, 0.f, 0.f};

    __syncthreads();

    // persistent Q A-frags
    short8 qa[3][2];
#pragma unroll
    for (int mt = 0; mt < 3; ++mt)
#pragma unroll
        for (int kk = 0; kk < 2; ++kk)
            qa[mt][kk] = *(const short8*)&Qb[(mt * 16 + c16) * 72 + kk * 32 + quad * 8];

    const ushortT* kb  = Kbuf + (size_t)bh * 8192 * 64;
    const ushortT* vtb = VT + ((size_t)bh * 64 + w * 16 + c16) * 8192;

    for (int ci = 0; ci < 4; ++ci) {
        const int s0 = s_base + ci * 128;

        // ---- QK^T: wave w owns keys [32w, 32w+32) ----
        short8 kf[2][2];
#pragma unroll
        for (int nt2 = 0; nt2 < 2; ++nt2)
#pragma unroll
            for (int kk = 0; kk < 2; ++kk)
                kf[nt2][kk] = *(const short8*)&kb[
                    (size_t)(s0 + w * 32 + nt2 * 16 + c16) * 64 + kk * 32 + quad * 8];
        f32x4 sacc[3][2];
#pragma unroll
        for (int mt = 0; mt < 3; ++mt)
#pragma unroll
            for (int nt2 = 0; nt2 < 2; ++nt2) {
                sacc[mt][nt2] = (f32x4){0.f, 0.f, 0.f, 0.f};
#pragma unroll
                for (int kk = 0; kk < 2; ++kk)
                    sacc[mt][nt2] = __builtin_amdgcn_mfma_f32_16x16x32_bf16(
                        qa[mt][kk], kf[nt2][kk], sacc[mt][nt2], 0, 0, 0);
            }
#pragma unroll
        for (int mt = 0; mt < 3; ++mt)
#pragma unroll
            for (int nt2 = 0; nt2 < 2; ++nt2)
#pragma unroll
                for (int r = 0; r < 4; ++r)
                    sc[(mt * 16 + quad * 4 + r) * 132 + w * 32 + nt2 * 16 + c16] =
                        sacc[mt][nt2][r];
        __syncthreads();

        // ---- prefetch VT B-frags (consumed after next barrier) ----
        short8 vb[4];
#pragma unroll
        for (int kk = 0; kk < 4; ++kk)
            vb[kk] = *(const short8*)&vtb[s0 + kk * 32 + quad * 8];

        // ---- online softmax: wave handles q rows [12w, 12w+12) ----
        for (int qi = 0; qi < 12; ++qi) {
            const int q = w * 12 + qi;
            float x0 = sc[q * 132 + lane];
            float x1 = sc[q * 132 + 64 + lane];
            float mx = fmaxf(x0, x1);
#pragma unroll
            for (int off = 1; off < 64; off <<= 1) mx = fmaxf(mx, __shfl_xor(mx, off));
            float mo = mrun[q];
            float mn = fmaxf(mo, mx);
            ushortT u0 = f2bf(__expf(x0 - mn));
            ushortT u1 = f2bf(__expf(x1 - mn));
            float ssum = bfbits2f(u0) + bfbits2f(u1);
#pragma unroll
            for (int off = 1; off < 64; off <<= 1) ssum += __shfl_xor(ssum, off);
            ushortT* pr = (ushortT*)&sc[q * 132];
            pr[lane] = u0;
            pr[lane + 64] = u1;
            if (lane == 0) {
                float al = __expf(mo - mn);
                alphaS[q] = al;
                lrun[q] = lrun[q] * al + ssum;
                mrun[q] = mn;
            }
        }
        __syncthreads();

        // ---- PV: rescale O, then O += P @ V (wave owns d-tile w*16..+16) ----
#pragma unroll
        for (int mt = 0; mt < 3; ++mt)
#pragma unroll
            for (int r = 0; r < 4; ++r)
                O[mt][r] *= alphaS[mt * 16 + quad * 4 + r];
#pragma unroll
        for (int mt = 0; mt < 3; ++mt)
#pragma unroll
            for (int kk = 0; kk < 4; ++kk) {
                short8 pa = *(const short8*)((const ushortT*)sc +
                    (size_t)(mt * 16 + c16) * 264 + kk * 32 + quad * 8);
                O[mt] = __builtin_amdgcn_mfma_f32_16x16x32_bf16(pa, vb[kk], O[mt], 0, 0, 0);
            }
        __syncthreads();
    }

    // ---- epilogue ----
#pragma unroll
    for (int mt = 0; mt < 3; ++mt)
#pragma unroll
        for (int r = 0; r < 4; ++r) {
            const int q = mt * 16 + quad * 4 + r;
            if (q < U_)
                pacc[(((size_t)bh * NCHUNK + blockIdx.x) * U_ + q) * 64 + w * 16 + c16] =
                    O[mt][r];
        }
    if (tid < U_) {
        pm[((size_t)bh * NCHUNK + blockIdx.x) * U_ + tid] = mrun[tid];
        pl[((size_t)bh * NCHUNK + blockIdx.x) * U_ + tid] = lrun[tid];
    }
}

// ---------------------------------------------------------------------------
// Combine chunk partials -> correction vector (sel_ctx - mean_v)
// ---------------------------------------------------------------------------
__global__ __launch_bounds__(64) void attn_combine(
    const float* __restrict__ pm, const float* __restrict__ pl,
    const float* __restrict__ pacc, const float* __restrict__ vsum,
    float* __restrict__ corr)
{
    const int q = blockIdx.x, bh = blockIdx.y, d = threadIdx.x;
    const int b = bh >> 3, h = bh & 7;
    float M = -INFINITY;
    for (int c = 0; c < NCHUNK; ++c)
        M = fmaxf(M, pm[((size_t)bh * NCHUNK + c) * U_ + q]);
    float L = 0.f, a = 0.f;
    for (int c = 0; c < NCHUNK; ++c) {
        float mc = pm[((size_t)bh * NCHUNK + c) * U_ + q];
        float lc = pl[((size_t)bh * NCHUNK + c) * U_ + q];
        float f = __expf(mc - M);
        L = fmaf(lc, f, L);
        a = fmaf(f, pacc[(((size_t)bh * NCHUNK + c) * U_ + q) * 64 + d], a);
    }
    corr[((size_t)bh * U_ + q) * 64 + d] =
        a / L - vsum[b * 512 + h * 64 + d] * (1.0f / S_);
}

// ---------------------------------------------------------------------------
// out_base[b][512] = bo + mean_flat[b] @ Wo
// ---------------------------------------------------------------------------
__global__ __launch_bounds__(512) void outbase_kernel(
    const float* __restrict__ vsum, const float* __restrict__ Wo,
    const float* __restrict__ bo, float* __restrict__ outbase)
{
    const int b = blockIdx.x, d = threadIdx.x;
    float acc = bo[d];
    for (int r = 0; r < 512; ++r) {
        float mv = vsum[b * 512 + r] * (1.0f / S_);
        acc = fmaf(mv, Wo[(size_t)r * 512 + d], acc);
    }
    outbase[b * 512 + d] = acc;
}

// ---------------------------------------------------------------------------
// Broadcast fill: out[b,s,:] = out_base[b,:]
// ---------------------------------------------------------------------------
__global__ __launch_bounds__(256) void fill_kernel(
    const float* __restrict__ outbase, float* __restrict__ out)
{
    size_t gid = (size_t)blockIdx.x * 256 + threadIdx.x;
    size_t e0 = gid * 4;
    int b = (int)(e0 >> 22);          // 8192*512 = 2^22
    int col = (int)(e0 & 511);
    float4 v = *(const float4*)&outbase[b * 512 + col];
    *(float4*)&out[e0] = v;
}

// ---------------------------------------------------------------------------
// Rank-64 corrections: out[b, s_q, :] += corr[bh][q] @ Wo_h
// ---------------------------------------------------------------------------
__global__ __launch_bounds__(512) void correction_kernel(
    const float* __restrict__ corr, const float* __restrict__ Wo,
    const int* __restrict__ topidx, float* __restrict__ out)
{
    const int q = blockIdx.x, bh = blockIdx.y;
    const int b = bh >> 3, h = bh & 7, d = threadIdx.x;
    const int s = topidx[bh * U_ + q];
    const float* cp = corr + ((size_t)bh * U_ + q) * 64;
    float delta = 0.f;
#pragma unroll
    for (int r = 0; r < 64; ++r)
        delta = fmaf(cp[r], Wo[(size_t)(h * 64 + r) * 512 + d], delta);
    atomicAdd(&out[((size_t)b * S_ + s) * 512 + d], delta);
}

// ---------------------------------------------------------------------------
extern "C" void kernel_launch(void* const* d_in, const int* in_sizes, int n_in,
                              void* d_out, int out_size, void* d_ws, size_t ws_size,
                              hipStream_t stream)
{
    const float* X  = (const float*)d_in[0];
    const float* Wq = (const float*)d_in[1];
    const float* bq = (const float*)d_in[2];
    const float* Wk = (const float*)d_in[3];
    const float* bk = (const float*)d_in[4];
    const float* Wv = (const float*)d_in[5];
    const float* bv = (const float*)d_in[6];
    const float* Wo = (const float*)d_in[7];
    const float* bo = (const float*)d_in[8];
    float* out = (float*)d_out;

    char* ws = (char*)d_ws;
    size_t off = 0;
    auto alloc = [&](size_t bytes) {
        void* p = ws + off;
        off = (off + bytes + 255) & ~(size_t)255;
        return p;
    };
    ushortT* Xh   = (ushortT*)alloc((size_t)B_ * S_ * D_ * 2);
    ushortT* Xl   = (ushortT*)alloc((size_t)B_ * S_ * D_ * 2);
    ushortT* Kbuf = (ushortT*)alloc((size_t)B_ * S_ * D_ * 2);
    ushortT* VT   = (ushortT*)alloc((size_t)B_ * S_ * D_ * 2);
    ushortT* WqhT = (ushortT*)alloc((size_t)D_ * D_ * 2);
    ushortT* WqlT = (ushortT*)alloc((size_t)D_ * D_ * 2);
    ushortT* WkT  = (ushortT*)alloc((size_t)D_ * D_ * 2);
    ushortT* WvT  = (ushortT*)alloc((size_t)D_ * D_ * 2);
    float* sparsity = (float*)alloc((size_t)B_ * H_ * S_ * 4);
    int*   topidx   = (int*)alloc((size_t)B_ * H_ * U_ * 4);
    float* selq     = (float*)alloc((size_t)B_ * H_ * U_ * 64 * 4);
    float* pm       = (float*)alloc((size_t)B_ * H_ * NCHUNK * U_ * 4);
    float* pl       = (float*)alloc((size_t)B_ * H_ * NCHUNK * U_ * 4);
    float* pacc     = (float*)alloc((size_t)B_ * H_ * NCHUNK * U_ * 64 * 4);
    float* corr     = (float*)alloc((size_t)B_ * H_ * U_ * 64 * 4);
    float* vsum     = (float*)alloc((size_t)B_ * 512 * 4);
    float* outbase  = (float*)alloc((size_t)B_ * 512 * 4);

    hipMemsetAsync(vsum, 0, (size_t)B_ * 512 * 4, stream);

    split_x<<<(B_ * S_ * D_) / (256 * 8), 256, 0, stream>>>(X, Xh, Xl);
    wprep<<<dim3(16, 16, 3), 256, 0, stream>>>(Wq, Wk, Wv, WqhT, WqlT, WkT, WvT);
    qkv_mfma<<<dim3(256, 12), 256, 0, stream>>>(Xh, Xl, WqhT, WqlT, WkT, WvT,
                                                bq, bk, bv, Kbuf, VT,
                                                sparsity, vsum);
    topk_kernel<<<B_ * H_, 256, 0, stream>>>(sparsity, topidx);
    selq_kernel<<<dim3(U_, B_ * H_), 64, 0, stream>>>(X, Wq, bq, topidx, selq);
    attn_mfma<<<dim3(NCHUNK, B_ * H_), 256, 0, stream>>>(Kbuf, VT, selq,
                                                         pm, pl, pacc);
    attn_combine<<<dim3(U_, B_ * H_), 64, 0, stream>>>(pm, pl, pacc, vsum, corr);
    outbase_kernel<<<B_, 512, 0, stream>>>(vsum, Wo, bo, outbase);
    fill_kernel<<<(B_ * S_ * D_ / 4 + 255) / 256, 256, 0, stream>>>(outbase, out);
    correction_kernel<<<dim3(U_, B_ * H_), 512, 0, stream>>>(corr, Wo, topidx, out);
}

// Round 4
// 384.295 us; speedup vs baseline: 4.3375x; 1.2591x over previous
//
#include <hip/hip_runtime.h>
#include <math.h>

#define B_ 4
#define S_ 8192
#define D_ 512
#define H_ 8
#define U_ 45            // int(5*ln(8193)) = 45
#define NCHUNK 16        // 512 keys per attention block

typedef unsigned short ushortT;
typedef __attribute__((ext_vector_type(8))) short short8;
typedef __attribute__((ext_vector_type(4))) float f32x4;

__device__ __forceinline__ float bfbits2f(unsigned short v) {
    unsigned u = ((unsigned)v) << 16;
    return __uint_as_float(u);
}
__device__ __forceinline__ unsigned short f2bf(float f) {
    unsigned u = __float_as_uint(f);
    unsigned r = u + 0x7fffu + ((u >> 16) & 1u);   // RNE
    return (unsigned short)(r >> 16);
}

__device__ __forceinline__ void gload_lds16(const ushortT* g, ushortT* l) {
    __builtin_amdgcn_global_load_lds(
        (const __attribute__((address_space(1))) void*)g,
        (__attribute__((address_space(3))) void*)l,
        16, 0, 0);
}

// ---------------------------------------------------------------------------
// Pre-pass 1: split X (fp32) into bf16 hi + bf16 lo residual.
// ---------------------------------------------------------------------------
__global__ __launch_bounds__(256) void split_x(
    const float* __restrict__ X, ushortT* __restrict__ Xh, ushortT* __restrict__ Xl)
{
    size_t i = ((size_t)blockIdx.x * 256 + threadIdx.x) * 8;
    float4 a = *(const float4*)(X + i);
    float4 b = *(const float4*)(X + i + 4);
    float v[8] = {a.x, a.y, a.z, a.w, b.x, b.y, b.z, b.w};
    ushortT h[8], l[8];
#pragma unroll
    for (int j = 0; j < 8; ++j) {
        h[j] = f2bf(v[j]);
        l[j] = f2bf(v[j] - bfbits2f(h[j]));
    }
    *(ushort4*)(Xh + i)     = make_ushort4(h[0], h[1], h[2], h[3]);
    *(ushort4*)(Xh + i + 4) = make_ushort4(h[4], h[5], h[6], h[7]);
    *(ushort4*)(Xl + i)     = make_ushort4(l[0], l[1], l[2], l[3]);
    *(ushort4*)(Xl + i + 4) = make_ushort4(l[4], l[5], l[6], l[7]);
}

// ---------------------------------------------------------------------------
// Pre-pass 2: transpose + bf16-convert weights.  WT[n][k] = W[k][n].
// ---------------------------------------------------------------------------
__global__ __launch_bounds__(256) void wprep(
    const float* __restrict__ Wq, const float* __restrict__ Wk,
    const float* __restrict__ Wv,
    ushortT* __restrict__ WqhT, ushortT* __restrict__ WqlT,
    ushortT* __restrict__ WkT,  ushortT* __restrict__ WvT)
{
    __shared__ float t[32][33];
    const int z = blockIdx.z;
    const float* W = (z == 0) ? Wq : (z == 1) ? Wk : Wv;
    const int tx = threadIdx.x & 31, ty4 = (threadIdx.x >> 5) * 4;
    const int r0 = blockIdx.y * 32, c0 = blockIdx.x * 32;
#pragma unroll
    for (int i = 0; i < 4; ++i)
        t[ty4 + i][tx] = W[(size_t)(r0 + ty4 + i) * 512 + c0 + tx];
    __syncthreads();
#pragma unroll
    for (int i = 0; i < 4; ++i) {
        float v = t[tx][ty4 + i];                       // = W[r0+tx][c0+ty4+i]
        size_t oidx = (size_t)(c0 + ty4 + i) * 512 + r0 + tx;
        if (z == 0) {
            ushortT h = f2bf(v);
            WqhT[oidx] = h;
            WqlT[oidx] = f2bf(v - bfbits2f(h));
        } else if (z == 1) {
            WkT[oidx] = f2bf(v);
        } else {
            WvT[oidx] = f2bf(v);
        }
    }
}

// ---------------------------------------------------------------------------
// MFMA QKV projection.  grid (256, 12): y 0-3 Q n-tiles, 4-7 K n-tiles,
// 8-11 V column-tiles.  128x128 tile, BK=32, 4 waves 2x2, wave = 64x64.
// LDS chunk-rotate swizzle: physical 16B-chunk = (logical + (row>>1)) & 3,
// realized by permuting the per-lane GLOBAL source of global_load_lds
// (dst is fixed lane*16).  Fragment ds_read_b128 becomes 2-way banked (free).
// ---------------------------------------------------------------------------
__global__ __launch_bounds__(256, 2) void qkv_mfma(
    const ushortT* __restrict__ Xh, const ushortT* __restrict__ Xl,
    const ushortT* __restrict__ WqhT, const ushortT* __restrict__ WqlT,
    const ushortT* __restrict__ WkT,  const ushortT* __restrict__ WvT,
    const float* __restrict__ bq, const float* __restrict__ bk,
    const float* __restrict__ bv,
    ushortT* __restrict__ Kbuf, ushortT* __restrict__ VT,
    float* __restrict__ sparsity, float* __restrict__ vsum)
{
    __shared__ ushortT lds[4 * 128 * 32];   // Ah | Bh | Al | Bl, 8KB each
    ushortT* Ah = lds;
    ushortT* Bh = lds + 4096;
    ushortT* Al = lds + 8192;
    ushortT* Bl = lds + 12288;

    const int tid  = threadIdx.x;
    const int w    = tid >> 6, lane = tid & 63;
    const int quad = lane >> 4, c16 = lane & 15;
    const int wr   = w >> 1,  wc  = w & 1;
    const int mat  = blockIdx.y >> 2;        // 0=Q 1=K 2=V
    const int nt   = blockIdx.y & 3;
    const int m0   = blockIdx.x * 128;
    const int n0   = nt * 128;

    const int srow   = lane >> 2;            // staging row within 16-row chunk
    // swizzled source chunk: logical = (phys - (row16>>1)) & 3
    const int schunk = ((((lane & 3) - (srow >> 1)) & 3)) * 8;
    // swizzled read chunk for this lane's fragments
    const int rchunk = ((quad + (c16 >> 1)) & 3) * 8;

    f32x4 acc[4][4];
#pragma unroll
    for (int i = 0; i < 4; ++i)
#pragma unroll
        for (int j = 0; j < 4; ++j) acc[i][j] = (f32x4){0.f, 0.f, 0.f, 0.f};

    if (mat == 0) {
        for (int k0 = 0; k0 < 512; k0 += 32) {
            __syncthreads();
#pragma unroll
            for (int c = 0; c < 2; ++c) {
                const int row = w * 32 + c * 16 + srow;
                const int lbase = (w * 32 + c * 16) * 32;
                gload_lds16(Xh   + (size_t)(m0 + row) * 512 + k0 + schunk, Ah + lbase);
                gload_lds16(Xl   + (size_t)(m0 + row) * 512 + k0 + schunk, Al + lbase);
                gload_lds16(WqhT + (size_t)(n0 + row) * 512 + k0 + schunk, Bh + lbase);
                gload_lds16(WqlT + (size_t)(n0 + row) * 512 + k0 + schunk, Bl + lbase);
            }
            __syncthreads();
            short8 ah[4], al[4], bhf[4], blf[4];
#pragma unroll
            for (int i = 0; i < 4; ++i) {
                ah[i]  = *(const short8*)&Ah[(wr * 64 + i * 16 + c16) * 32 + rchunk];
                al[i]  = *(const short8*)&Al[(wr * 64 + i * 16 + c16) * 32 + rchunk];
                bhf[i] = *(const short8*)&Bh[(wc * 64 + i * 16 + c16) * 32 + rchunk];
                blf[i] = *(const short8*)&Bl[(wc * 64 + i * 16 + c16) * 32 + rchunk];
            }
#pragma unroll
            for (int i = 0; i < 4; ++i)
#pragma unroll
                for (int j = 0; j < 4; ++j) {
                    acc[i][j] = __builtin_amdgcn_mfma_f32_16x16x32_bf16(ah[i], bhf[j], acc[i][j], 0, 0, 0);
                    acc[i][j] = __builtin_amdgcn_mfma_f32_16x16x32_bf16(ah[i], blf[j], acc[i][j], 0, 0, 0);
                    acc[i][j] = __builtin_amdgcn_mfma_f32_16x16x32_bf16(al[i], bhf[j], acc[i][j], 0, 0, 0);
                }
        }
    } else {
        // mat1 (K): A = Xh rows m0+, B = WkT rows n0+   -> C[s][col]
        // mat2 (V): A = WvT rows n0+, B = Xh rows m0+   -> C^T[col][s]
        const ushortT* Ag = (mat == 1) ? Xh : WvT;
        const ushortT* Bg = (mat == 1) ? WkT : Xh;
        const int arow0 = (mat == 1) ? m0 : n0;
        const int brow0 = (mat == 1) ? n0 : m0;
        for (int k0 = 0; k0 < 512; k0 += 32) {
            __syncthreads();
#pragma unroll
            for (int c = 0; c < 2; ++c) {
                const int row = w * 32 + c * 16 + srow;
                const int lbase = (w * 32 + c * 16) * 32;
                gload_lds16(Ag + (size_t)(arow0 + row) * 512 + k0 + schunk, Ah + lbase);
                gload_lds16(Bg + (size_t)(brow0 + row) * 512 + k0 + schunk, Bh + lbase);
            }
            __syncthreads();
            short8 af[4], bf[4];
#pragma unroll
            for (int i = 0; i < 4; ++i) {
                af[i] = *(const short8*)&Ah[(wr * 64 + i * 16 + c16) * 32 + rchunk];
                bf[i] = *(const short8*)&Bh[(wc * 64 + i * 16 + c16) * 32 + rchunk];
            }
#pragma unroll
            for (int i = 0; i < 4; ++i)
#pragma unroll
                for (int j = 0; j < 4; ++j)
                    acc[i][j] = __builtin_amdgcn_mfma_f32_16x16x32_bf16(af[i], bf[j], acc[i][j], 0, 0, 0);
        }
    }

    // ---- epilogue ----
    if (mat == 0) {
        const int b = m0 >> 13;
        const int srow0 = (m0 & 8191) + wr * 64;
        float bb[4];
#pragma unroll
        for (int j = 0; j < 4; ++j) bb[j] = bq[n0 + wc * 64 + j * 16 + c16];
        const int head = (n0 + wc * 64) >> 6;
#pragma unroll
        for (int i = 0; i < 4; ++i)
#pragma unroll
            for (int r = 0; r < 4; ++r) {
                float p = 0.f;
#pragma unroll
                for (int j = 0; j < 4; ++j) {
                    float v = acc[i][j][r] + bb[j];
                    p = fmaf(v, v, p);
                }
                p += __shfl_xor(p, 1);
                p += __shfl_xor(p, 2);
                p += __shfl_xor(p, 4);
                p += __shfl_xor(p, 8);
                if (c16 == 0) {
                    int s = srow0 + i * 16 + quad * 4 + r;
                    sparsity[((size_t)b * H_ + head) * S_ + s] = p;
                }
            }
    } else if (mat == 1) {
        // K head-major: Kbuf[((b*8+head)*8192 + s)*64 + dd]
        const int b = m0 >> 13;
        const int head = (n0 + wc * 64) >> 6;     // uniform (j*16+c16 < 64)
        float bb[4];
#pragma unroll
        for (int j = 0; j < 4; ++j) bb[j] = bk[n0 + wc * 64 + j * 16 + c16];
        ushortT* kbase = Kbuf + ((size_t)(b * 8 + head) * 8192) * 64;
#pragma unroll
        for (int i = 0; i < 4; ++i)
#pragma unroll
            for (int r = 0; r < 4; ++r) {
                const int s = (m0 & 8191) + wr * 64 + i * 16 + quad * 4 + r;
#pragma unroll
                for (int j = 0; j < 4; ++j)
                    kbase[(size_t)s * 64 + j * 16 + c16] = f2bf(acc[i][j][r] + bb[j]);
            }
    } else {
        // V transposed: VT[((b*8+head)*64 + dd)*8192 + s]
        const int b = m0 >> 13;
        const int sbase = (m0 & 8191) + wc * 64;
#pragma unroll
        for (int i = 0; i < 4; ++i)
#pragma unroll
            for (int r = 0; r < 4; ++r) {
                const int dcol = n0 + wr * 64 + i * 16 + quad * 4 + r;
                const int head = dcol >> 6, dd = dcol & 63;
                const float biasv = bv[dcol];
                ushortT* vrow = VT + ((size_t)(b * 8 + head) * 64 + dd) * 8192;
                float vsa = 0.f;
#pragma unroll
                for (int j = 0; j < 4; ++j) {
                    float v = acc[i][j][r] + biasv;
                    vrow[sbase + j * 16 + c16] = f2bf(v);
                    vsa += v;
                }
                vsa += __shfl_xor(vsa, 1);
                vsa += __shfl_xor(vsa, 2);
                vsa += __shfl_xor(vsa, 4);
                vsa += __shfl_xor(vsa, 8);
                if (c16 == 0) atomicAdd(&vsum[b * 512 + dcol], vsa);
            }
    }
}

// ---------------------------------------------------------------------------
// Top-45 per (b,h) via radix-select on fp32 bits (values >= 0 so uint order
// == float order).  8 nibble levels, 8-way replicated LDS histograms.
// Output set matches top_k; order is irrelevant (scatter is permutation-
// invariant); ties at the boundary take smallest indices (matches top_k).
// ---------------------------------------------------------------------------
__global__ __launch_bounds__(256) void topk_kernel(
    const float* __restrict__ sparsity, int* __restrict__ topidx)
{
    __shared__ unsigned vals[S_];        // 32 KB
    __shared__ unsigned hist[8][16];
    __shared__ unsigned prefix_s;
    __shared__ int need_s;
    __shared__ int cnt_gt_s, cnt_eq_s;
    __shared__ int eqidx[64];
    const int bh = blockIdx.x, tid = threadIdx.x;
    const unsigned* sp = (const unsigned*)(sparsity + (size_t)bh * S_);
    for (int i = tid; i < S_; i += 256) vals[i] = sp[i];

    unsigned prefix = 0;
    int need = U_;
    const int rep = tid & 7;
    for (int level = 0; level < 8; ++level) {
        const int shift = 28 - level * 4;
        if (tid < 128) hist[tid >> 4][tid & 15] = 0;
        __syncthreads();
        const unsigned pmask = (level == 0) ? 0u : (0xFFFFFFFFu << (shift + 4));
        for (int i = tid; i < S_; i += 256) {
            unsigned v = vals[i];
            if ((v & pmask) == prefix)
                atomicAdd(&hist[rep][(v >> shift) & 15], 1u);
        }
        __syncthreads();
        if (tid == 0) {
            int acc = 0, b = 15;
            for (; b > 0; --b) {
                int c = 0;
#pragma unroll
                for (int r = 0; r < 8; ++r) c += (int)hist[r][b];
                if (acc + c >= need) break;
                acc += c;
            }
            prefix_s = prefix | ((unsigned)b << shift);
            need_s = need - acc;
        }
        __syncthreads();
        prefix = prefix_s;
        need = need_s;
        __syncthreads();
    }
    // prefix == exact bits of the 45th-largest value
    const unsigned T = prefix;
    if (tid == 0) { cnt_gt_s = 0; cnt_eq_s = 0; }
    __syncthreads();
    for (int i = tid; i < S_; i += 256) {
        unsigned v = vals[i];
        if (v > T) {
            int p = atomicAdd(&cnt_gt_s, 1);
            topidx[bh * U_ + p] = i;
        } else if (v == T) {
            int p = atomicAdd(&cnt_eq_s, 1);
            if (p < 64) eqidx[p] = i;
        }
    }
    __syncthreads();
    if (tid == 0) {
        int rem = U_ - cnt_gt_s;            // >= 1
        int n = cnt_eq_s < 64 ? cnt_eq_s : 64;
        for (int a = 0; a < rem; ++a) {     // take smallest indices among ties
            int best = 1 << 30, bj = 0;
            for (int j = 0; j < n; ++j)
                if (eqidx[j] < best) { best = eqidx[j]; bj = j; }
            topidx[bh * U_ + cnt_gt_s + a] = best;
            eqidx[bj] = 1 << 30;
        }
    }
}

// ---------------------------------------------------------------------------
// Recompute selected Q rows exactly in fp32: selq[bh][q][64]
// ---------------------------------------------------------------------------
__global__ __launch_bounds__(64) void selq_kernel(
    const float* __restrict__ X, const float* __restrict__ Wq,
    const float* __restrict__ bq, const int* __restrict__ topidx,
    float* __restrict__ selq)
{
    const int q = blockIdx.x, bh = blockIdx.y;
    const int b = bh >> 3, h = bh & 7, d = threadIdx.x;
    const int s = topidx[bh * U_ + q];
    const float* xr = X + ((size_t)b * S_ + s) * 512;
    const float* wp = Wq + h * 64 + d;
    float acc = bq[h * 64 + d];
    for (int r = 0; r < 512; ++r)
        acc = fmaf(xr[r], wp[(size_t)r * 512], acc);
    selq[((size_t)bh * U_ + q) * 64 + d] = acc;
}

// ---------------------------------------------------------------------------
// MFMA attention partials, no-max softmax (scores are bounded: |s| <~ 4).
// Grid (NCHUNK=16, 32 bh), 256 thr.  Block = 512 keys, 4 chunks of 128.
// Per chunk: QK mfma -> sc LDS -> pointwise exp -> P bf16 in-place,
// per-row sums accumulated in REGISTERS across chunks -> PV mfma (plain
// accumulate, no rescale).  Partials combine by simple summation.
// ---------------------------------------------------------------------------
__global__ __launch_bounds__(256, 2) void attn_mfma(
    const ushortT* __restrict__ Kbuf, const ushortT* __restrict__ VT,
    const float* __restrict__ selq,
    float* __restrict__ pl, float* __restrict__ pacc)
{
    __shared__ float sc[48 * 132];          // scores f32; P bf16 in-place
    __shared__ ushortT Qb[48 * 72];         // Q bf16, scale folded, padded

    const int tid = threadIdx.x;
    const int w = tid >> 6, lane = tid & 63;
    const int quad = lane >> 4, c16 = lane & 15;
    const int bh = blockIdx.y;
    const int s_base = blockIdx.x * 512;

    // stage Q (scale 0.125 folded; exact: pow2 scale)
    for (int i = tid; i < 48 * 64; i += 256) {
        int q = i >> 6, d = i & 63;
        float v = (q < U_) ? selq[((size_t)bh * U_ + q) * 64 + d] * 0.125f : 0.f;
        Qb[q * 72 + d] = f2bf(v);
    }

    f32x4 O[3];
#pragma unroll
    for (int mt = 0; mt < 3; ++mt) O[mt] = (f32x4){0.f, 0.f, 0.f, 0.f};
    float lacc[12];
#pragma unroll
    for (int qi = 0; qi < 12; ++qi) lacc[qi] = 0.f;

    __syncthreads();

    // persistent Q A-frags
    short8 qa[3][2];
#pragma unroll
    for (int mt = 0; mt < 3; ++mt)
#pragma unroll
        for (int kk = 0; kk < 2; ++kk)
            qa[mt][kk] = *(const short8*)&Qb[(mt * 16 + c16) * 72 + kk * 32 + quad * 8];

    const ushortT* kb  = Kbuf + (size_t)bh * 8192 * 64;
    const ushortT* vtb = VT + ((size_t)bh * 64 + w * 16 + c16) * 8192;

    for (int ci = 0; ci < 4; ++ci) {
        const int s0 = s_base + ci * 128;

        // ---- QK^T: wave w owns keys [32w, 32w+32) ----
        short8 kf[2][2];
#pragma unroll
        for (int nt2 = 0; nt2 < 2; ++nt2)
#pragma unroll
            for (int kk = 0; kk < 2; ++kk)
                kf[nt2][kk] = *(const short8*)&kb[
                    (size_t)(s0 + w * 32 + nt2 * 16 + c16) * 64 + kk * 32 + quad * 8];
        f32x4 sacc[3][2];
#pragma unroll
        for (int mt = 0; mt < 3; ++mt)
#pragma unroll
            for (int nt2 = 0; nt2 < 2; ++nt2) {
                sacc[mt][nt2] = (f32x4){0.f, 0.f, 0.f, 0.f};
#pragma unroll
                for (int kk = 0; kk < 2; ++kk)
                    sacc[mt][nt2] = __builtin_amdgcn_mfma_f32_16x16x32_bf16(
                        qa[mt][kk], kf[nt2][kk], sacc[mt][nt2], 0, 0, 0);
            }
#pragma unroll
        for (int mt = 0; mt < 3; ++mt)
#pragma unroll
            for (int nt2 = 0; nt2 < 2; ++nt2)
#pragma unroll
                for (int r = 0; r < 4; ++r)
                    sc[(mt * 16 + quad * 4 + r) * 132 + w * 32 + nt2 * 16 + c16] =
                        sacc[mt][nt2][r];
        __syncthreads();

        // ---- prefetch VT B-frags (consumed after next barrier) ----
        short8 vb[4];
#pragma unroll
        for (int kk = 0; kk < 4; ++kk)
            vb[kk] = *(const short8*)&vtb[s0 + kk * 32 + quad * 8];

        // ---- pointwise exp (no max), P bf16 in-place, reg row-sums ----
#pragma unroll
        for (int qi = 0; qi < 12; ++qi) {
            const int q = w * 12 + qi;
            float x0 = sc[q * 132 + lane];
            float x1 = sc[q * 132 + 64 + lane];
            ushortT u0 = f2bf(__expf(x0));
            ushortT u1 = f2bf(__expf(x1));
            lacc[qi] += bfbits2f(u0) + bfbits2f(u1);
            ushortT* pr = (ushortT*)&sc[q * 132];
            pr[lane] = u0;
            pr[lane + 64] = u1;
        }
        __syncthreads();

        // ---- PV: O += P @ V (wave owns d-tile w*16..+16) ----
#pragma unroll
        for (int mt = 0; mt < 3; ++mt)
#pragma unroll
            for (int kk = 0; kk < 4; ++kk) {
                short8 pa = *(const short8*)((const ushortT*)sc +
                    (size_t)(mt * 16 + c16) * 264 + kk * 32 + quad * 8);
                O[mt] = __builtin_amdgcn_mfma_f32_16x16x32_bf16(pa, vb[kk], O[mt], 0, 0, 0);
            }
        __syncthreads();
    }

    // ---- epilogue ----
#pragma unroll
    for (int mt = 0; mt < 3; ++mt)
#pragma unroll
        for (int r = 0; r < 4; ++r) {
            const int q = mt * 16 + quad * 4 + r;
            if (q < U_)
                pacc[(((size_t)bh * NCHUNK + blockIdx.x) * U_ + q) * 64 + w * 16 + c16] =
                    O[mt][r];
        }
#pragma unroll
    for (int qi = 0; qi < 12; ++qi) {
        const int q = w * 12 + qi;
        float ssum = lacc[qi];
#pragma unroll
        for (int off = 1; off < 64; off <<= 1) ssum += __shfl_xor(ssum, off);
        if (lane == 0 && q < U_)
            pl[((size_t)bh * NCHUNK + blockIdx.x) * U_ + q] = ssum;
    }
}

// ---------------------------------------------------------------------------
// Combine chunk partials (plain sums) -> correction (sel_ctx - mean_v)
// ---------------------------------------------------------------------------
__global__ __launch_bounds__(64) void attn_combine(
    const float* __restrict__ pl, const float* __restrict__ pacc,
    const float* __restrict__ vsum, float* __restrict__ corr)
{
    const int q = blockIdx.x, bh = blockIdx.y, d = threadIdx.x;
    const int b = bh >> 3, h = bh & 7;
    float L = 0.f, a = 0.f;
    for (int c = 0; c < NCHUNK; ++c) {
        L += pl[((size_t)bh * NCHUNK + c) * U_ + q];
        a += pacc[(((size_t)bh * NCHUNK + c) * U_ + q) * 64 + d];
    }
    corr[((size_t)bh * U_ + q) * 64 + d] =
        a / L - vsum[b * 512 + h * 64 + d] * (1.0f / S_);
}

// ---------------------------------------------------------------------------
// out_base[b][512] = bo + mean_flat[b] @ Wo
// ---------------------------------------------------------------------------
__global__ __launch_bounds__(512) void outbase_kernel(
    const float* __restrict__ vsum, const float* __restrict__ Wo,
    const float* __restrict__ bo, float* __restrict__ outbase)
{
    const int b = blockIdx.x, d = threadIdx.x;
    float acc = bo[d];
    for (int r = 0; r < 512; ++r) {
        float mv = vsum[b * 512 + r] * (1.0f / S_);
        acc = fmaf(mv, Wo[(size_t)r * 512 + d], acc);
    }
    outbase[b * 512 + d] = acc;
}

// ---------------------------------------------------------------------------
// Broadcast fill: out[b,s,:] = out_base[b,:]
// ---------------------------------------------------------------------------
__global__ __launch_bounds__(256) void fill_kernel(
    const float* __restrict__ outbase, float* __restrict__ out)
{
    size_t gid = (size_t)blockIdx.x * 256 + threadIdx.x;
    size_t e0 = gid * 4;
    int b = (int)(e0 >> 22);          // 8192*512 = 2^22
    int col = (int)(e0 & 511);
    float4 v = *(const float4*)&outbase[b * 512 + col];
    *(float4*)&out[e0] = v;
}

// ---------------------------------------------------------------------------
// Rank-64 corrections: out[b, s_q, :] += corr[bh][q] @ Wo_h
// ---------------------------------------------------------------------------
__global__ __launch_bounds__(512) void correction_kernel(
    const float* __restrict__ corr, const float* __restrict__ Wo,
    const int* __restrict__ topidx, float* __restrict__ out)
{
    const int q = blockIdx.x, bh = blockIdx.y;
    const int b = bh >> 3, h = bh & 7, d = threadIdx.x;
    const int s = topidx[bh * U_ + q];
    const float* cp = corr + ((size_t)bh * U_ + q) * 64;
    float delta = 0.f;
#pragma unroll
    for (int r = 0; r < 64; ++r)
        delta = fmaf(cp[r], Wo[(size_t)(h * 64 + r) * 512 + d], delta);
    atomicAdd(&out[((size_t)b * S_ + s) * 512 + d], delta);
}

// ---------------------------------------------------------------------------
extern "C" void kernel_launch(void* const* d_in, const int* in_sizes, int n_in,
                              void* d_out, int out_size, void* d_ws, size_t ws_size,
                              hipStream_t stream)
{
    const float* X  = (const float*)d_in[0];
    const float* Wq = (const float*)d_in[1];
    const float* bq = (const float*)d_in[2];
    const float* Wk = (const float*)d_in[3];
    const float* bk = (const float*)d_in[4];
    const float* Wv = (const float*)d_in[5];
    const float* bv = (const float*)d_in[6];
    const float* Wo = (const float*)d_in[7];
    const float* bo = (const float*)d_in[8];
    float* out = (float*)d_out;

    char* ws = (char*)d_ws;
    size_t off = 0;
    auto alloc = [&](size_t bytes) {
        void* p = ws + off;
        off = (off + bytes + 255) & ~(size_t)255;
        return p;
    };
    ushortT* Xh   = (ushortT*)alloc((size_t)B_ * S_ * D_ * 2);
    ushortT* Xl   = (ushortT*)alloc((size_t)B_ * S_ * D_ * 2);
    ushortT* Kbuf = (ushortT*)alloc((size_t)B_ * S_ * D_ * 2);
    ushortT* VT   = (ushortT*)alloc((size_t)B_ * S_ * D_ * 2);
    ushortT* WqhT = (ushortT*)alloc((size_t)D_ * D_ * 2);
    ushortT* WqlT = (ushortT*)alloc((size_t)D_ * D_ * 2);
    ushortT* WkT  = (ushortT*)alloc((size_t)D_ * D_ * 2);
    ushortT* WvT  = (ushortT*)alloc((size_t)D_ * D_ * 2);
    float* sparsity = (float*)alloc((size_t)B_ * H_ * S_ * 4);
    int*   topidx   = (int*)alloc((size_t)B_ * H_ * U_ * 4);
    float* selq     = (float*)alloc((size_t)B_ * H_ * U_ * 64 * 4);
    float* pl       = (float*)alloc((size_t)B_ * H_ * NCHUNK * U_ * 4);
    float* pacc     = (float*)alloc((size_t)B_ * H_ * NCHUNK * U_ * 64 * 4);
    float* corr     = (float*)alloc((size_t)B_ * H_ * U_ * 64 * 4);
    float* vsum     = (float*)alloc((size_t)B_ * 512 * 4);
    float* outbase  = (float*)alloc((size_t)B_ * 512 * 4);

    hipMemsetAsync(vsum, 0, (size_t)B_ * 512 * 4, stream);

    split_x<<<(B_ * S_ * D_) / (256 * 8), 256, 0, stream>>>(X, Xh, Xl);
    wprep<<<dim3(16, 16, 3), 256, 0, stream>>>(Wq, Wk, Wv, WqhT, WqlT, WkT, WvT);
    qkv_mfma<<<dim3(256, 12), 256, 0, stream>>>(Xh, Xl, WqhT, WqlT, WkT, WvT,
                                                bq, bk, bv, Kbuf, VT,
                                                sparsity, vsum);
    topk_kernel<<<B_ * H_, 256, 0, stream>>>(sparsity, topidx);
    selq_kernel<<<dim3(U_, B_ * H_), 64, 0, stream>>>(X, Wq, bq, topidx, selq);
    attn_mfma<<<dim3(NCHUNK, B_ * H_), 256, 0, stream>>>(Kbuf, VT, selq, pl, pacc);
    attn_combine<<<dim3(U_, B_ * H_), 64, 0, stream>>>(pl, pacc, vsum, corr);
    outbase_kernel<<<B_, 512, 0, stream>>>(vsum, Wo, bo, outbase);
    fill_kernel<<<(B_ * S_ * D_ / 4 + 255) / 256, 256, 0, stream>>>(outbase, out);
    correction_kernel<<<dim3(U_, B_ * H_), 512, 0, stream>>>(corr, Wo, topidx, out);
}

// Round 5
// 347.290 us; speedup vs baseline: 4.7997x; 1.1066x over previous
//
#include <hip/hip_runtime.h>
#include <hip/hip_fp16.h>
#include <math.h>

#define B_ 4
#define S_ 8192
#define D_ 512
#define H_ 8
#define U_ 45            // int(5*ln(8193)) = 45
#define NCHUNK 16        // 512 keys per attention block

typedef unsigned short ushortT;
typedef __attribute__((ext_vector_type(8))) _Float16 half8;
typedef __attribute__((ext_vector_type(4))) float f32x4;

__device__ __forceinline__ ushortT f2h(float f) {
    return __half_as_ushort(__float2half(f));    // RNE
}
__device__ __forceinline__ float h2f(ushortT u) {
    return __half2float(__ushort_as_half(u));
}

__device__ __forceinline__ void gload_lds16(const ushortT* g, ushortT* l) {
    __builtin_amdgcn_global_load_lds(
        (const __attribute__((address_space(1))) void*)g,
        (__attribute__((address_space(3))) void*)l,
        16, 0, 0);
}

// ---------------------------------------------------------------------------
// Pre-pass 1: convert X (fp32) to fp16.
// ---------------------------------------------------------------------------
__global__ __launch_bounds__(256) void xconv(
    const float* __restrict__ X, ushortT* __restrict__ Xf)
{
    size_t i = ((size_t)blockIdx.x * 256 + threadIdx.x) * 8;
    float4 a = *(const float4*)(X + i);
    float4 b = *(const float4*)(X + i + 4);
    *(ushort4*)(Xf + i)     = make_ushort4(f2h(a.x), f2h(a.y), f2h(a.z), f2h(a.w));
    *(ushort4*)(Xf + i + 4) = make_ushort4(f2h(b.x), f2h(b.y), f2h(b.z), f2h(b.w));
}

// ---------------------------------------------------------------------------
// Pre-pass 2: transpose + fp16-convert weights.  WT[n][k] = W[k][n].
// ---------------------------------------------------------------------------
__global__ __launch_bounds__(256) void wprep(
    const float* __restrict__ Wq, const float* __restrict__ Wk,
    const float* __restrict__ Wv,
    ushortT* __restrict__ WqT, ushortT* __restrict__ WkT,
    ushortT* __restrict__ WvT)
{
    __shared__ float t[32][33];
    const int z = blockIdx.z;
    const float* W = (z == 0) ? Wq : (z == 1) ? Wk : Wv;
    ushortT* O = (z == 0) ? WqT : (z == 1) ? WkT : WvT;
    const int tx = threadIdx.x & 31, ty4 = (threadIdx.x >> 5) * 4;
    const int r0 = blockIdx.y * 32, c0 = blockIdx.x * 32;
#pragma unroll
    for (int i = 0; i < 4; ++i)
        t[ty4 + i][tx] = W[(size_t)(r0 + ty4 + i) * 512 + c0 + tx];
    __syncthreads();
#pragma unroll
    for (int i = 0; i < 4; ++i)
        O[(size_t)(c0 + ty4 + i) * 512 + r0 + tx] = f2h(t[tx][ty4 + i]);
}

// ---------------------------------------------------------------------------
// MFMA QKV projection, all fp16, single pass per matrix.
// grid (256, 12): y 0-3 Q n-tiles, 4-7 K n-tiles, 8-11 V column-tiles.
// 128x128 tile, BK=32, 4 waves 2x2, wave = 64x64 (4x4 MFMA 16x16x32_f16).
// LDS chunk-rotate swizzle (conflict-free, verified R3->R4: 8.4M -> 0).
// Q -> sparsity (sum q^2 per head).  K -> head-major fp16 [bh][s][64].
// V -> computed transposed (A=WvT, B=Xf): VT [bh][64][8192] fp16; vsum folded.
// ---------------------------------------------------------------------------
__global__ __launch_bounds__(256, 2) void qkv_mfma(
    const ushortT* __restrict__ Xf,
    const ushortT* __restrict__ WqT, const ushortT* __restrict__ WkT,
    const ushortT* __restrict__ WvT,
    const float* __restrict__ bq, const float* __restrict__ bk,
    const float* __restrict__ bv,
    ushortT* __restrict__ Kbuf, ushortT* __restrict__ VT,
    float* __restrict__ sparsity, float* __restrict__ vsum)
{
    __shared__ ushortT lds[2 * 128 * 32];   // A | B, 8KB each
    ushortT* As = lds;
    ushortT* Bs = lds + 4096;

    const int tid  = threadIdx.x;
    const int w    = tid >> 6, lane = tid & 63;
    const int quad = lane >> 4, c16 = lane & 15;
    const int wr   = w >> 1,  wc  = w & 1;
    const int mat  = blockIdx.y >> 2;        // 0=Q 1=K 2=V
    const int nt   = blockIdx.y & 3;
    const int m0   = blockIdx.x * 128;
    const int n0   = nt * 128;

    const int srow   = lane >> 2;            // staging row within 16-row chunk
    // chunk-rotate swizzle: physical chunk = (logical + (row>>1)) & 3
    const int schunk = ((((lane & 3) - (srow >> 1)) & 3)) * 8;
    const int rchunk = ((quad + (c16 >> 1)) & 3) * 8;

    const ushortT* Ag = (mat == 2) ? WvT : Xf;
    const ushortT* Bg = (mat == 0) ? WqT : (mat == 1) ? WkT : Xf;
    const int arow0 = (mat == 2) ? n0 : m0;
    const int brow0 = (mat == 2) ? m0 : n0;

    f32x4 acc[4][4];
#pragma unroll
    for (int i = 0; i < 4; ++i)
#pragma unroll
        for (int j = 0; j < 4; ++j) acc[i][j] = (f32x4){0.f, 0.f, 0.f, 0.f};

    for (int k0 = 0; k0 < 512; k0 += 32) {
        __syncthreads();
#pragma unroll
        for (int c = 0; c < 2; ++c) {
            const int row = w * 32 + c * 16 + srow;
            const int lbase = (w * 32 + c * 16) * 32;
            gload_lds16(Ag + (size_t)(arow0 + row) * 512 + k0 + schunk, As + lbase);
            gload_lds16(Bg + (size_t)(brow0 + row) * 512 + k0 + schunk, Bs + lbase);
        }
        __syncthreads();
        half8 af[4], bf[4];
#pragma unroll
        for (int i = 0; i < 4; ++i) {
            af[i] = *(const half8*)&As[(wr * 64 + i * 16 + c16) * 32 + rchunk];
            bf[i] = *(const half8*)&Bs[(wc * 64 + i * 16 + c16) * 32 + rchunk];
        }
#pragma unroll
        for (int i = 0; i < 4; ++i)
#pragma unroll
            for (int j = 0; j < 4; ++j)
                acc[i][j] = __builtin_amdgcn_mfma_f32_16x16x32_f16(af[i], bf[j], acc[i][j], 0, 0, 0);
    }

    // ---- epilogue ----
    if (mat == 0) {
        const int b = m0 >> 13;
        const int srow0 = (m0 & 8191) + wr * 64;
        float bb[4];
#pragma unroll
        for (int j = 0; j < 4; ++j) bb[j] = bq[n0 + wc * 64 + j * 16 + c16];
        const int head = (n0 + wc * 64) >> 6;
#pragma unroll
        for (int i = 0; i < 4; ++i)
#pragma unroll
            for (int r = 0; r < 4; ++r) {
                float p = 0.f;
#pragma unroll
                for (int j = 0; j < 4; ++j) {
                    float v = acc[i][j][r] + bb[j];
                    p = fmaf(v, v, p);
                }
                p += __shfl_xor(p, 1);
                p += __shfl_xor(p, 2);
                p += __shfl_xor(p, 4);
                p += __shfl_xor(p, 8);
                if (c16 == 0) {
                    int s = srow0 + i * 16 + quad * 4 + r;
                    sparsity[((size_t)b * H_ + head) * S_ + s] = p;
                }
            }
    } else if (mat == 1) {
        // K head-major: Kbuf[((b*8+head)*8192 + s)*64 + dd]  (fp16)
        const int b = m0 >> 13;
        const int head = (n0 + wc * 64) >> 6;
        float bb[4];
#pragma unroll
        for (int j = 0; j < 4; ++j) bb[j] = bk[n0 + wc * 64 + j * 16 + c16];
        ushortT* kbase = Kbuf + ((size_t)(b * 8 + head) * 8192) * 64;
#pragma unroll
        for (int i = 0; i < 4; ++i)
#pragma unroll
            for (int r = 0; r < 4; ++r) {
                const int s = (m0 & 8191) + wr * 64 + i * 16 + quad * 4 + r;
#pragma unroll
                for (int j = 0; j < 4; ++j)
                    kbase[(size_t)s * 64 + j * 16 + c16] = f2h(acc[i][j][r] + bb[j]);
            }
    } else {
        // V transposed: VT[((b*8+head)*64 + dd)*8192 + s]  (fp16)
        const int b = m0 >> 13;
        const int sbase = (m0 & 8191) + wc * 64;
#pragma unroll
        for (int i = 0; i < 4; ++i)
#pragma unroll
            for (int r = 0; r < 4; ++r) {
                const int dcol = n0 + wr * 64 + i * 16 + quad * 4 + r;
                const int head = dcol >> 6, dd = dcol & 63;
                const float biasv = bv[dcol];
                ushortT* vrow = VT + ((size_t)(b * 8 + head) * 64 + dd) * 8192;
                float vsa = 0.f;
#pragma unroll
                for (int j = 0; j < 4; ++j) {
                    float v = acc[i][j][r] + biasv;
                    vrow[sbase + j * 16 + c16] = f2h(v);
                    vsa += v;
                }
                vsa += __shfl_xor(vsa, 1);
                vsa += __shfl_xor(vsa, 2);
                vsa += __shfl_xor(vsa, 4);
                vsa += __shfl_xor(vsa, 8);
                if (c16 == 0) atomicAdd(&vsum[b * 512 + dcol], vsa);
            }
    }
}

// ---------------------------------------------------------------------------
// Top-45 per (b,h) via radix-select on fp32 bits (values >= 0).
// ---------------------------------------------------------------------------
__global__ __launch_bounds__(256) void topk_kernel(
    const float* __restrict__ sparsity, int* __restrict__ topidx)
{
    __shared__ unsigned vals[S_];        // 32 KB
    __shared__ unsigned hist[8][16];
    __shared__ unsigned prefix_s;
    __shared__ int need_s;
    __shared__ int cnt_gt_s, cnt_eq_s;
    __shared__ int eqidx[64];
    const int bh = blockIdx.x, tid = threadIdx.x;
    const unsigned* sp = (const unsigned*)(sparsity + (size_t)bh * S_);
    for (int i = tid; i < S_; i += 256) vals[i] = sp[i];

    unsigned prefix = 0;
    int need = U_;
    const int rep = tid & 7;
    for (int level = 0; level < 8; ++level) {
        const int shift = 28 - level * 4;
        if (tid < 128) hist[tid >> 4][tid & 15] = 0;
        __syncthreads();
        const unsigned pmask = (level == 0) ? 0u : (0xFFFFFFFFu << (shift + 4));
        for (int i = tid; i < S_; i += 256) {
            unsigned v = vals[i];
            if ((v & pmask) == prefix)
                atomicAdd(&hist[rep][(v >> shift) & 15], 1u);
        }
        __syncthreads();
        if (tid == 0) {
            int acc = 0, b = 15;
            for (; b > 0; --b) {
                int c = 0;
#pragma unroll
                for (int r = 0; r < 8; ++r) c += (int)hist[r][b];
                if (acc + c >= need) break;
                acc += c;
            }
            prefix_s = prefix | ((unsigned)b << shift);
            need_s = need - acc;
        }
        __syncthreads();
        prefix = prefix_s;
        need = need_s;
        __syncthreads();
    }
    const unsigned T = prefix;
    if (tid == 0) { cnt_gt_s = 0; cnt_eq_s = 0; }
    __syncthreads();
    for (int i = tid; i < S_; i += 256) {
        unsigned v = vals[i];
        if (v > T) {
            int p = atomicAdd(&cnt_gt_s, 1);
            topidx[bh * U_ + p] = i;
        } else if (v == T) {
            int p = atomicAdd(&cnt_eq_s, 1);
            if (p < 64) eqidx[p] = i;
        }
    }
    __syncthreads();
    if (tid == 0) {
        int rem = U_ - cnt_gt_s;
        int n = cnt_eq_s < 64 ? cnt_eq_s : 64;
        for (int a = 0; a < rem; ++a) {
            int best = 1 << 30, bj = 0;
            for (int j = 0; j < n; ++j)
                if (eqidx[j] < best) { best = eqidx[j]; bj = j; }
            topidx[bh * U_ + cnt_gt_s + a] = best;
            eqidx[bj] = 1 << 30;
        }
    }
}

// ---------------------------------------------------------------------------
// Recompute selected Q rows exactly in fp32: selq[bh][q][64]
// ---------------------------------------------------------------------------
__global__ __launch_bounds__(64) void selq_kernel(
    const float* __restrict__ X, const float* __restrict__ Wq,
    const float* __restrict__ bq, const int* __restrict__ topidx,
    float* __restrict__ selq)
{
    const int q = blockIdx.x, bh = blockIdx.y;
    const int b = bh >> 3, h = bh & 7, d = threadIdx.x;
    const int s = topidx[bh * U_ + q];
    const float* xr = X + ((size_t)b * S_ + s) * 512;
    const float* wp = Wq + h * 64 + d;
    float acc = bq[h * 64 + d];
    for (int r = 0; r < 512; ++r)
        acc = fmaf(xr[r], wp[(size_t)r * 512], acc);
    selq[((size_t)bh * U_ + q) * 64 + d] = acc;
}

// ---------------------------------------------------------------------------
// MFMA attention partials (fp16), no-max softmax (|s| bounded ~4).
// Grid (NCHUNK=16, 32 bh), 256 thr.  Block = 512 keys, 4 chunks of 128.
// ---------------------------------------------------------------------------
__global__ __launch_bounds__(256, 2) void attn_mfma(
    const ushortT* __restrict__ Kbuf, const ushortT* __restrict__ VT,
    const float* __restrict__ selq,
    float* __restrict__ pl, float* __restrict__ pacc)
{
    __shared__ float sc[48 * 132];          // scores f32; P fp16 in-place
    __shared__ ushortT Qb[48 * 72];         // Q fp16, scale folded, padded

    const int tid = threadIdx.x;
    const int w = tid >> 6, lane = tid & 63;
    const int quad = lane >> 4, c16 = lane & 15;
    const int bh = blockIdx.y;
    const int s_base = blockIdx.x * 512;

    for (int i = tid; i < 48 * 64; i += 256) {
        int q = i >> 6, d = i & 63;
        float v = (q < U_) ? selq[((size_t)bh * U_ + q) * 64 + d] * 0.125f : 0.f;
        Qb[q * 72 + d] = f2h(v);
    }

    f32x4 O[3];
#pragma unroll
    for (int mt = 0; mt < 3; ++mt) O[mt] = (f32x4){0.f, 0.f, 0.f, 0.f};
    float lacc[12];
#pragma unroll
    for (int qi = 0; qi < 12; ++qi) lacc[qi] = 0.f;

    __syncthreads();

    half8 qa[3][2];
#pragma unroll
    for (int mt = 0; mt < 3; ++mt)
#pragma unroll
        for (int kk = 0; kk < 2; ++kk)
            qa[mt][kk] = *(const half8*)&Qb[(mt * 16 + c16) * 72 + kk * 32 + quad * 8];

    const ushortT* kb  = Kbuf + (size_t)bh * 8192 * 64;
    const ushortT* vtb = VT + ((size_t)bh * 64 + w * 16 + c16) * 8192;

    for (int ci = 0; ci < 4; ++ci) {
        const int s0 = s_base + ci * 128;

        // ---- QK^T: wave w owns keys [32w, 32w+32) ----
        half8 kf[2][2];
#pragma unroll
        for (int nt2 = 0; nt2 < 2; ++nt2)
#pragma unroll
            for (int kk = 0; kk < 2; ++kk)
                kf[nt2][kk] = *(const half8*)&kb[
                    (size_t)(s0 + w * 32 + nt2 * 16 + c16) * 64 + kk * 32 + quad * 8];
        f32x4 sacc[3][2];
#pragma unroll
        for (int mt = 0; mt < 3; ++mt)
#pragma unroll
            for (int nt2 = 0; nt2 < 2; ++nt2) {
                sacc[mt][nt2] = (f32x4){0.f, 0.f, 0.f, 0.f};
#pragma unroll
                for (int kk = 0; kk < 2; ++kk)
                    sacc[mt][nt2] = __builtin_amdgcn_mfma_f32_16x16x32_f16(
                        qa[mt][kk], kf[nt2][kk], sacc[mt][nt2], 0, 0, 0);
            }
#pragma unroll
        for (int mt = 0; mt < 3; ++mt)
#pragma unroll
            for (int nt2 = 0; nt2 < 2; ++nt2)
#pragma unroll
                for (int r = 0; r < 4; ++r)
                    sc[(mt * 16 + quad * 4 + r) * 132 + w * 32 + nt2 * 16 + c16] =
                        sacc[mt][nt2][r];
        __syncthreads();

        // ---- prefetch VT B-frags ----
        half8 vb[4];
#pragma unroll
        for (int kk = 0; kk < 4; ++kk)
            vb[kk] = *(const half8*)&vtb[s0 + kk * 32 + quad * 8];

        // ---- pointwise exp (no max), P fp16 in-place, reg row-sums ----
#pragma unroll
        for (int qi = 0; qi < 12; ++qi) {
            const int q = w * 12 + qi;
            float x0 = sc[q * 132 + lane];
            float x1 = sc[q * 132 + 64 + lane];
            ushortT u0 = f2h(__expf(x0));
            ushortT u1 = f2h(__expf(x1));
            lacc[qi] += h2f(u0) + h2f(u1);
            ushortT* pr = (ushortT*)&sc[q * 132];
            pr[lane] = u0;
            pr[lane + 64] = u1;
        }
        __syncthreads();

        // ---- PV: O += P @ V (wave owns d-tile w*16..+16) ----
#pragma unroll
        for (int mt = 0; mt < 3; ++mt)
#pragma unroll
            for (int kk = 0; kk < 4; ++kk) {
                half8 pa = *(const half8*)((const ushortT*)sc +
                    (size_t)(mt * 16 + c16) * 264 + kk * 32 + quad * 8);
                O[mt] = __builtin_amdgcn_mfma_f32_16x16x32_f16(pa, vb[kk], O[mt], 0, 0, 0);
            }
        __syncthreads();
    }

    // ---- epilogue ----
#pragma unroll
    for (int mt = 0; mt < 3; ++mt)
#pragma unroll
        for (int r = 0; r < 4; ++r) {
            const int q = mt * 16 + quad * 4 + r;
            if (q < U_)
                pacc[(((size_t)bh * NCHUNK + blockIdx.x) * U_ + q) * 64 + w * 16 + c16] =
                    O[mt][r];
        }
#pragma unroll
    for (int qi = 0; qi < 12; ++qi) {
        const int q = w * 12 + qi;
        float ssum = lacc[qi];
#pragma unroll
        for (int off = 1; off < 64; off <<= 1) ssum += __shfl_xor(ssum, off);
        if (lane == 0 && q < U_)
            pl[((size_t)bh * NCHUNK + blockIdx.x) * U_ + q] = ssum;
    }
}

// ---------------------------------------------------------------------------
// Combine chunk partials (plain sums) -> correction (sel_ctx - mean_v)
// ---------------------------------------------------------------------------
__global__ __launch_bounds__(64) void attn_combine(
    const float* __restrict__ pl, const float* __restrict__ pacc,
    const float* __restrict__ vsum, float* __restrict__ corr)
{
    const int q = blockIdx.x, bh = blockIdx.y, d = threadIdx.x;
    const int b = bh >> 3, h = bh & 7;
    float L = 0.f, a = 0.f;
    for (int c = 0; c < NCHUNK; ++c) {
        L += pl[((size_t)bh * NCHUNK + c) * U_ + q];
        a += pacc[(((size_t)bh * NCHUNK + c) * U_ + q) * 64 + d];
    }
    corr[((size_t)bh * U_ + q) * 64 + d] =
        a / L - vsum[b * 512 + h * 64 + d] * (1.0f / S_);
}

// ---------------------------------------------------------------------------
// out_base[b][512] = bo + mean_flat[b] @ Wo
// ---------------------------------------------------------------------------
__global__ __launch_bounds__(512) void outbase_kernel(
    const float* __restrict__ vsum, const float* __restrict__ Wo,
    const float* __restrict__ bo, float* __restrict__ outbase)
{
    const int b = blockIdx.x, d = threadIdx.x;
    float acc = bo[d];
    for (int r = 0; r < 512; ++r) {
        float mv = vsum[b * 512 + r] * (1.0f / S_);
        acc = fmaf(mv, Wo[(size_t)r * 512 + d], acc);
    }
    outbase[b * 512 + d] = acc;
}

// ---------------------------------------------------------------------------
// Broadcast fill: out[b,s,:] = out_base[b,:]
// ---------------------------------------------------------------------------
__global__ __launch_bounds__(256) void fill_kernel(
    const float* __restrict__ outbase, float* __restrict__ out)
{
    size_t gid = (size_t)blockIdx.x * 256 + threadIdx.x;
    size_t e0 = gid * 4;
    int b = (int)(e0 >> 22);          // 8192*512 = 2^22
    int col = (int)(e0 & 511);
    float4 v = *(const float4*)&outbase[b * 512 + col];
    *(float4*)&out[e0] = v;
}

// ---------------------------------------------------------------------------
// Rank-64 corrections: out[b, s_q, :] += corr[bh][q] @ Wo_h
// ---------------------------------------------------------------------------
__global__ __launch_bounds__(512) void correction_kernel(
    const float* __restrict__ corr, const float* __restrict__ Wo,
    const int* __restrict__ topidx, float* __restrict__ out)
{
    const int q = blockIdx.x, bh = blockIdx.y;
    const int b = bh >> 3, h = bh & 7, d = threadIdx.x;
    const int s = topidx[bh * U_ + q];
    const float* cp = corr + ((size_t)bh * U_ + q) * 64;
    float delta = 0.f;
#pragma unroll
    for (int r = 0; r < 64; ++r)
        delta = fmaf(cp[r], Wo[(size_t)(h * 64 + r) * 512 + d], delta);
    atomicAdd(&out[((size_t)b * S_ + s) * 512 + d], delta);
}

// ---------------------------------------------------------------------------
extern "C" void kernel_launch(void* const* d_in, const int* in_sizes, int n_in,
                              void* d_out, int out_size, void* d_ws, size_t ws_size,
                              hipStream_t stream)
{
    const float* X  = (const float*)d_in[0];
    const float* Wq = (const float*)d_in[1];
    const float* bq = (const float*)d_in[2];
    const float* Wk = (const float*)d_in[3];
    const float* bk = (const float*)d_in[4];
    const float* Wv = (const float*)d_in[5];
    const float* bv = (const float*)d_in[6];
    const float* Wo = (const float*)d_in[7];
    const float* bo = (const float*)d_in[8];
    float* out = (float*)d_out;

    char* ws = (char*)d_ws;
    size_t off = 0;
    auto alloc = [&](size_t bytes) {
        void* p = ws + off;
        off = (off + bytes + 255) & ~(size_t)255;
        return p;
    };
    ushortT* Xf   = (ushortT*)alloc((size_t)B_ * S_ * D_ * 2);
    ushortT* Kbuf = (ushortT*)alloc((size_t)B_ * S_ * D_ * 2);
    ushortT* VT   = (ushortT*)alloc((size_t)B_ * S_ * D_ * 2);
    ushortT* WqT  = (ushortT*)alloc((size_t)D_ * D_ * 2);
    ushortT* WkT  = (ushortT*)alloc((size_t)D_ * D_ * 2);
    ushortT* WvT  = (ushortT*)alloc((size_t)D_ * D_ * 2);
    float* sparsity = (float*)alloc((size_t)B_ * H_ * S_ * 4);
    int*   topidx   = (int*)alloc((size_t)B_ * H_ * U_ * 4);
    float* selq     = (float*)alloc((size_t)B_ * H_ * U_ * 64 * 4);
    float* pl       = (float*)alloc((size_t)B_ * H_ * NCHUNK * U_ * 4);
    float* pacc     = (float*)alloc((size_t)B_ * H_ * NCHUNK * U_ * 64 * 4);
    float* corr     = (float*)alloc((size_t)B_ * H_ * U_ * 64 * 4);
    float* vsum     = (float*)alloc((size_t)B_ * 512 * 4);
    float* outbase  = (float*)alloc((size_t)B_ * 512 * 4);

    hipMemsetAsync(vsum, 0, (size_t)B_ * 512 * 4, stream);

    xconv<<<(B_ * S_ * D_) / (256 * 8), 256, 0, stream>>>(X, Xf);
    wprep<<<dim3(16, 16, 3), 256, 0, stream>>>(Wq, Wk, Wv, WqT, WkT, WvT);
    qkv_mfma<<<dim3(256, 12), 256, 0, stream>>>(Xf, WqT, WkT, WvT,
                                                bq, bk, bv, Kbuf, VT,
                                                sparsity, vsum);
    topk_kernel<<<B_ * H_, 256, 0, stream>>>(sparsity, topidx);
    selq_kernel<<<dim3(U_, B_ * H_), 64, 0, stream>>>(X, Wq, bq, topidx, selq);
    attn_mfma<<<dim3(NCHUNK, B_ * H_), 256, 0, stream>>>(Kbuf, VT, selq, pl, pacc);
    attn_combine<<<dim3(U_, B_ * H_), 64, 0, stream>>>(pl, pacc, vsum, corr);
    outbase_kernel<<<B_, 512, 0, stream>>>(vsum, Wo, bo, outbase);
    fill_kernel<<<(B_ * S_ * D_ / 4 + 255) / 256, 256, 0, stream>>>(outbase, out);
    correction_kernel<<<dim3(U_, B_ * H_), 512, 0, stream>>>(corr, Wo, topidx, out);
}

// Round 6
// 333.589 us; speedup vs baseline: 4.9968x; 1.0411x over previous
//
#include <hip/hip_runtime.h>
#include <hip/hip_fp16.h>
#include <math.h>

#define B_ 4
#define S_ 8192
#define D_ 512
#define H_ 8
#define U_ 45            // int(5*ln(8193)) = 45
#define NCHUNK 32        // 256 keys per attention block

typedef unsigned short ushortT;
typedef __attribute__((ext_vector_type(8))) _Float16 half8;
typedef __attribute__((ext_vector_type(4))) float f32x4;

__device__ __forceinline__ ushortT f2h(float f) {
    return __half_as_ushort(__float2half(f));    // RNE
}
__device__ __forceinline__ float h2f(ushortT u) {
    return __half2float(__ushort_as_half(u));
}

__device__ __forceinline__ void gload_lds16(const ushortT* g, ushortT* l) {
    __builtin_amdgcn_global_load_lds(
        (const __attribute__((address_space(1))) void*)g,
        (__attribute__((address_space(3))) void*)l,
        16, 0, 0);
}

// ---------------------------------------------------------------------------
// Pre-pass 1: convert X (fp32) to fp16.  Block 0 also zeroes vsum (2048 f32).
// ---------------------------------------------------------------------------
__global__ __launch_bounds__(256) void xconv(
    const float* __restrict__ X, ushortT* __restrict__ Xf,
    float* __restrict__ vsum)
{
    if (blockIdx.x == 0) {
        float4 z = {0.f, 0.f, 0.f, 0.f};
        *(float4*)&vsum[threadIdx.x * 8]     = z;
        *(float4*)&vsum[threadIdx.x * 8 + 4] = z;
    }
    size_t i = ((size_t)blockIdx.x * 256 + threadIdx.x) * 8;
    float4 a = *(const float4*)(X + i);
    float4 b = *(const float4*)(X + i + 4);
    *(ushort4*)(Xf + i)     = make_ushort4(f2h(a.x), f2h(a.y), f2h(a.z), f2h(a.w));
    *(ushort4*)(Xf + i + 4) = make_ushort4(f2h(b.x), f2h(b.y), f2h(b.z), f2h(b.w));
}

// ---------------------------------------------------------------------------
// Pre-pass 2: transpose + fp16-convert weights.  WT[n][k] = W[k][n].
// ---------------------------------------------------------------------------
__global__ __launch_bounds__(256) void wprep(
    const float* __restrict__ Wq, const float* __restrict__ Wk,
    const float* __restrict__ Wv,
    ushortT* __restrict__ WqT, ushortT* __restrict__ WkT,
    ushortT* __restrict__ WvT)
{
    __shared__ float t[32][33];
    const int z = blockIdx.z;
    const float* W = (z == 0) ? Wq : (z == 1) ? Wk : Wv;
    ushortT* O = (z == 0) ? WqT : (z == 1) ? WkT : WvT;
    const int tx = threadIdx.x & 31, ty4 = (threadIdx.x >> 5) * 4;
    const int r0 = blockIdx.y * 32, c0 = blockIdx.x * 32;
#pragma unroll
    for (int i = 0; i < 4; ++i)
        t[ty4 + i][tx] = W[(size_t)(r0 + ty4 + i) * 512 + c0 + tx];
    __syncthreads();
#pragma unroll
    for (int i = 0; i < 4; ++i)
        O[(size_t)(c0 + ty4 + i) * 512 + r0 + tx] = f2h(t[tx][ty4 + i]);
}

// ---------------------------------------------------------------------------
// MFMA QKV projection, fp16, BK=64 (8 K-iters, 32 MFMA per barrier pair).
// grid (256, 12): y 0-3 Q n-tiles, 4-7 K n-tiles, 8-11 V column-tiles.
// 128x128 tile, 4 waves 2x2, wave = 64x64.  LDS 32KB (A|B 16KB each).
// 8-chunk rotate swizzle: phys16B = (logical + (row&7)) & 7 -> 2-way reads.
// Q -> Qbuf head-major fp16 + sparsity.  K -> Kbuf head-major fp16.
// V -> computed transposed (A=WvT, B=Xf): VT [bh][64][8192] fp16; vsum folded.
// ---------------------------------------------------------------------------
__global__ __launch_bounds__(256, 2) void qkv_mfma(
    const ushortT* __restrict__ Xf,
    const ushortT* __restrict__ WqT, const ushortT* __restrict__ WkT,
    const ushortT* __restrict__ WvT,
    const float* __restrict__ bq, const float* __restrict__ bk,
    const float* __restrict__ bv,
    ushortT* __restrict__ Qbuf, ushortT* __restrict__ Kbuf,
    ushortT* __restrict__ VT,
    float* __restrict__ sparsity, float* __restrict__ vsum)
{
    __shared__ ushortT lds[2 * 128 * 64];   // A | B, 16KB each
    ushortT* As = lds;
    ushortT* Bs = lds + 8192;

    const int tid  = threadIdx.x;
    const int w    = tid >> 6, lane = tid & 63;
    const int quad = lane >> 4, c16 = lane & 15;
    const int wr   = w >> 1,  wc  = w & 1;
    const int mat  = blockIdx.y >> 2;        // 0=Q 1=K 2=V
    const int nt   = blockIdx.y & 3;
    const int m0   = blockIdx.x * 128;
    const int n0   = nt * 128;

    // staging: pass c covers rows [32c,32c+32); wave w rows 8w..8w+8
    const int srowL = lane >> 3;                           // 0..7 within wave
    const int slc   = (((lane & 7) - (srowL & 7)) & 7) * 8; // logical chunk (halves)
    // fragment read swizzle
    const int rrot  = c16 & 7;

    const ushortT* Ag = (mat == 2) ? WvT : Xf;
    const ushortT* Bg = (mat == 0) ? WqT : (mat == 1) ? WkT : Xf;
    const int arow0 = (mat == 2) ? n0 : m0;
    const int brow0 = (mat == 2) ? m0 : n0;

    f32x4 acc[4][4];
#pragma unroll
    for (int i = 0; i < 4; ++i)
#pragma unroll
        for (int j = 0; j < 4; ++j) acc[i][j] = (f32x4){0.f, 0.f, 0.f, 0.f};

    for (int k0 = 0; k0 < 512; k0 += 64) {
        __syncthreads();
#pragma unroll
        for (int c = 0; c < 4; ++c) {
            const int R = c * 32 + w * 8 + srowL;
            const int lbase = c * 2048 + w * 512;          // halves
            gload_lds16(Ag + (size_t)(arow0 + R) * 512 + k0 + slc, As + lbase);
            gload_lds16(Bg + (size_t)(brow0 + R) * 512 + k0 + slc, Bs + lbase);
        }
        __syncthreads();
#pragma unroll
        for (int kk = 0; kk < 2; ++kk) {
            const int phk = (((kk * 4 + quad) + rrot) & 7) * 8;
            half8 af[4], bf[4];
#pragma unroll
            for (int i = 0; i < 4; ++i) {
                af[i] = *(const half8*)&As[(wr * 64 + i * 16 + c16) * 64 + phk];
                bf[i] = *(const half8*)&Bs[(wc * 64 + i * 16 + c16) * 64 + phk];
            }
#pragma unroll
            for (int i = 0; i < 4; ++i)
#pragma unroll
                for (int j = 0; j < 4; ++j)
                    acc[i][j] = __builtin_amdgcn_mfma_f32_16x16x32_f16(af[i], bf[j], acc[i][j], 0, 0, 0);
        }
    }

    // ---- epilogue ----
    if (mat == 0) {
        // Q: store head-major fp16 + sparsity (sum of squares per row)
        const int b = m0 >> 13;
        const int head = (n0 + wc * 64) >> 6;
        float bb[4];
#pragma unroll
        for (int j = 0; j < 4; ++j) bb[j] = bq[n0 + wc * 64 + j * 16 + c16];
        ushortT* qbase = Qbuf + ((size_t)(b * 8 + head) * 8192) * 64;
#pragma unroll
        for (int i = 0; i < 4; ++i)
#pragma unroll
            for (int r = 0; r < 4; ++r) {
                const int s = (m0 & 8191) + wr * 64 + i * 16 + quad * 4 + r;
                float p = 0.f;
#pragma unroll
                for (int j = 0; j < 4; ++j) {
                    float v = acc[i][j][r] + bb[j];
                    qbase[(size_t)s * 64 + j * 16 + c16] = f2h(v);
                    p = fmaf(v, v, p);
                }
                p += __shfl_xor(p, 1);
                p += __shfl_xor(p, 2);
                p += __shfl_xor(p, 4);
                p += __shfl_xor(p, 8);
                if (c16 == 0)
                    sparsity[((size_t)b * H_ + head) * S_ + s] = p;
            }
    } else if (mat == 1) {
        const int b = m0 >> 13;
        const int head = (n0 + wc * 64) >> 6;
        float bb[4];
#pragma unroll
        for (int j = 0; j < 4; ++j) bb[j] = bk[n0 + wc * 64 + j * 16 + c16];
        ushortT* kbase = Kbuf + ((size_t)(b * 8 + head) * 8192) * 64;
#pragma unroll
        for (int i = 0; i < 4; ++i)
#pragma unroll
            for (int r = 0; r < 4; ++r) {
                const int s = (m0 & 8191) + wr * 64 + i * 16 + quad * 4 + r;
#pragma unroll
                for (int j = 0; j < 4; ++j)
                    kbase[(size_t)s * 64 + j * 16 + c16] = f2h(acc[i][j][r] + bb[j]);
            }
    } else {
        // V transposed: VT[((b*8+head)*64 + dd)*8192 + s]
        const int b = m0 >> 13;
        const int sbase = (m0 & 8191) + wc * 64;
#pragma unroll
        for (int i = 0; i < 4; ++i)
#pragma unroll
            for (int r = 0; r < 4; ++r) {
                const int dcol = n0 + wr * 64 + i * 16 + quad * 4 + r;
                const int head = dcol >> 6, dd = dcol & 63;
                const float biasv = bv[dcol];
                ushortT* vrow = VT + ((size_t)(b * 8 + head) * 64 + dd) * 8192;
                float vsa = 0.f;
#pragma unroll
                for (int j = 0; j < 4; ++j) {
                    float v = acc[i][j][r] + biasv;
                    vrow[sbase + j * 16 + c16] = f2h(v);
                    vsa += v;
                }
                vsa += __shfl_xor(vsa, 1);
                vsa += __shfl_xor(vsa, 2);
                vsa += __shfl_xor(vsa, 4);
                vsa += __shfl_xor(vsa, 8);
                if (c16 == 0) atomicAdd(&vsum[b * 512 + dcol], vsa);
            }
    }
}

// ---------------------------------------------------------------------------
// Top-45 per (b,h) via radix-select on fp32 bits (values >= 0).
// ---------------------------------------------------------------------------
__global__ __launch_bounds__(256) void topk_kernel(
    const float* __restrict__ sparsity, int* __restrict__ topidx)
{
    __shared__ unsigned vals[S_];        // 32 KB
    __shared__ unsigned hist[8][16];
    __shared__ unsigned prefix_s;
    __shared__ int need_s;
    __shared__ int cnt_gt_s, cnt_eq_s;
    __shared__ int eqidx[64];
    const int bh = blockIdx.x, tid = threadIdx.x;
    const unsigned* sp = (const unsigned*)(sparsity + (size_t)bh * S_);
    for (int i = tid; i < S_; i += 256) vals[i] = sp[i];

    unsigned prefix = 0;
    int need = U_;
    const int rep = tid & 7;
    for (int level = 0; level < 8; ++level) {
        const int shift = 28 - level * 4;
        if (tid < 128) hist[tid >> 4][tid & 15] = 0;
        __syncthreads();
        const unsigned pmask = (level == 0) ? 0u : (0xFFFFFFFFu << (shift + 4));
        for (int i = tid; i < S_; i += 256) {
            unsigned v = vals[i];
            if ((v & pmask) == prefix)
                atomicAdd(&hist[rep][(v >> shift) & 15], 1u);
        }
        __syncthreads();
        if (tid == 0) {
            int acc = 0, b = 15;
            for (; b > 0; --b) {
                int c = 0;
#pragma unroll
                for (int r = 0; r < 8; ++r) c += (int)hist[r][b];
                if (acc + c >= need) break;
                acc += c;
            }
            prefix_s = prefix | ((unsigned)b << shift);
            need_s = need - acc;
        }
        __syncthreads();
        prefix = prefix_s;
        need = need_s;
        __syncthreads();
    }
    const unsigned T = prefix;
    if (tid == 0) { cnt_gt_s = 0; cnt_eq_s = 0; }
    __syncthreads();
    for (int i = tid; i < S_; i += 256) {
        unsigned v = vals[i];
        if (v > T) {
            int p = atomicAdd(&cnt_gt_s, 1);
            topidx[bh * U_ + p] = i;
        } else if (v == T) {
            int p = atomicAdd(&cnt_eq_s, 1);
            if (p < 64) eqidx[p] = i;
        }
    }
    __syncthreads();
    if (tid == 0) {
        int rem = U_ - cnt_gt_s;
        int n = cnt_eq_s < 64 ? cnt_eq_s : 64;
        for (int a = 0; a < rem; ++a) {
            int best = 1 << 30, bj = 0;
            for (int j = 0; j < n; ++j)
                if (eqidx[j] < best) { best = eqidx[j]; bj = j; }
            topidx[bh * U_ + cnt_gt_s + a] = best;
            eqidx[bj] = 1 << 30;
        }
    }
}

// ---------------------------------------------------------------------------
// MFMA attention partials (fp16), no-max softmax (|s| bounded ~4).
// Grid (NCHUNK=32, 32 bh), 256 thr.  Block = 256 keys, 2 chunks of 128.
// Q gathered directly from Qbuf via topidx (selq kernel eliminated).
// ---------------------------------------------------------------------------
__global__ __launch_bounds__(256, 2) void attn_mfma(
    const ushortT* __restrict__ Qbuf, const ushortT* __restrict__ Kbuf,
    const ushortT* __restrict__ VT, const int* __restrict__ topidx,
    float* __restrict__ pl, float* __restrict__ pacc)
{
    __shared__ float sc[48 * 132];          // scores f32; P fp16 in-place
    __shared__ ushortT Qb[48 * 72];         // Q fp16, scale folded, padded

    const int tid = threadIdx.x;
    const int w = tid >> 6, lane = tid & 63;
    const int quad = lane >> 4, c16 = lane & 15;
    const int bh = blockIdx.y;
    const int s_base = blockIdx.x * 256;

    for (int i = tid; i < 48 * 64; i += 256) {
        int q = i >> 6, d = i & 63;
        float v = 0.f;
        if (q < U_) {
            int s = topidx[bh * U_ + q];
            v = h2f(Qbuf[((size_t)bh * 8192 + s) * 64 + d]) * 0.125f;
        }
        Qb[q * 72 + d] = f2h(v);
    }

    f32x4 O[3];
#pragma unroll
    for (int mt = 0; mt < 3; ++mt) O[mt] = (f32x4){0.f, 0.f, 0.f, 0.f};
    float lacc[12];
#pragma unroll
    for (int qi = 0; qi < 12; ++qi) lacc[qi] = 0.f;

    __syncthreads();

    half8 qa[3][2];
#pragma unroll
    for (int mt = 0; mt < 3; ++mt)
#pragma unroll
        for (int kk = 0; kk < 2; ++kk)
            qa[mt][kk] = *(const half8*)&Qb[(mt * 16 + c16) * 72 + kk * 32 + quad * 8];

    const ushortT* kb  = Kbuf + (size_t)bh * 8192 * 64;
    const ushortT* vtb = VT + ((size_t)bh * 64 + w * 16 + c16) * 8192;

    for (int ci = 0; ci < 2; ++ci) {
        const int s0 = s_base + ci * 128;

        // ---- QK^T: wave w owns keys [32w, 32w+32) ----
        half8 kf[2][2];
#pragma unroll
        for (int nt2 = 0; nt2 < 2; ++nt2)
#pragma unroll
            for (int kk = 0; kk < 2; ++kk)
                kf[nt2][kk] = *(const half8*)&kb[
                    (size_t)(s0 + w * 32 + nt2 * 16 + c16) * 64 + kk * 32 + quad * 8];
        f32x4 sacc[3][2];
#pragma unroll
        for (int mt = 0; mt < 3; ++mt)
#pragma unroll
            for (int nt2 = 0; nt2 < 2; ++nt2) {
                sacc[mt][nt2] = (f32x4){0.f, 0.f, 0.f, 0.f};
#pragma unroll
                for (int kk = 0; kk < 2; ++kk)
                    sacc[mt][nt2] = __builtin_amdgcn_mfma_f32_16x16x32_f16(
                        qa[mt][kk], kf[nt2][kk], sacc[mt][nt2], 0, 0, 0);
            }
#pragma unroll
        for (int mt = 0; mt < 3; ++mt)
#pragma unroll
            for (int nt2 = 0; nt2 < 2; ++nt2)
#pragma unroll
                for (int r = 0; r < 4; ++r)
                    sc[(mt * 16 + quad * 4 + r) * 132 + w * 32 + nt2 * 16 + c16] =
                        sacc[mt][nt2][r];
        __syncthreads();

        // ---- prefetch VT B-frags ----
        half8 vb[4];
#pragma unroll
        for (int kk = 0; kk < 4; ++kk)
            vb[kk] = *(const half8*)&vtb[s0 + kk * 32 + quad * 8];

        // ---- pointwise exp (no max), P fp16 in-place, reg row-sums ----
#pragma unroll
        for (int qi = 0; qi < 12; ++qi) {
            const int q = w * 12 + qi;
            float x0 = sc[q * 132 + lane];
            float x1 = sc[q * 132 + 64 + lane];
            ushortT u0 = f2h(__expf(x0));
            ushortT u1 = f2h(__expf(x1));
            lacc[qi] += h2f(u0) + h2f(u1);
            ushortT* pr = (ushortT*)&sc[q * 132];
            pr[lane] = u0;
            pr[lane + 64] = u1;
        }
        __syncthreads();

        // ---- PV: O += P @ V (wave owns d-tile w*16..+16) ----
#pragma unroll
        for (int mt = 0; mt < 3; ++mt)
#pragma unroll
            for (int kk = 0; kk < 4; ++kk) {
                half8 pa = *(const half8*)((const ushortT*)sc +
                    (size_t)(mt * 16 + c16) * 264 + kk * 32 + quad * 8);
                O[mt] = __builtin_amdgcn_mfma_f32_16x16x32_f16(pa, vb[kk], O[mt], 0, 0, 0);
            }
        __syncthreads();
    }

    // ---- epilogue ----
#pragma unroll
    for (int mt = 0; mt < 3; ++mt)
#pragma unroll
        for (int r = 0; r < 4; ++r) {
            const int q = mt * 16 + quad * 4 + r;
            if (q < U_)
                pacc[(((size_t)bh * NCHUNK + blockIdx.x) * U_ + q) * 64 + w * 16 + c16] =
                    O[mt][r];
        }
#pragma unroll
    for (int qi = 0; qi < 12; ++qi) {
        const int q = w * 12 + qi;
        float ssum = lacc[qi];
#pragma unroll
        for (int off = 1; off < 64; off <<= 1) ssum += __shfl_xor(ssum, off);
        if (lane == 0 && q < U_)
            pl[((size_t)bh * NCHUNK + blockIdx.x) * U_ + q] = ssum;
    }
}

// ---------------------------------------------------------------------------
// out_base[b][512] = bo + mean_flat[b] @ Wo
// ---------------------------------------------------------------------------
__global__ __launch_bounds__(512) void outbase_kernel(
    const float* __restrict__ vsum, const float* __restrict__ Wo,
    const float* __restrict__ bo, float* __restrict__ outbase)
{
    const int b = blockIdx.x, d = threadIdx.x;
    float acc = bo[d];
    for (int r = 0; r < 512; ++r) {
        float mv = vsum[b * 512 + r] * (1.0f / S_);
        acc = fmaf(mv, Wo[(size_t)r * 512 + d], acc);
    }
    outbase[b * 512 + d] = acc;
}

// ---------------------------------------------------------------------------
// Broadcast fill: out[b,s,:] = out_base[b,:]
// ---------------------------------------------------------------------------
__global__ __launch_bounds__(256) void fill_kernel(
    const float* __restrict__ outbase, float* __restrict__ out)
{
    size_t gid = (size_t)blockIdx.x * 256 + threadIdx.x;
    size_t e0 = gid * 4;
    int b = (int)(e0 >> 22);          // 8192*512 = 2^22
    int col = (int)(e0 & 511);
    float4 v = *(const float4*)&outbase[b * 512 + col];
    *(float4*)&out[e0] = v;
}

// ---------------------------------------------------------------------------
// Merged combine + correction: block (q, bh).
// Phase 1 (64 thr): corr = sum(pacc)/sum(pl) - mean_v.
// Phase 2 (512 thr): out[b, s_q, :] += corr @ Wo_h  (atomic, s may repeat
// across heads).
// ---------------------------------------------------------------------------
__global__ __launch_bounds__(512) void corr_out_kernel(
    const float* __restrict__ pl, const float* __restrict__ pacc,
    const float* __restrict__ vsum, const float* __restrict__ Wo,
    const int* __restrict__ topidx, float* __restrict__ out)
{
    __shared__ float corrS[64];
    const int q = blockIdx.x, bh = blockIdx.y;
    const int b = bh >> 3, h = bh & 7, tid = threadIdx.x;
    if (tid < 64) {
        float L = 0.f, a = 0.f;
        for (int c = 0; c < NCHUNK; ++c) {
            L += pl[((size_t)bh * NCHUNK + c) * U_ + q];
            a += pacc[(((size_t)bh * NCHUNK + c) * U_ + q) * 64 + tid];
        }
        corrS[tid] = a / L - vsum[b * 512 + h * 64 + tid] * (1.0f / S_);
    }
    __syncthreads();
    const int s = topidx[bh * U_ + q];
    const int d = tid;
    float delta = 0.f;
#pragma unroll
    for (int r = 0; r < 64; ++r)
        delta = fmaf(corrS[r], Wo[(size_t)(h * 64 + r) * 512 + d], delta);
    atomicAdd(&out[((size_t)b * S_ + s) * 512 + d], delta);
}

// ---------------------------------------------------------------------------
extern "C" void kernel_launch(void* const* d_in, const int* in_sizes, int n_in,
                              void* d_out, int out_size, void* d_ws, size_t ws_size,
                              hipStream_t stream)
{
    const float* X  = (const float*)d_in[0];
    const float* Wq = (const float*)d_in[1];
    const float* bq = (const float*)d_in[2];
    const float* Wk = (const float*)d_in[3];
    const float* bk = (const float*)d_in[4];
    const float* Wv = (const float*)d_in[5];
    const float* bv = (const float*)d_in[6];
    const float* Wo = (const float*)d_in[7];
    const float* bo = (const float*)d_in[8];
    float* out = (float*)d_out;

    char* ws = (char*)d_ws;
    size_t off = 0;
    auto alloc = [&](size_t bytes) {
        void* p = ws + off;
        off = (off + bytes + 255) & ~(size_t)255;
        return p;
    };
    ushortT* Xf   = (ushortT*)alloc((size_t)B_ * S_ * D_ * 2);
    ushortT* Qbuf = (ushortT*)alloc((size_t)B_ * S_ * D_ * 2);
    ushortT* Kbuf = (ushortT*)alloc((size_t)B_ * S_ * D_ * 2);
    ushortT* VT   = (ushortT*)alloc((size_t)B_ * S_ * D_ * 2);
    ushortT* WqT  = (ushortT*)alloc((size_t)D_ * D_ * 2);
    ushortT* WkT  = (ushortT*)alloc((size_t)D_ * D_ * 2);
    ushortT* WvT  = (ushortT*)alloc((size_t)D_ * D_ * 2);
    float* sparsity = (float*)alloc((size_t)B_ * H_ * S_ * 4);
    int*   topidx   = (int*)alloc((size_t)B_ * H_ * U_ * 4);
    float* pl       = (float*)alloc((size_t)B_ * H_ * NCHUNK * U_ * 4);
    float* pacc     = (float*)alloc((size_t)B_ * H_ * NCHUNK * U_ * 64 * 4);
    float* vsum     = (float*)alloc((size_t)B_ * 512 * 4);
    float* outbase  = (float*)alloc((size_t)B_ * 512 * 4);

    xconv<<<(B_ * S_ * D_) / (256 * 8), 256, 0, stream>>>(X, Xf, vsum);
    wprep<<<dim3(16, 16, 3), 256, 0, stream>>>(Wq, Wk, Wv, WqT, WkT, WvT);
    qkv_mfma<<<dim3(256, 12), 256, 0, stream>>>(Xf, WqT, WkT, WvT,
                                                bq, bk, bv, Qbuf, Kbuf, VT,
                                                sparsity, vsum);
    topk_kernel<<<B_ * H_, 256, 0, stream>>>(sparsity, topidx);
    attn_mfma<<<dim3(NCHUNK, B_ * H_), 256, 0, stream>>>(Qbuf, Kbuf, VT, topidx,
                                                         pl, pacc);
    outbase_kernel<<<B_, 512, 0, stream>>>(vsum, Wo, bo, outbase);
    fill_kernel<<<(B_ * S_ * D_ / 4 + 255) / 256, 256, 0, stream>>>(outbase, out);
    corr_out_kernel<<<dim3(U_, B_ * H_), 512, 0, stream>>>(pl, pacc, vsum, Wo,
                                                           topidx, out);
}

// Round 7
// 312.109 us; speedup vs baseline: 5.3407x; 1.0688x over previous
//
#include <hip/hip_runtime.h>
#include <hip/hip_fp16.h>
#include <math.h>

#define B_ 4
#define S_ 8192
#define D_ 512
#define H_ 8
#define U_ 45            // int(5*ln(8193)) = 45
#define NCHUNK 32        // 256 keys per attention block

typedef unsigned short ushortT;
typedef __attribute__((ext_vector_type(8))) _Float16 half8;
typedef __attribute__((ext_vector_type(4))) float f32x4;

__device__ __forceinline__ ushortT f2h(float f) {
    return __half_as_ushort(__float2half(f));    // RNE
}
__device__ __forceinline__ float h2f(ushortT u) {
    return __half2float(__ushort_as_half(u));
}

__device__ __forceinline__ void gload_lds16(const ushortT* g, ushortT* l) {
    __builtin_amdgcn_global_load_lds(
        (const __attribute__((address_space(1))) void*)g,
        (__attribute__((address_space(3))) void*)l,
        16, 0, 0);
}

// ---------------------------------------------------------------------------
// Pre-pass 1: convert X (fp32) to fp16.  Block 0 zeroes vsum + outbase.
// ---------------------------------------------------------------------------
__global__ __launch_bounds__(256) void xconv(
    const float* __restrict__ X, ushortT* __restrict__ Xf,
    float* __restrict__ vsum, float* __restrict__ outbase)
{
    if (blockIdx.x == 0) {
        float4 z = {0.f, 0.f, 0.f, 0.f};
        *(float4*)&vsum[threadIdx.x * 8]        = z;
        *(float4*)&vsum[threadIdx.x * 8 + 4]    = z;
        *(float4*)&outbase[threadIdx.x * 8]     = z;
        *(float4*)&outbase[threadIdx.x * 8 + 4] = z;
    }
    size_t i = ((size_t)blockIdx.x * 256 + threadIdx.x) * 8;
    float4 a = *(const float4*)(X + i);
    float4 b = *(const float4*)(X + i + 4);
    *(ushort4*)(Xf + i)     = make_ushort4(f2h(a.x), f2h(a.y), f2h(a.z), f2h(a.w));
    *(ushort4*)(Xf + i + 4) = make_ushort4(f2h(b.x), f2h(b.y), f2h(b.z), f2h(b.w));
}

// ---------------------------------------------------------------------------
// Pre-pass 2: transpose + fp16-convert weights.  WT[n][k] = W[k][n].
// ---------------------------------------------------------------------------
__global__ __launch_bounds__(256) void wprep(
    const float* __restrict__ Wq, const float* __restrict__ Wk,
    const float* __restrict__ Wv,
    ushortT* __restrict__ WqT, ushortT* __restrict__ WkT,
    ushortT* __restrict__ WvT)
{
    __shared__ float t[32][33];
    const int z = blockIdx.z;
    const float* W = (z == 0) ? Wq : (z == 1) ? Wk : Wv;
    ushortT* O = (z == 0) ? WqT : (z == 1) ? WkT : WvT;
    const int tx = threadIdx.x & 31, ty4 = (threadIdx.x >> 5) * 4;
    const int r0 = blockIdx.y * 32, c0 = blockIdx.x * 32;
#pragma unroll
    for (int i = 0; i < 4; ++i)
        t[ty4 + i][tx] = W[(size_t)(r0 + ty4 + i) * 512 + c0 + tx];
    __syncthreads();
#pragma unroll
    for (int i = 0; i < 4; ++i)
        O[(size_t)(c0 + ty4 + i) * 512 + r0 + tx] = f2h(t[tx][ty4 + i]);
}

// ---------------------------------------------------------------------------
// MFMA QKV projection, fp16, BK=64 (8 K-iters, 32 MFMA per barrier pair).
// grid (256, 12): y 0-3 Q n-tiles, 4-7 K n-tiles, 8-11 V column-tiles.
// 128x128 tile, 4 waves 2x2, wave = 64x64.  LDS 32KB -> 4 blocks/CU
// (launch_bounds min-waves 4; VGPR 64 <= 128 cap).
// 8-chunk rotate swizzle keeps ds_read 2-way (free, verified 0 conflicts).
// ---------------------------------------------------------------------------
__global__ __launch_bounds__(256, 4) void qkv_mfma(
    const ushortT* __restrict__ Xf,
    const ushortT* __restrict__ WqT, const ushortT* __restrict__ WkT,
    const ushortT* __restrict__ WvT,
    const float* __restrict__ bq, const float* __restrict__ bk,
    const float* __restrict__ bv,
    ushortT* __restrict__ Qbuf, ushortT* __restrict__ Kbuf,
    ushortT* __restrict__ VT,
    float* __restrict__ sparsity, float* __restrict__ vsum)
{
    __shared__ ushortT lds[2 * 128 * 64];   // A | B, 16KB each
    ushortT* As = lds;
    ushortT* Bs = lds + 8192;

    const int tid  = threadIdx.x;
    const int w    = tid >> 6, lane = tid & 63;
    const int quad = lane >> 4, c16 = lane & 15;
    const int wr   = w >> 1,  wc  = w & 1;
    const int mat  = blockIdx.y >> 2;        // 0=Q 1=K 2=V
    const int nt   = blockIdx.y & 3;
    const int m0   = blockIdx.x * 128;
    const int n0   = nt * 128;

    // staging: pass c covers rows [32c,32c+32); wave w rows 8w..8w+8
    const int srowL = lane >> 3;                           // 0..7 within wave
    const int slc   = (((lane & 7) - (srowL & 7)) & 7) * 8; // logical chunk (halves)
    const int rrot  = c16 & 7;

    const ushortT* Ag = (mat == 2) ? WvT : Xf;
    const ushortT* Bg = (mat == 0) ? WqT : (mat == 1) ? WkT : Xf;
    const int arow0 = (mat == 2) ? n0 : m0;
    const int brow0 = (mat == 2) ? m0 : n0;

    f32x4 acc[4][4];
#pragma unroll
    for (int i = 0; i < 4; ++i)
#pragma unroll
        for (int j = 0; j < 4; ++j) acc[i][j] = (f32x4){0.f, 0.f, 0.f, 0.f};

    for (int k0 = 0; k0 < 512; k0 += 64) {
        __syncthreads();
#pragma unroll
        for (int c = 0; c < 4; ++c) {
            const int R = c * 32 + w * 8 + srowL;
            const int lbase = c * 2048 + w * 512;          // halves
            gload_lds16(Ag + (size_t)(arow0 + R) * 512 + k0 + slc, As + lbase);
            gload_lds16(Bg + (size_t)(brow0 + R) * 512 + k0 + slc, Bs + lbase);
        }
        __syncthreads();
#pragma unroll
        for (int kk = 0; kk < 2; ++kk) {
            const int phk = (((kk * 4 + quad) + rrot) & 7) * 8;
            half8 af[4], bf[4];
#pragma unroll
            for (int i = 0; i < 4; ++i) {
                af[i] = *(const half8*)&As[(wr * 64 + i * 16 + c16) * 64 + phk];
                bf[i] = *(const half8*)&Bs[(wc * 64 + i * 16 + c16) * 64 + phk];
            }
#pragma unroll
            for (int i = 0; i < 4; ++i)
#pragma unroll
                for (int j = 0; j < 4; ++j)
                    acc[i][j] = __builtin_amdgcn_mfma_f32_16x16x32_f16(af[i], bf[j], acc[i][j], 0, 0, 0);
        }
    }

    // ---- epilogue ----
    if (mat == 0) {
        // Q: store head-major fp16 + sparsity (sum of squares per row)
        const int b = m0 >> 13;
        const int head = (n0 + wc * 64) >> 6;
        float bb[4];
#pragma unroll
        for (int j = 0; j < 4; ++j) bb[j] = bq[n0 + wc * 64 + j * 16 + c16];
        ushortT* qbase = Qbuf + ((size_t)(b * 8 + head) * 8192) * 64;
#pragma unroll
        for (int i = 0; i < 4; ++i)
#pragma unroll
            for (int r = 0; r < 4; ++r) {
                const int s = (m0 & 8191) + wr * 64 + i * 16 + quad * 4 + r;
                float p = 0.f;
#pragma unroll
                for (int j = 0; j < 4; ++j) {
                    float v = acc[i][j][r] + bb[j];
                    qbase[(size_t)s * 64 + j * 16 + c16] = f2h(v);
                    p = fmaf(v, v, p);
                }
                p += __shfl_xor(p, 1);
                p += __shfl_xor(p, 2);
                p += __shfl_xor(p, 4);
                p += __shfl_xor(p, 8);
                if (c16 == 0)
                    sparsity[((size_t)b * H_ + head) * S_ + s] = p;
            }
    } else if (mat == 1) {
        const int b = m0 >> 13;
        const int head = (n0 + wc * 64) >> 6;
        float bb[4];
#pragma unroll
        for (int j = 0; j < 4; ++j) bb[j] = bk[n0 + wc * 64 + j * 16 + c16];
        ushortT* kbase = Kbuf + ((size_t)(b * 8 + head) * 8192) * 64;
#pragma unroll
        for (int i = 0; i < 4; ++i)
#pragma unroll
            for (int r = 0; r < 4; ++r) {
                const int s = (m0 & 8191) + wr * 64 + i * 16 + quad * 4 + r;
#pragma unroll
                for (int j = 0; j < 4; ++j)
                    kbase[(size_t)s * 64 + j * 16 + c16] = f2h(acc[i][j][r] + bb[j]);
            }
    } else {
        // V transposed: VT[((b*8+head)*64 + dd)*8192 + s]
        const int b = m0 >> 13;
        const int sbase = (m0 & 8191) + wc * 64;
#pragma unroll
        for (int i = 0; i < 4; ++i)
#pragma unroll
            for (int r = 0; r < 4; ++r) {
                const int dcol = n0 + wr * 64 + i * 16 + quad * 4 + r;
                const int head = dcol >> 6, dd = dcol & 63;
                const float biasv = bv[dcol];
                ushortT* vrow = VT + ((size_t)(b * 8 + head) * 64 + dd) * 8192;
                float vsa = 0.f;
#pragma unroll
                for (int j = 0; j < 4; ++j) {
                    float v = acc[i][j][r] + biasv;
                    vrow[sbase + j * 16 + c16] = f2h(v);
                    vsa += v;
                }
                vsa += __shfl_xor(vsa, 1);
                vsa += __shfl_xor(vsa, 2);
                vsa += __shfl_xor(vsa, 4);
                vsa += __shfl_xor(vsa, 8);
                if (c16 == 0) atomicAdd(&vsum[b * 512 + dcol], vsa);
            }
    }
}

// ---------------------------------------------------------------------------
// Top-45 per (b,h) via radix-select on fp32 bits (values >= 0).
// ---------------------------------------------------------------------------
__global__ __launch_bounds__(256) void topk_kernel(
    const float* __restrict__ sparsity, int* __restrict__ topidx)
{
    __shared__ unsigned vals[S_];        // 32 KB
    __shared__ unsigned hist[8][16];
    __shared__ unsigned prefix_s;
    __shared__ int need_s;
    __shared__ int cnt_gt_s, cnt_eq_s;
    __shared__ int eqidx[64];
    const int bh = blockIdx.x, tid = threadIdx.x;
    const unsigned* sp = (const unsigned*)(sparsity + (size_t)bh * S_);
    for (int i = tid; i < S_; i += 256) vals[i] = sp[i];

    unsigned prefix = 0;
    int need = U_;
    const int rep = tid & 7;
    for (int level = 0; level < 8; ++level) {
        const int shift = 28 - level * 4;
        if (tid < 128) hist[tid >> 4][tid & 15] = 0;
        __syncthreads();
        const unsigned pmask = (level == 0) ? 0u : (0xFFFFFFFFu << (shift + 4));
        for (int i = tid; i < S_; i += 256) {
            unsigned v = vals[i];
            if ((v & pmask) == prefix)
                atomicAdd(&hist[rep][(v >> shift) & 15], 1u);
        }
        __syncthreads();
        if (tid == 0) {
            int acc = 0, b = 15;
            for (; b > 0; --b) {
                int c = 0;
#pragma unroll
                for (int r = 0; r < 8; ++r) c += (int)hist[r][b];
                if (acc + c >= need) break;
                acc += c;
            }
            prefix_s = prefix | ((unsigned)b << shift);
            need_s = need - acc;
        }
        __syncthreads();
        prefix = prefix_s;
        need = need_s;
        __syncthreads();
    }
    const unsigned T = prefix;
    if (tid == 0) { cnt_gt_s = 0; cnt_eq_s = 0; }
    __syncthreads();
    for (int i = tid; i < S_; i += 256) {
        unsigned v = vals[i];
        if (v > T) {
            int p = atomicAdd(&cnt_gt_s, 1);
            topidx[bh * U_ + p] = i;
        } else if (v == T) {
            int p = atomicAdd(&cnt_eq_s, 1);
            if (p < 64) eqidx[p] = i;
        }
    }
    __syncthreads();
    if (tid == 0) {
        int rem = U_ - cnt_gt_s;
        int n = cnt_eq_s < 64 ? cnt_eq_s : 64;
        for (int a = 0; a < rem; ++a) {
            int best = 1 << 30, bj = 0;
            for (int j = 0; j < n; ++j)
                if (eqidx[j] < best) { best = eqidx[j]; bj = j; }
            topidx[bh * U_ + cnt_gt_s + a] = best;
            eqidx[bj] = 1 << 30;
        }
    }
}

// ---------------------------------------------------------------------------
// MFMA attention partials (fp16), no-max softmax (|s| bounded ~4).
// Grid (NCHUNK=32, 32 bh), 256 thr.  Block = 256 keys, 2 chunks of 128.
// LDS 32.3KB -> 4 blocks/CU via launch_bounds min-waves 4.
// ---------------------------------------------------------------------------
__global__ __launch_bounds__(256, 4) void attn_mfma(
    const ushortT* __restrict__ Qbuf, const ushortT* __restrict__ Kbuf,
    const ushortT* __restrict__ VT, const int* __restrict__ topidx,
    float* __restrict__ pl, float* __restrict__ pacc)
{
    __shared__ float sc[48 * 132];          // scores f32; P fp16 in-place
    __shared__ ushortT Qb[48 * 72];         // Q fp16, scale folded, padded

    const int tid = threadIdx.x;
    const int w = tid >> 6, lane = tid & 63;
    const int quad = lane >> 4, c16 = lane & 15;
    const int bh = blockIdx.y;
    const int s_base = blockIdx.x * 256;

    for (int i = tid; i < 48 * 64; i += 256) {
        int q = i >> 6, d = i & 63;
        float v = 0.f;
        if (q < U_) {
            int s = topidx[bh * U_ + q];
            v = h2f(Qbuf[((size_t)bh * 8192 + s) * 64 + d]) * 0.125f;
        }
        Qb[q * 72 + d] = f2h(v);
    }

    f32x4 O[3];
#pragma unroll
    for (int mt = 0; mt < 3; ++mt) O[mt] = (f32x4){0.f, 0.f, 0.f, 0.f};
    float lacc[12];
#pragma unroll
    for (int qi = 0; qi < 12; ++qi) lacc[qi] = 0.f;

    __syncthreads();

    half8 qa[3][2];
#pragma unroll
    for (int mt = 0; mt < 3; ++mt)
#pragma unroll
        for (int kk = 0; kk < 2; ++kk)
            qa[mt][kk] = *(const half8*)&Qb[(mt * 16 + c16) * 72 + kk * 32 + quad * 8];

    const ushortT* kb  = Kbuf + (size_t)bh * 8192 * 64;
    const ushortT* vtb = VT + ((size_t)bh * 64 + w * 16 + c16) * 8192;

    for (int ci = 0; ci < 2; ++ci) {
        const int s0 = s_base + ci * 128;

        // ---- QK^T: wave w owns keys [32w, 32w+32) ----
        half8 kf[2][2];
#pragma unroll
        for (int nt2 = 0; nt2 < 2; ++nt2)
#pragma unroll
            for (int kk = 0; kk < 2; ++kk)
                kf[nt2][kk] = *(const half8*)&kb[
                    (size_t)(s0 + w * 32 + nt2 * 16 + c16) * 64 + kk * 32 + quad * 8];
        f32x4 sacc[3][2];
#pragma unroll
        for (int mt = 0; mt < 3; ++mt)
#pragma unroll
            for (int nt2 = 0; nt2 < 2; ++nt2) {
                sacc[mt][nt2] = (f32x4){0.f, 0.f, 0.f, 0.f};
#pragma unroll
                for (int kk = 0; kk < 2; ++kk)
                    sacc[mt][nt2] = __builtin_amdgcn_mfma_f32_16x16x32_f16(
                        qa[mt][kk], kf[nt2][kk], sacc[mt][nt2], 0, 0, 0);
            }
#pragma unroll
        for (int mt = 0; mt < 3; ++mt)
#pragma unroll
            for (int nt2 = 0; nt2 < 2; ++nt2)
#pragma unroll
                for (int r = 0; r < 4; ++r)
                    sc[(mt * 16 + quad * 4 + r) * 132 + w * 32 + nt2 * 16 + c16] =
                        sacc[mt][nt2][r];
        __syncthreads();

        // ---- prefetch VT B-frags ----
        half8 vb[4];
#pragma unroll
        for (int kk = 0; kk < 4; ++kk)
            vb[kk] = *(const half8*)&vtb[s0 + kk * 32 + quad * 8];

        // ---- pointwise exp (no max), P fp16 in-place, reg row-sums ----
#pragma unroll
        for (int qi = 0; qi < 12; ++qi) {
            const int q = w * 12 + qi;
            float x0 = sc[q * 132 + lane];
            float x1 = sc[q * 132 + 64 + lane];
            ushortT u0 = f2h(__expf(x0));
            ushortT u1 = f2h(__expf(x1));
            lacc[qi] += h2f(u0) + h2f(u1);
            ushortT* pr = (ushortT*)&sc[q * 132];
            pr[lane] = u0;
            pr[lane + 64] = u1;
        }
        __syncthreads();

        // ---- PV: O += P @ V (wave owns d-tile w*16..+16) ----
#pragma unroll
        for (int mt = 0; mt < 3; ++mt)
#pragma unroll
            for (int kk = 0; kk < 4; ++kk) {
                half8 pa = *(const half8*)((const ushortT*)sc +
                    (size_t)(mt * 16 + c16) * 264 + kk * 32 + quad * 8);
                O[mt] = __builtin_amdgcn_mfma_f32_16x16x32_f16(pa, vb[kk], O[mt], 0, 0, 0);
            }
        __syncthreads();
    }

    // ---- epilogue ----
#pragma unroll
    for (int mt = 0; mt < 3; ++mt)
#pragma unroll
        for (int r = 0; r < 4; ++r) {
            const int q = mt * 16 + quad * 4 + r;
            if (q < U_)
                pacc[(((size_t)bh * NCHUNK + blockIdx.x) * U_ + q) * 64 + w * 16 + c16] =
                    O[mt][r];
        }
#pragma unroll
    for (int qi = 0; qi < 12; ++qi) {
        const int q = w * 12 + qi;
        float ssum = lacc[qi];
#pragma unroll
        for (int off = 1; off < 64; off <<= 1) ssum += __shfl_xor(ssum, off);
        if (lane == 0 && q < U_)
            pl[((size_t)bh * NCHUNK + blockIdx.x) * U_ + q] = ssum;
    }
}

// ---------------------------------------------------------------------------
// out_base[b][512] += bo/4 + (k-slice of mean_flat[b] @ Wo), k split x4.
// outbase zero-initialized in xconv.
// ---------------------------------------------------------------------------
__global__ __launch_bounds__(512) void outbase_kernel(
    const float* __restrict__ vsum, const float* __restrict__ Wo,
    const float* __restrict__ bo, float* __restrict__ outbase)
{
    const int b = blockIdx.x, ks = blockIdx.y, d = threadIdx.x;
    float acc = (ks == 0) ? bo[d] : 0.f;
    const int r0 = ks * 128;
    for (int r = r0; r < r0 + 128; ++r) {
        float mv = vsum[b * 512 + r] * (1.0f / S_);
        acc = fmaf(mv, Wo[(size_t)r * 512 + d], acc);
    }
    atomicAdd(&outbase[b * 512 + d], acc);
}

// ---------------------------------------------------------------------------
// Broadcast fill: out[b,s,:] = out_base[b,:]
// ---------------------------------------------------------------------------
__global__ __launch_bounds__(256) void fill_kernel(
    const float* __restrict__ outbase, float* __restrict__ out)
{
    size_t gid = (size_t)blockIdx.x * 256 + threadIdx.x;
    size_t e0 = gid * 4;
    int b = (int)(e0 >> 22);          // 8192*512 = 2^22
    int col = (int)(e0 & 511);
    float4 v = *(const float4*)&outbase[b * 512 + col];
    *(float4*)&out[e0] = v;
}

// ---------------------------------------------------------------------------
// Merged combine + correction: block (q, bh).
// ---------------------------------------------------------------------------
__global__ __launch_bounds__(512) void corr_out_kernel(
    const float* __restrict__ pl, const float* __restrict__ pacc,
    const float* __restrict__ vsum, const float* __restrict__ Wo,
    const int* __restrict__ topidx, float* __restrict__ out)
{
    __shared__ float corrS[64];
    const int q = blockIdx.x, bh = blockIdx.y;
    const int b = bh >> 3, h = bh & 7, tid = threadIdx.x;
    if (tid < 64) {
        float L = 0.f, a = 0.f;
        for (int c = 0; c < NCHUNK; ++c) {
            L += pl[((size_t)bh * NCHUNK + c) * U_ + q];
            a += pacc[(((size_t)bh * NCHUNK + c) * U_ + q) * 64 + tid];
        }
        corrS[tid] = a / L - vsum[b * 512 + h * 64 + tid] * (1.0f / S_);
    }
    __syncthreads();
    const int s = topidx[bh * U_ + q];
    const int d = tid;
    float delta = 0.f;
#pragma unroll
    for (int r = 0; r < 64; ++r)
        delta = fmaf(corrS[r], Wo[(size_t)(h * 64 + r) * 512 + d], delta);
    atomicAdd(&out[((size_t)b * S_ + s) * 512 + d], delta);
}

// ---------------------------------------------------------------------------
extern "C" void kernel_launch(void* const* d_in, const int* in_sizes, int n_in,
                              void* d_out, int out_size, void* d_ws, size_t ws_size,
                              hipStream_t stream)
{
    const float* X  = (const float*)d_in[0];
    const float* Wq = (const float*)d_in[1];
    const float* bq = (const float*)d_in[2];
    const float* Wk = (const float*)d_in[3];
    const float* bk = (const float*)d_in[4];
    const float* Wv = (const float*)d_in[5];
    const float* bv = (const float*)d_in[6];
    const float* Wo = (const float*)d_in[7];
    const float* bo = (const float*)d_in[8];
    float* out = (float*)d_out;

    char* ws = (char*)d_ws;
    size_t off = 0;
    auto alloc = [&](size_t bytes) {
        void* p = ws + off;
        off = (off + bytes + 255) & ~(size_t)255;
        return p;
    };
    ushortT* Xf   = (ushortT*)alloc((size_t)B_ * S_ * D_ * 2);
    ushortT* Qbuf = (ushortT*)alloc((size_t)B_ * S_ * D_ * 2);
    ushortT* Kbuf = (ushortT*)alloc((size_t)B_ * S_ * D_ * 2);
    ushortT* VT   = (ushortT*)alloc((size_t)B_ * S_ * D_ * 2);
    ushortT* WqT  = (ushortT*)alloc((size_t)D_ * D_ * 2);
    ushortT* WkT  = (ushortT*)alloc((size_t)D_ * D_ * 2);
    ushortT* WvT  = (ushortT*)alloc((size_t)D_ * D_ * 2);
    float* sparsity = (float*)alloc((size_t)B_ * H_ * S_ * 4);
    int*   topidx   = (int*)alloc((size_t)B_ * H_ * U_ * 4);
    float* pl       = (float*)alloc((size_t)B_ * H_ * NCHUNK * U_ * 4);
    float* pacc     = (float*)alloc((size_t)B_ * H_ * NCHUNK * U_ * 64 * 4);
    float* vsum     = (float*)alloc((size_t)B_ * 512 * 4);
    float* outbase  = (float*)alloc((size_t)B_ * 512 * 4);

    xconv<<<(B_ * S_ * D_) / (256 * 8), 256, 0, stream>>>(X, Xf, vsum, outbase);
    wprep<<<dim3(16, 16, 3), 256, 0, stream>>>(Wq, Wk, Wv, WqT, WkT, WvT);
    qkv_mfma<<<dim3(256, 12), 256, 0, stream>>>(Xf, WqT, WkT, WvT,
                                                bq, bk, bv, Qbuf, Kbuf, VT,
                                                sparsity, vsum);
    topk_kernel<<<B_ * H_, 256, 0, stream>>>(sparsity, topidx);
    attn_mfma<<<dim3(NCHUNK, B_ * H_), 256, 0, stream>>>(Qbuf, Kbuf, VT, topidx,
                                                         pl, pacc);
    outbase_kernel<<<dim3(B_, 4), 512, 0, stream>>>(vsum, Wo, bo, outbase);
    fill_kernel<<<(B_ * S_ * D_ / 4 + 255) / 256, 256, 0, stream>>>(outbase, out);
    corr_out_kernel<<<dim3(U_, B_ * H_), 512, 0, stream>>>(pl, pacc, vsum, Wo,
                                                           topidx, out);
}

// Round 8
// 290.692 us; speedup vs baseline: 5.7342x; 1.0737x over previous
//
#include <hip/hip_runtime.h>
#include <hip/hip_fp16.h>
#include <math.h>

#define B_ 4
#define S_ 8192
#define D_ 512
#define H_ 8
#define U_ 45            // int(5*ln(8193)) = 45
#define NCHUNK 16        // 512 keys per attention block

typedef unsigned short ushortT;
typedef __attribute__((ext_vector_type(8))) _Float16 half8;
typedef __attribute__((ext_vector_type(4))) float f32x4;

__device__ __forceinline__ ushortT f2h(float f) {
    return __half_as_ushort(__float2half(f));    // RNE
}
__device__ __forceinline__ float h2f(ushortT u) {
    return __half2float(__ushort_as_half(u));
}

__device__ __forceinline__ void gload_lds16(const ushortT* g, ushortT* l) {
    __builtin_amdgcn_global_load_lds(
        (const __attribute__((address_space(1))) void*)g,
        (__attribute__((address_space(3))) void*)l,
        16, 0, 0);
}

// ---------------------------------------------------------------------------
// Pre-pass 1: convert X (fp32) to fp16.  Block 0 zeroes vsum + outbase.
// ---------------------------------------------------------------------------
__global__ __launch_bounds__(256) void xconv(
    const float* __restrict__ X, ushortT* __restrict__ Xf,
    float* __restrict__ vsum, float* __restrict__ outbase)
{
    if (blockIdx.x == 0) {
        float4 z = {0.f, 0.f, 0.f, 0.f};
        *(float4*)&vsum[threadIdx.x * 8]        = z;
        *(float4*)&vsum[threadIdx.x * 8 + 4]    = z;
        *(float4*)&outbase[threadIdx.x * 8]     = z;
        *(float4*)&outbase[threadIdx.x * 8 + 4] = z;
    }
    size_t i = ((size_t)blockIdx.x * 256 + threadIdx.x) * 8;
    float4 a = *(const float4*)(X + i);
    float4 b = *(const float4*)(X + i + 4);
    *(ushort4*)(Xf + i)     = make_ushort4(f2h(a.x), f2h(a.y), f2h(a.z), f2h(a.w));
    *(ushort4*)(Xf + i + 4) = make_ushort4(f2h(b.x), f2h(b.y), f2h(b.z), f2h(b.w));
}

// ---------------------------------------------------------------------------
// Pre-pass 2: transpose + fp16-convert weights.  WT[n][k] = W[k][n].
// ---------------------------------------------------------------------------
__global__ __launch_bounds__(256) void wprep(
    const float* __restrict__ Wq, const float* __restrict__ Wk,
    const float* __restrict__ Wv,
    ushortT* __restrict__ WqT, ushortT* __restrict__ WkT,
    ushortT* __restrict__ WvT)
{
    __shared__ float t[32][33];
    const int z = blockIdx.z;
    const float* W = (z == 0) ? Wq : (z == 1) ? Wk : Wv;
    ushortT* O = (z == 0) ? WqT : (z == 1) ? WkT : WvT;
    const int tx = threadIdx.x & 31, ty4 = (threadIdx.x >> 5) * 4;
    const int r0 = blockIdx.y * 32, c0 = blockIdx.x * 32;
#pragma unroll
    for (int i = 0; i < 4; ++i)
        t[ty4 + i][tx] = W[(size_t)(r0 + ty4 + i) * 512 + c0 + tx];
    __syncthreads();
#pragma unroll
    for (int i = 0; i < 4; ++i)
        O[(size_t)(c0 + ty4 + i) * 512 + r0 + tx] = f2h(t[tx][ty4 + i]);
}

// ---------------------------------------------------------------------------
// MFMA QKV projection, fp16, BK=64 (8 K-iters, 32 MFMA per barrier pair).
// grid (256, 12): y 0-3 Q n-tiles, 4-7 K n-tiles, 8-11 V column-tiles.
// 128x128 tile, 4 waves 2x2, wave = 64x64.  launch_bounds (256,2): the
// measured-best config (R5: 80us; R6's (256,4) regressed to 87us).
// 8-chunk rotate swizzle keeps ds_read 2-way (free, verified 0 conflicts).
// ---------------------------------------------------------------------------
__global__ __launch_bounds__(256, 2) void qkv_mfma(
    const ushortT* __restrict__ Xf,
    const ushortT* __restrict__ WqT, const ushortT* __restrict__ WkT,
    const ushortT* __restrict__ WvT,
    const float* __restrict__ bq, const float* __restrict__ bk,
    const float* __restrict__ bv,
    ushortT* __restrict__ Qbuf, ushortT* __restrict__ Kbuf,
    ushortT* __restrict__ VT,
    float* __restrict__ sparsity, float* __restrict__ vsum)
{
    __shared__ ushortT lds[2 * 128 * 64];   // A | B, 16KB each
    ushortT* As = lds;
    ushortT* Bs = lds + 8192;

    const int tid  = threadIdx.x;
    const int w    = tid >> 6, lane = tid & 63;
    const int quad = lane >> 4, c16 = lane & 15;
    const int wr   = w >> 1,  wc  = w & 1;
    const int mat  = blockIdx.y >> 2;        // 0=Q 1=K 2=V
    const int nt   = blockIdx.y & 3;
    const int m0   = blockIdx.x * 128;
    const int n0   = nt * 128;

    // staging: pass c covers rows [32c,32c+32); wave w rows 8w..8w+8
    const int srowL = lane >> 3;                           // 0..7 within wave
    const int slc   = (((lane & 7) - (srowL & 7)) & 7) * 8; // logical chunk (halves)
    const int rrot  = c16 & 7;

    const ushortT* Ag = (mat == 2) ? WvT : Xf;
    const ushortT* Bg = (mat == 0) ? WqT : (mat == 1) ? WkT : Xf;
    const int arow0 = (mat == 2) ? n0 : m0;
    const int brow0 = (mat == 2) ? m0 : n0;

    f32x4 acc[4][4];
#pragma unroll
    for (int i = 0; i < 4; ++i)
#pragma unroll
        for (int j = 0; j < 4; ++j) acc[i][j] = (f32x4){0.f, 0.f, 0.f, 0.f};

    for (int k0 = 0; k0 < 512; k0 += 64) {
        __syncthreads();
#pragma unroll
        for (int c = 0; c < 4; ++c) {
            const int R = c * 32 + w * 8 + srowL;
            const int lbase = c * 2048 + w * 512;          // halves
            gload_lds16(Ag + (size_t)(arow0 + R) * 512 + k0 + slc, As + lbase);
            gload_lds16(Bg + (size_t)(brow0 + R) * 512 + k0 + slc, Bs + lbase);
        }
        __syncthreads();
#pragma unroll
        for (int kk = 0; kk < 2; ++kk) {
            const int phk = (((kk * 4 + quad) + rrot) & 7) * 8;
            half8 af[4], bf[4];
#pragma unroll
            for (int i = 0; i < 4; ++i) {
                af[i] = *(const half8*)&As[(wr * 64 + i * 16 + c16) * 64 + phk];
                bf[i] = *(const half8*)&Bs[(wc * 64 + i * 16 + c16) * 64 + phk];
            }
#pragma unroll
            for (int i = 0; i < 4; ++i)
#pragma unroll
                for (int j = 0; j < 4; ++j)
                    acc[i][j] = __builtin_amdgcn_mfma_f32_16x16x32_f16(af[i], bf[j], acc[i][j], 0, 0, 0);
        }
    }

    // ---- epilogue ----
    if (mat == 0) {
        // Q: store head-major fp16 + sparsity (sum of squares per row)
        const int b = m0 >> 13;
        const int head = (n0 + wc * 64) >> 6;
        float bb[4];
#pragma unroll
        for (int j = 0; j < 4; ++j) bb[j] = bq[n0 + wc * 64 + j * 16 + c16];
        ushortT* qbase = Qbuf + ((size_t)(b * 8 + head) * 8192) * 64;
#pragma unroll
        for (int i = 0; i < 4; ++i)
#pragma unroll
            for (int r = 0; r < 4; ++r) {
                const int s = (m0 & 8191) + wr * 64 + i * 16 + quad * 4 + r;
                float p = 0.f;
#pragma unroll
                for (int j = 0; j < 4; ++j) {
                    float v = acc[i][j][r] + bb[j];
                    qbase[(size_t)s * 64 + j * 16 + c16] = f2h(v);
                    p = fmaf(v, v, p);
                }
                p += __shfl_xor(p, 1);
                p += __shfl_xor(p, 2);
                p += __shfl_xor(p, 4);
                p += __shfl_xor(p, 8);
                if (c16 == 0)
                    sparsity[((size_t)b * H_ + head) * S_ + s] = p;
            }
    } else if (mat == 1) {
        const int b = m0 >> 13;
        const int head = (n0 + wc * 64) >> 6;
        float bb[4];
#pragma unroll
        for (int j = 0; j < 4; ++j) bb[j] = bk[n0 + wc * 64 + j * 16 + c16];
        ushortT* kbase = Kbuf + ((size_t)(b * 8 + head) * 8192) * 64;
#pragma unroll
        for (int i = 0; i < 4; ++i)
#pragma unroll
            for (int r = 0; r < 4; ++r) {
                const int s = (m0 & 8191) + wr * 64 + i * 16 + quad * 4 + r;
#pragma unroll
                for (int j = 0; j < 4; ++j)
                    kbase[(size_t)s * 64 + j * 16 + c16] = f2h(acc[i][j][r] + bb[j]);
            }
    } else {
        // V transposed: VT[((b*8+head)*64 + dd)*8192 + s]
        const int b = m0 >> 13;
        const int sbase = (m0 & 8191) + wc * 64;
#pragma unroll
        for (int i = 0; i < 4; ++i)
#pragma unroll
            for (int r = 0; r < 4; ++r) {
                const int dcol = n0 + wr * 64 + i * 16 + quad * 4 + r;
                const int head = dcol >> 6, dd = dcol & 63;
                const float biasv = bv[dcol];
                ushortT* vrow = VT + ((size_t)(b * 8 + head) * 64 + dd) * 8192;
                float vsa = 0.f;
#pragma unroll
                for (int j = 0; j < 4; ++j) {
                    float v = acc[i][j][r] + biasv;
                    vrow[sbase + j * 16 + c16] = f2h(v);
                    vsa += v;
                }
                vsa += __shfl_xor(vsa, 1);
                vsa += __shfl_xor(vsa, 2);
                vsa += __shfl_xor(vsa, 4);
                vsa += __shfl_xor(vsa, 8);
                if (c16 == 0) atomicAdd(&vsum[b * 512 + dcol], vsa);
            }
    }
}

// ---------------------------------------------------------------------------
// Top-45 per (b,h): 4-level byte radix-select on fp32 bits (values >= 0 so
// uint order == float order).  8-way replicated 256-bin LDS histograms;
// threshold bin found via parallel suffix-sum scan (no serial thread-0 scan).
// ---------------------------------------------------------------------------
__global__ __launch_bounds__(256) void topk_kernel(
    const float* __restrict__ sparsity, int* __restrict__ topidx)
{
    __shared__ unsigned vals[S_];        // 32 KB
    __shared__ unsigned hist[8][256];    // 8 KB
    __shared__ int ssum[256];
    __shared__ unsigned prefix_s;
    __shared__ int need_s;
    __shared__ int cnt_gt_s, cnt_eq_s;
    __shared__ int eqidx[64];
    const int bh = blockIdx.x, tid = threadIdx.x;
    const unsigned* sp = (const unsigned*)(sparsity + (size_t)bh * S_);
    for (int i = tid; i < S_; i += 256) vals[i] = sp[i];

    unsigned prefix = 0;
    int need = U_;
    const int rep = tid & 7;
    for (int level = 0; level < 4; ++level) {
        const int shift = 24 - level * 8;
#pragma unroll
        for (int r = 0; r < 8; ++r) hist[r][tid] = 0;
        __syncthreads();
        const unsigned pmask = (level == 0) ? 0u : (0xFFFFFFFFu << (shift + 8));
        for (int i = tid; i < S_; i += 256) {
            unsigned v = vals[i];
            if ((v & pmask) == prefix)
                atomicAdd(&hist[rep][(v >> shift) & 255], 1u);
        }
        __syncthreads();
        int bs = 0;
#pragma unroll
        for (int r = 0; r < 8; ++r) bs += (int)hist[r][tid];
        ssum[tid] = bs;
        __syncthreads();
        // suffix sum: ssum[t] = count of values in bins >= t (matching prefix)
        for (int off = 1; off < 256; off <<= 1) {
            int add = (tid + off < 256) ? ssum[tid + off] : 0;
            __syncthreads();
            ssum[tid] += add;
            __syncthreads();
        }
        int snext = (tid == 255) ? 0 : ssum[tid + 1];
        if (ssum[tid] >= need && snext < need) {   // exactly one thread
            prefix_s = prefix | ((unsigned)tid << shift);
            need_s = need - snext;
        }
        __syncthreads();
        prefix = prefix_s;
        need = need_s;
        __syncthreads();
    }
    // prefix == exact bits of the 45th-largest value
    const unsigned T = prefix;
    if (tid == 0) { cnt_gt_s = 0; cnt_eq_s = 0; }
    __syncthreads();
    for (int i = tid; i < S_; i += 256) {
        unsigned v = vals[i];
        if (v > T) {
            int p = atomicAdd(&cnt_gt_s, 1);
            topidx[bh * U_ + p] = i;
        } else if (v == T) {
            int p = atomicAdd(&cnt_eq_s, 1);
            if (p < 64) eqidx[p] = i;
        }
    }
    __syncthreads();
    if (tid == 0) {
        int rem = U_ - cnt_gt_s;
        int n = cnt_eq_s < 64 ? cnt_eq_s : 64;
        for (int a = 0; a < rem; ++a) {     // smallest indices among ties
            int best = 1 << 30, bj = 0;
            for (int j = 0; j < n; ++j)
                if (eqidx[j] < best) { best = eqidx[j]; bj = j; }
            topidx[bh * U_ + cnt_gt_s + a] = best;
            eqidx[bj] = 1 << 30;
        }
    }
}

// ---------------------------------------------------------------------------
// MFMA attention partials (fp16), no-max softmax (|s| bounded ~4).
// Grid (NCHUNK=16, 32 bh), 256 thr.  Block = 512 keys, 4 chunks of 128.
// Q gathered from Qbuf via topidx; prologue amortized over 512 keys.
// ---------------------------------------------------------------------------
__global__ __launch_bounds__(256, 2) void attn_mfma(
    const ushortT* __restrict__ Qbuf, const ushortT* __restrict__ Kbuf,
    const ushortT* __restrict__ VT, const int* __restrict__ topidx,
    float* __restrict__ pl, float* __restrict__ pacc)
{
    __shared__ float sc[48 * 132];          // scores f32; P fp16 in-place
    __shared__ ushortT Qb[48 * 72];         // Q fp16, scale folded, padded

    const int tid = threadIdx.x;
    const int w = tid >> 6, lane = tid & 63;
    const int quad = lane >> 4, c16 = lane & 15;
    const int bh = blockIdx.y;
    const int s_base = blockIdx.x * 512;

    for (int i = tid; i < 48 * 64; i += 256) {
        int q = i >> 6, d = i & 63;
        float v = 0.f;
        if (q < U_) {
            int s = topidx[bh * U_ + q];
            v = h2f(Qbuf[((size_t)bh * 8192 + s) * 64 + d]) * 0.125f;
        }
        Qb[q * 72 + d] = f2h(v);
    }

    f32x4 O[3];
#pragma unroll
    for (int mt = 0; mt < 3; ++mt) O[mt] = (f32x4){0.f, 0.f, 0.f, 0.f};
    float lacc[12];
#pragma unroll
    for (int qi = 0; qi < 12; ++qi) lacc[qi] = 0.f;

    __syncthreads();

    half8 qa[3][2];
#pragma unroll
    for (int mt = 0; mt < 3; ++mt)
#pragma unroll
        for (int kk = 0; kk < 2; ++kk)
            qa[mt][kk] = *(const half8*)&Qb[(mt * 16 + c16) * 72 + kk * 32 + quad * 8];

    const ushortT* kb  = Kbuf + (size_t)bh * 8192 * 64;
    const ushortT* vtb = VT + ((size_t)bh * 64 + w * 16 + c16) * 8192;

    for (int ci = 0; ci < 4; ++ci) {
        const int s0 = s_base + ci * 128;

        // ---- QK^T: wave w owns keys [32w, 32w+32) ----
        half8 kf[2][2];
#pragma unroll
        for (int nt2 = 0; nt2 < 2; ++nt2)
#pragma unroll
            for (int kk = 0; kk < 2; ++kk)
                kf[nt2][kk] = *(const half8*)&kb[
                    (size_t)(s0 + w * 32 + nt2 * 16 + c16) * 64 + kk * 32 + quad * 8];
        f32x4 sacc[3][2];
#pragma unroll
        for (int mt = 0; mt < 3; ++mt)
#pragma unroll
            for (int nt2 = 0; nt2 < 2; ++nt2) {
                sacc[mt][nt2] = (f32x4){0.f, 0.f, 0.f, 0.f};
#pragma unroll
                for (int kk = 0; kk < 2; ++kk)
                    sacc[mt][nt2] = __builtin_amdgcn_mfma_f32_16x16x32_f16(
                        qa[mt][kk], kf[nt2][kk], sacc[mt][nt2], 0, 0, 0);
            }
#pragma unroll
        for (int mt = 0; mt < 3; ++mt)
#pragma unroll
            for (int nt2 = 0; nt2 < 2; ++nt2)
#pragma unroll
                for (int r = 0; r < 4; ++r)
                    sc[(mt * 16 + quad * 4 + r) * 132 + w * 32 + nt2 * 16 + c16] =
                        sacc[mt][nt2][r];
        __syncthreads();

        // ---- prefetch VT B-frags ----
        half8 vb[4];
#pragma unroll
        for (int kk = 0; kk < 4; ++kk)
            vb[kk] = *(const half8*)&vtb[s0 + kk * 32 + quad * 8];

        // ---- pointwise exp (no max), P fp16 in-place, reg row-sums ----
#pragma unroll
        for (int qi = 0; qi < 12; ++qi) {
            const int q = w * 12 + qi;
            float x0 = sc[q * 132 + lane];
            float x1 = sc[q * 132 + 64 + lane];
            ushortT u0 = f2h(__expf(x0));
            ushortT u1 = f2h(__expf(x1));
            lacc[qi] += h2f(u0) + h2f(u1);
            ushortT* pr = (ushortT*)&sc[q * 132];
            pr[lane] = u0;
            pr[lane + 64] = u1;
        }
        __syncthreads();

        // ---- PV: O += P @ V (wave owns d-tile w*16..+16) ----
#pragma unroll
        for (int mt = 0; mt < 3; ++mt)
#pragma unroll
            for (int kk = 0; kk < 4; ++kk) {
                half8 pa = *(const half8*)((const ushortT*)sc +
                    (size_t)(mt * 16 + c16) * 264 + kk * 32 + quad * 8);
                O[mt] = __builtin_amdgcn_mfma_f32_16x16x32_f16(pa, vb[kk], O[mt], 0, 0, 0);
            }
        __syncthreads();
    }

    // ---- epilogue ----
#pragma unroll
    for (int mt = 0; mt < 3; ++mt)
#pragma unroll
        for (int r = 0; r < 4; ++r) {
            const int q = mt * 16 + quad * 4 + r;
            if (q < U_)
                pacc[(((size_t)bh * NCHUNK + blockIdx.x) * U_ + q) * 64 + w * 16 + c16] =
                    O[mt][r];
        }
#pragma unroll
    for (int qi = 0; qi < 12; ++qi) {
        const int q = w * 12 + qi;
        float ssum = lacc[qi];
#pragma unroll
        for (int off = 1; off < 64; off <<= 1) ssum += __shfl_xor(ssum, off);
        if (lane == 0 && q < U_)
            pl[((size_t)bh * NCHUNK + blockIdx.x) * U_ + q] = ssum;
    }
}

// ---------------------------------------------------------------------------
// out_base[b][512] += bo (ks==0) + k-slice of mean_flat[b] @ Wo, k split x4.
// outbase zero-initialized in xconv.
// ---------------------------------------------------------------------------
__global__ __launch_bounds__(512) void outbase_kernel(
    const float* __restrict__ vsum, const float* __restrict__ Wo,
    const float* __restrict__ bo, float* __restrict__ outbase)
{
    const int b = blockIdx.x, ks = blockIdx.y, d = threadIdx.x;
    float acc = (ks == 0) ? bo[d] : 0.f;
    const int r0 = ks * 128;
    for (int r = r0; r < r0 + 128; ++r) {
        float mv = vsum[b * 512 + r] * (1.0f / S_);
        acc = fmaf(mv, Wo[(size_t)r * 512 + d], acc);
    }
    atomicAdd(&outbase[b * 512 + d], acc);
}

// ---------------------------------------------------------------------------
// Broadcast fill: out[b,s,:] = out_base[b,:]
// ---------------------------------------------------------------------------
__global__ __launch_bounds__(256) void fill_kernel(
    const float* __restrict__ outbase, float* __restrict__ out)
{
    size_t gid = (size_t)blockIdx.x * 256 + threadIdx.x;
    size_t e0 = gid * 4;
    int b = (int)(e0 >> 22);          // 8192*512 = 2^22
    int col = (int)(e0 & 511);
    float4 v = *(const float4*)&outbase[b * 512 + col];
    *(float4*)&out[e0] = v;
}

// ---------------------------------------------------------------------------
// Merged combine + correction: block (q, bh).
// ---------------------------------------------------------------------------
__global__ __launch_bounds__(512) void corr_out_kernel(
    const float* __restrict__ pl, const float* __restrict__ pacc,
    const float* __restrict__ vsum, const float* __restrict__ Wo,
    const int* __restrict__ topidx, float* __restrict__ out)
{
    __shared__ float corrS[64];
    const int q = blockIdx.x, bh = blockIdx.y;
    const int b = bh >> 3, h = bh & 7, tid = threadIdx.x;
    if (tid < 64) {
        float L = 0.f, a = 0.f;
        for (int c = 0; c < NCHUNK; ++c) {
            L += pl[((size_t)bh * NCHUNK + c) * U_ + q];
            a += pacc[(((size_t)bh * NCHUNK + c) * U_ + q) * 64 + tid];
        }
        corrS[tid] = a / L - vsum[b * 512 + h * 64 + tid] * (1.0f / S_);
    }
    __syncthreads();
    const int s = topidx[bh * U_ + q];
    const int d = tid;
    float delta = 0.f;
#pragma unroll
    for (int r = 0; r < 64; ++r)
        delta = fmaf(corrS[r], Wo[(size_t)(h * 64 + r) * 512 + d], delta);
    atomicAdd(&out[((size_t)b * S_ + s) * 512 + d], delta);
}

// ---------------------------------------------------------------------------
extern "C" void kernel_launch(void* const* d_in, const int* in_sizes, int n_in,
                              void* d_out, int out_size, void* d_ws, size_t ws_size,
                              hipStream_t stream)
{
    const float* X  = (const float*)d_in[0];
    const float* Wq = (const float*)d_in[1];
    const float* bq = (const float*)d_in[2];
    const float* Wk = (const float*)d_in[3];
    const float* bk = (const float*)d_in[4];
    const float* Wv = (const float*)d_in[5];
    const float* bv = (const float*)d_in[6];
    const float* Wo = (const float*)d_in[7];
    const float* bo = (const float*)d_in[8];
    float* out = (float*)d_out;

    char* ws = (char*)d_ws;
    size_t off = 0;
    auto alloc = [&](size_t bytes) {
        void* p = ws + off;
        off = (off + bytes + 255) & ~(size_t)255;
        return p;
    };
    ushortT* Xf   = (ushortT*)alloc((size_t)B_ * S_ * D_ * 2);
    ushortT* Qbuf = (ushortT*)alloc((size_t)B_ * S_ * D_ * 2);
    ushortT* Kbuf = (ushortT*)alloc((size_t)B_ * S_ * D_ * 2);
    ushortT* VT   = (ushortT*)alloc((size_t)B_ * S_ * D_ * 2);
    ushortT* WqT  = (ushortT*)alloc((size_t)D_ * D_ * 2);
    ushortT* WkT  = (ushortT*)alloc((size_t)D_ * D_ * 2);
    ushortT* WvT  = (ushortT*)alloc((size_t)D_ * D_ * 2);
    float* sparsity = (float*)alloc((size_t)B_ * H_ * S_ * 4);
    int*   topidx   = (int*)alloc((size_t)B_ * H_ * U_ * 4);
    float* pl       = (float*)alloc((size_t)B_ * H_ * NCHUNK * U_ * 4);
    float* pacc     = (float*)alloc((size_t)B_ * H_ * NCHUNK * U_ * 64 * 4);
    float* vsum     = (float*)alloc((size_t)B_ * 512 * 4);
    float* outbase  = (float*)alloc((size_t)B_ * 512 * 4);

    xconv<<<(B_ * S_ * D_) / (256 * 8), 256, 0, stream>>>(X, Xf, vsum, outbase);
    wprep<<<dim3(16, 16, 3), 256, 0, stream>>>(Wq, Wk, Wv, WqT, WkT, WvT);
    qkv_mfma<<<dim3(256, 12), 256, 0, stream>>>(Xf, WqT, WkT, WvT,
                                                bq, bk, bv, Qbuf, Kbuf, VT,
                                                sparsity, vsum);
    topk_kernel<<<B_ * H_, 256, 0, stream>>>(sparsity, topidx);
    attn_mfma<<<dim3(NCHUNK, B_ * H_), 256, 0, stream>>>(Qbuf, Kbuf, VT, topidx,
                                                         pl, pacc);
    outbase_kernel<<<dim3(B_, 4), 512, 0, stream>>>(vsum, Wo, bo, outbase);
    fill_kernel<<<(B_ * S_ * D_ / 4 + 255) / 256, 256, 0, stream>>>(outbase, out);
    corr_out_kernel<<<dim3(U_, B_ * H_), 512, 0, stream>>>(pl, pacc, vsum, Wo,
                                                           topidx, out);
}